// Round 3
// baseline (3033.417 us; speedup 1.0000x reference)
//
#include <hip/hip_runtime.h>

#define NN 50000
#define EE 800000
#define DIM 128
#define OUTC 20
#define LL 7
#define LE (LL*EE)
#define LN (LL*NN)
#define NBUK 391              // ceil(NN/128) buckets of 128 dst nodes
#define LBUK (LL*NBUK)        // 2737
#define BN_EPS 1e-5f

static __device__ __forceinline__ float sigm(float z){ return 1.0f/(1.0f+expf(-z)); }

// ============ preprocessing: two-level binned counting sort by (layer,dst) ============

// bucket histogram, LDS-aggregated (no hot global atomics)
__global__ __launch_bounds__(256) void k_bhist(const int* __restrict__ ei,
                                               int* __restrict__ bcnt){
  __shared__ int h[LBUK];
  int tid = threadIdx.x;
  for (int i=tid;i<LBUK;i+=256) h[i]=0;
  __syncthreads();
  for (int gid = blockIdx.x*256+tid; gid < LE; gid += gridDim.x*256){
    int l = gid / EE;
    int e = gid - l*EE;
    int dst = ei[(2*l+1)*EE + e];
    atomicAdd(&h[l*NBUK + (dst>>7)], 1);
  }
  __syncthreads();
  for (int i=tid;i<LBUK;i+=256){ int v=h[i]; if (v) atomicAdd(&bcnt[i], v); }
}

// exclusive scan over 2737 bucket counts (single block)
__global__ __launch_bounds__(1024) void k_bscan(const int* __restrict__ bcnt,
                                                int* __restrict__ bbase,
                                                int* __restrict__ bcur){
  __shared__ int s[1024];
  int t = threadIdx.x;
  int v[3]; int sum=0;
  #pragma unroll
  for (int i=0;i<3;i++){ int idx=t*3+i; v[i]=(idx<LBUK)? bcnt[idx]:0; sum+=v[i]; }
  s[t]=sum; __syncthreads();
  for (int off=1; off<1024; off<<=1){
    int x = (t>=off)? s[t-off]:0;
    __syncthreads(); s[t]+=x; __syncthreads();
  }
  int run = s[t]-sum;
  #pragma unroll
  for (int i=0;i<3;i++){
    int idx=t*3+i;
    if (idx<LBUK){ bbase[idx]=run; bcur[idx]=run; }
    run += v[i];
  }
  if (t==1023) bbase[LBUK] = s[1023];   // == LE
}

// bin scatter: write frontier = 2737 cursors -> L2-resident, lines fill fully
__global__ __launch_bounds__(256) void k_bin(const int* __restrict__ ei,
    const float* __restrict__ ew, int* __restrict__ bcur, int2* __restrict__ btmp){
  int gid = blockIdx.x*256+threadIdx.x;
  if (gid>=LE) return;
  int l = gid / EE;
  int e = gid - l*EE;
  int src = ei[(2*l)*EE + e];
  int dst = ei[(2*l+1)*EE + e];
  int b = l*NBUK + (dst>>7);
  int pos = atomicAdd(&bcur[b], 1);
  btmp[pos] = make_int2(src | ((dst&127)<<16), __float_as_int(ew[gid]));
}

// per-dst histogram from binned edges (sequential reads, LDS counters)
__global__ __launch_bounds__(256) void k_chist(const int2* __restrict__ btmp,
    const int* __restrict__ bbase, int* __restrict__ cnt){
  int b = blockIdx.x;
  int l = b / NBUK, bl = b - l*NBUK;
  __shared__ int h[128];
  int tid=threadIdx.x;
  if (tid<128) h[tid]=0;
  __syncthreads();
  int beg=bbase[b], end=bbase[b+1];
  for (int p=beg+tid; p<end; p+=256){
    int d = (btmp[p].x>>16)&127;
    atomicAdd(&h[d],1);
  }
  __syncthreads();
  if (tid<128){
    int node = bl*128+tid;
    if (node<NN) cnt[l*NN+node] = h[tid];
  }
}

__global__ void k_scan1(const int* __restrict__ cnt, int* __restrict__ offs,
                        int* __restrict__ bsums, int n){
  __shared__ int s[256];
  int t = threadIdx.x;
  int base = blockIdx.x*1024 + t*4;
  int v[4]; int sum = 0;
  #pragma unroll
  for (int i=0;i<4;i++){ v[i] = (base+i<n)? cnt[base+i] : 0; sum += v[i]; }
  s[t]=sum; __syncthreads();
  for (int off=1; off<256; off<<=1){
    int x = (t>=off)? s[t-off] : 0;
    __syncthreads();
    s[t] += x;
    __syncthreads();
  }
  if (t==255) bsums[blockIdx.x] = s[255];
  int run = s[t]-sum;
  #pragma unroll
  for (int i=0;i<4;i++){ if (base+i<n) offs[base+i]=run; run += v[i]; }
}

__global__ void k_scan2(int* bsums, int nb){
  __shared__ int s[512];
  int t=threadIdx.x;
  int v = (t<nb)? bsums[t]:0;
  s[t]=v; __syncthreads();
  for (int off=1; off<512; off<<=1){
    int x=(t>=off)? s[t-off]:0; __syncthreads(); s[t]+=x; __syncthreads();
  }
  if (t<nb) bsums[t] = s[t]-v;
}

__global__ void k_scan3(int* __restrict__ offs, const int* __restrict__ bsums, int n){
  int gid = blockIdx.x*256+threadIdx.x;
  if (gid < n) offs[gid] += bsums[gid>>10];
  if (gid==0) offs[n]=LE;
}

// local sort: per-bucket scatter into final positions (16KB output window, L2-resident)
__global__ __launch_bounds__(256) void k_csort(const int2* __restrict__ btmp,
    const int* __restrict__ bbase, const int* __restrict__ offs,
    int2* __restrict__ sedge){
  int b = blockIdx.x;
  int l = b / NBUK, bl = b - l*NBUK;
  __shared__ int cur[128];
  int tid=threadIdx.x;
  if (tid<128){
    int node = bl*128+tid;
    cur[tid] = (node<NN)? offs[l*NN+node] : 0;
  }
  __syncthreads();
  int beg=bbase[b], end=bbase[b+1];
  for (int p=beg+tid; p<end; p+=256){
    int2 r = btmp[p];
    int d = (r.x>>16)&127;
    int pos = atomicAdd(&cur[d],1);
    sedge[pos] = make_int2(r.x & 0xFFFF, r.y);
  }
}

__global__ void k_gather_emb(const int* __restrict__ verts, const float* __restrict__ emb,
                             float* __restrict__ x){
  int gid = blockIdx.x*256+threadIdx.x;   // over NN*32 float4s
  int n = gid>>5, q = gid&31;
  if (n>=NN) return;
  int v = verts[n];
  ((float4*)x)[gid] = ((const float4*)emb)[(size_t)v*32+q];
}

// ---------------- GEMM: Y[M,128] = X[M,128] @ W[128,128] ----------------
#define XS_STRIDE 68
__global__ __launch_bounds__(256) void k_gemm128v(const float* __restrict__ X,
    const float* __restrict__ W, float* __restrict__ Y, int M){
  __shared__ float Xs[128*XS_STRIDE];     // 34 KB
  int tid = threadIdx.x;
  int row0 = blockIdx.x*64;
  #pragma unroll
  for (int it=0; it<8; it++){
    int idx = tid + it*256;
    int r = idx>>5, kq = idx&31;
    float4 v = make_float4(0.f,0.f,0.f,0.f);
    if (row0+r < M) v = ((const float4*)X)[(size_t)(row0+r)*32 + kq];
    Xs[(kq*4+0)*XS_STRIDE+r]=v.x; Xs[(kq*4+1)*XS_STRIDE+r]=v.y;
    Xs[(kq*4+2)*XS_STRIDE+r]=v.z; Xs[(kq*4+3)*XS_STRIDE+r]=v.w;
  }
  __syncthreads();
  int ty = tid>>4, tx = tid&15;           // rows ty*4..+3, cols tx*8..+7
  float acc[4][8];
  #pragma unroll
  for (int i=0;i<4;i++){
    #pragma unroll
    for (int j=0;j<8;j++) acc[i][j]=0.f;
  }
  const float* Wp = W + tx*8;
  #pragma unroll 4
  for (int k=0;k<128;k++){
    float4 xv = *(const float4*)&Xs[k*XS_STRIDE + ty*4];
    float4 w0 = *(const float4*)(Wp + k*128);
    float4 w1 = *(const float4*)(Wp + k*128 + 4);
    float xr[4] = {xv.x, xv.y, xv.z, xv.w};
    #pragma unroll
    for (int i=0;i<4;i++){
      acc[i][0]+=xr[i]*w0.x; acc[i][1]+=xr[i]*w0.y; acc[i][2]+=xr[i]*w0.z; acc[i][3]+=xr[i]*w0.w;
      acc[i][4]+=xr[i]*w1.x; acc[i][5]+=xr[i]*w1.y; acc[i][6]+=xr[i]*w1.z; acc[i][7]+=xr[i]*w1.w;
    }
  }
  #pragma unroll
  for (int i=0;i<4;i++){
    int r = row0 + ty*4 + i;
    if (r<M){
      float* yp = Y + (size_t)r*128 + tx*8;
      *(float4*)yp     = make_float4(acc[i][0],acc[i][1],acc[i][2],acc[i][3]);
      *(float4*)(yp+4) = make_float4(acc[i][4],acc[i][5],acc[i][6],acc[i][7]);
    }
  }
}

// ---------------- fused: BN(h)+ReLU during staging, GEMM (hn @ te_wc), gate epilogue ----------------
__global__ __launch_bounds__(256) void k_gemm_gate(const float* __restrict__ H,
    const float* __restrict__ W, const float* __restrict__ D,
    const float* __restrict__ teb,
    const float* __restrict__ gsum, const float* __restrict__ gsumsq,
    const float* __restrict__ gamma, const float* __restrict__ beta,
    float* __restrict__ x, int M){
  __shared__ float Xs[128*XS_STRIDE];
  int tid = threadIdx.x;
  int row0 = blockIdx.x*64;
  const float invN = 1.0f/NN;
  #pragma unroll
  for (int it=0; it<8; it++){
    int idx = tid + it*256;
    int r = idx>>5, kq = idx&31;
    float4 v = make_float4(0.f,0.f,0.f,0.f);
    if (row0+r < M) v = ((const float4*)H)[(size_t)(row0+r)*32 + kq];
    float4 s  = ((const float4*)gsum)[kq];
    float4 sq = ((const float4*)gsumsq)[kq];
    float4 ga = ((const float4*)gamma)[kq];
    float4 be = ((const float4*)beta)[kq];
    float m, var, sc;
    m=s.x*invN; var=sq.x*invN-m*m; sc=rsqrtf(var+BN_EPS)*ga.x; v.x=fmaxf((v.x-m)*sc+be.x,0.f);
    m=s.y*invN; var=sq.y*invN-m*m; sc=rsqrtf(var+BN_EPS)*ga.y; v.y=fmaxf((v.y-m)*sc+be.y,0.f);
    m=s.z*invN; var=sq.z*invN-m*m; sc=rsqrtf(var+BN_EPS)*ga.z; v.z=fmaxf((v.z-m)*sc+be.z,0.f);
    m=s.w*invN; var=sq.w*invN-m*m; sc=rsqrtf(var+BN_EPS)*ga.w; v.w=fmaxf((v.w-m)*sc+be.w,0.f);
    Xs[(kq*4+0)*XS_STRIDE+r]=v.x; Xs[(kq*4+1)*XS_STRIDE+r]=v.y;
    Xs[(kq*4+2)*XS_STRIDE+r]=v.z; Xs[(kq*4+3)*XS_STRIDE+r]=v.w;
  }
  __syncthreads();
  int ty = tid>>4, tx = tid&15;
  float acc[4][8];
  #pragma unroll
  for (int i=0;i<4;i++){
    #pragma unroll
    for (int j=0;j<8;j++) acc[i][j]=0.f;
  }
  const float* Wp = W + tx*8;
  #pragma unroll 4
  for (int k=0;k<128;k++){
    float4 xv = *(const float4*)&Xs[k*XS_STRIDE + ty*4];
    float4 w0 = *(const float4*)(Wp + k*128);
    float4 w1 = *(const float4*)(Wp + k*128 + 4);
    float xr[4] = {xv.x, xv.y, xv.z, xv.w};
    #pragma unroll
    for (int i=0;i<4;i++){
      acc[i][0]+=xr[i]*w0.x; acc[i][1]+=xr[i]*w0.y; acc[i][2]+=xr[i]*w0.z; acc[i][3]+=xr[i]*w0.w;
      acc[i][4]+=xr[i]*w1.x; acc[i][5]+=xr[i]*w1.y; acc[i][6]+=xr[i]*w1.z; acc[i][7]+=xr[i]*w1.w;
    }
  }
  float4 b0 = ((const float4*)teb)[tx*2];
  float4 b1 = ((const float4*)teb)[tx*2+1];
  float hcol[8][4];     // hcol[j][i] = hn[row ty*4+i][col tx*8+j]
  #pragma unroll
  for (int j=0;j<8;j++){
    float4 hv = *(const float4*)&Xs[(tx*8+j)*XS_STRIDE + ty*4];
    hcol[j][0]=hv.x; hcol[j][1]=hv.y; hcol[j][2]=hv.z; hcol[j][3]=hv.w;
  }
  #pragma unroll
  for (int i=0;i<4;i++){
    int r = row0 + ty*4 + i;
    if (r<M){
      const float* dp = D + (size_t)r*128 + tx*8;
      float* xp = x + (size_t)r*128 + tx*8;
      float4 d0 = *(const float4*)dp, d1 = *(const float4*)(dp+4);
      float4 xo0 = *(const float4*)xp, xo1 = *(const float4*)(xp+4);
      float g;
      float4 n0, n1;
      g=sigm(acc[i][0]+d0.x+b0.x); n0.x = g*hcol[0][i] + (1.f-g)*xo0.x;
      g=sigm(acc[i][1]+d0.y+b0.y); n0.y = g*hcol[1][i] + (1.f-g)*xo0.y;
      g=sigm(acc[i][2]+d0.z+b0.z); n0.z = g*hcol[2][i] + (1.f-g)*xo0.z;
      g=sigm(acc[i][3]+d0.w+b0.w); n0.w = g*hcol[3][i] + (1.f-g)*xo0.w;
      g=sigm(acc[i][4]+d1.x+b1.x); n1.x = g*hcol[4][i] + (1.f-g)*xo1.x;
      g=sigm(acc[i][5]+d1.y+b1.y); n1.y = g*hcol[5][i] + (1.f-g)*xo1.y;
      g=sigm(acc[i][6]+d1.z+b1.z); n1.z = g*hcol[6][i] + (1.f-g)*xo1.z;
      g=sigm(acc[i][7]+d1.w+b1.w); n1.w = g*hcol[7][i] + (1.f-g)*xo1.w;
      *(float4*)xp = n0; *(float4*)(xp+4) = n1;
    }
  }
}

// ---------------- Y[M,20] = X[M,128] @ W[128,20] ----------------
__global__ __launch_bounds__(256) void k_gemm_out(const float* __restrict__ X,
    const float* __restrict__ W, float* __restrict__ Y, int M){
  __shared__ float Ws[DIM*OUTC];
  __shared__ float Xs2[8*DIM];
  int tid=threadIdx.x;
  for (int i=tid;i<DIM*OUTC;i+=256) Ws[i]=W[i];
  int row0=blockIdx.x*8;
  {
    int r = tid>>5, kq = tid&31;
    float4 v = make_float4(0.f,0.f,0.f,0.f);
    if (row0+r<M) v = ((const float4*)X)[(size_t)(row0+r)*32+kq];
    *(float4*)&Xs2[r*DIM+kq*4]=v;
  }
  __syncthreads();
  int c = tid&31, rl=tid>>5;
  if (c<OUTC && row0+rl<M){
    float acc=0.f;
    #pragma unroll 8
    for (int k=0;k<DIM;k++) acc += Xs2[rl*DIM+k]*Ws[k*OUTC+c];
    Y[(size_t)(row0+rl)*OUTC+c]=acc;
  }
}

// ---------------- SpMM gather: h[n] = sum_e w_e * sup[src_e] ----------------
__global__ __launch_bounds__(256) void k_spmm128(const float* __restrict__ sup,
    const int2* __restrict__ sedge, const int* __restrict__ offs,
    float* __restrict__ h, int base){
  int node = blockIdx.x*2 + (threadIdx.x>>7);
  int f = threadIdx.x & 127;
  int beg = offs[base+node], end = offs[base+node+1];
  float acc=0.f, acc2=0.f;
  int p=beg;
  for (; p+1<end; p+=2){
    int2 e0 = sedge[p], e1 = sedge[p+1];
    acc  += __int_as_float(e0.y) * sup[(size_t)e0.x*DIM + f];
    acc2 += __int_as_float(e1.y) * sup[(size_t)e1.x*DIM + f];
  }
  if (p<end){
    int2 e0 = sedge[p];
    acc += __int_as_float(e0.y) * sup[(size_t)e0.x*DIM + f];
  }
  h[(size_t)node*DIM+f]=acc+acc2;
}

__global__ __launch_bounds__(256) void k_spmm_out(const float* __restrict__ sup,
    const int2* __restrict__ sedge, const int* __restrict__ offs,
    float* __restrict__ h, int base){
  int node = blockIdx.x*4 + (threadIdx.x>>6);
  int f = threadIdx.x & 63;
  if (f >= OUTC) return;
  int beg=offs[base+node], end=offs[base+node+1];
  float acc=0.f;
  for (int p=beg;p<end;p++){
    int2 e = sedge[p];
    acc += __int_as_float(e.y)*sup[(size_t)e.x*OUTC+f];
  }
  h[(size_t)node*OUTC+f]=acc;
}

// ---------------- BatchNorm stats ----------------
template<int DP>
__global__ __launch_bounds__(256) void k_bn_stats(const float* __restrict__ h,
    int M, int D, float* __restrict__ gsum, float* __restrict__ gsumsq, int rpb){
  const int G = 256/DP;
  int f = threadIdx.x % DP;
  int g = threadIdx.x / DP;
  float s=0.f, ss=0.f;
  int r0 = blockIdx.x*rpb;
  int r1 = min(M, r0+rpb);
  if (f < D){
    for (int r=r0+g; r<r1; r+=G){ float v = h[(size_t)r*D+f]; s+=v; ss+=v*v; }
  }
  __shared__ float sh[256], sh2[256];
  sh[threadIdx.x]=s; sh2[threadIdx.x]=ss; __syncthreads();
  if (threadIdx.x < DP){
    #pragma unroll
    for (int i=1;i<G;i++){ s+=sh[threadIdx.x+i*DP]; ss+=sh2[threadIdx.x+i*DP]; }
    if (f<D){ atomicAdd(&gsum[f], s); atomicAdd(&gsumsq[f], ss); }
  }
}

__global__ void k_bn_out(float* __restrict__ h, const float* __restrict__ gsum,
    const float* __restrict__ gsumsq, const float* __restrict__ gamma,
    const float* __restrict__ beta){
  int gid = blockIdx.x*256+threadIdx.x;
  if (gid>=NN*OUTC) return;
  int f = gid % OUTC;
  const float invN = 1.0f/NN;
  float m = gsum[f]*invN;
  float var = gsumsq[f]*invN - m*m;
  float sc = rsqrtf(var+BN_EPS)*gamma[f];
  h[gid] = fmaxf((h[gid]-m)*sc + beta[f], 0.f);   // fused post-loop relu
}

// ---------------- final masked reduce ----------------
__global__ __launch_bounds__(256) void k_reduce(const float* __restrict__ xf,
    const int* __restrict__ verts, const float* __restrict__ mw,
    float* __restrict__ acc, int rpb){
  int c = threadIdx.x & 31, g = threadIdx.x >> 5;
  int r0 = blockIdx.x*rpb;
  int r1 = min(NN, r0+rpb);
  float s=0.f;
  for (int r=r0+g; r<r1; r+=8){
    float m = mw[verts[r]];
    if (c<OUTC) s += m * xf[(size_t)r*OUTC+c];
  }
  __shared__ float sh[256];
  sh[threadIdx.x]=s; __syncthreads();
  if (threadIdx.x<32){
    #pragma unroll
    for (int i=1;i<8;i++) s += sh[threadIdx.x + i*32];
    if (c<OUTC) atomicAdd(&acc[c], s);
  }
}

__global__ void k_final(const float* __restrict__ acc, const float* __restrict__ mb,
                        float* __restrict__ out){
  int c=threadIdx.x;
  if (c<OUTC) out[c] = sigm(acc[c]+mb[c]);
}

// ---------------- host ----------------
extern "C" void kernel_launch(void* const* d_in, const int* in_sizes, int n_in,
                              void* d_out, int out_size, void* d_ws, size_t ws_size,
                              hipStream_t stream){
  const int*   verts = (const int*)d_in[0];
  const int*   ei    = (const int*)d_in[1];
  const float* ew    = (const float*)d_in[2];
  const float* emb   = (const float*)d_in[3];
  const float* wh    = (const float*)d_in[4];
  // d_in[5] gcn_b_hidden, d_in[7] gcn_b_out: cancel exactly under batchnorm
  const float* w_out = (const float*)d_in[6];
  const float* bng_h = (const float*)d_in[8];
  const float* bnb_h = (const float*)d_in[9];
  const float* bng_o = (const float*)d_in[10];
  const float* bnb_o = (const float*)d_in[11];
  const float* tewl  = (const float*)d_in[12];
  const float* tewc  = (const float*)d_in[13];
  const float* teb   = (const float*)d_in[14];
  const float* maskw = (const float*)d_in[15];
  const float* maskb = (const float*)d_in[16];
  float* out = (float*)d_out;

  char* ws = (char*)d_ws;
  size_t off=0;
  auto alloc=[&](size_t bytes)->char*{ char* p = ws+off; off += (bytes+255)&~(size_t)255; return p; };
  int2*  sedge  = (int2*) alloc(sizeof(int2)*LE);         // 44.8 MB
  int*   offs   = (int*)  alloc(sizeof(int)*(LN+1));      // 1.4 MB
  int*   cnth   = (int*)  alloc(sizeof(int)*LN);          // 1.4 MB per-dst histogram
  int*   bsums  = (int*)  alloc(sizeof(int)*512);
  int*   bcnt   = (int*)  alloc(sizeof(int)*LBUK);
  int*   bbase  = (int*)  alloc(sizeof(int)*(LBUK+1));
  int*   bcur   = (int*)  alloc(sizeof(int)*LBUK);
  float* x      = (float*)alloc(sizeof(float)*NN*DIM);    // 25.6 MB
  float* bufB   = (float*)alloc(sizeof(float)*NN*DIM);    // 25.6 MB
  float* bufC   = (float*)alloc(sizeof(float)*NN*DIM);    // 25.6 MB
  float* stats  = (float*)alloc(sizeof(float)*(LL*256+32)); // per-layer gsum/gsumsq + racc
  float* racc   = stats + LL*256;
  // btmp (44.8 MB) aliases bufB+bufC (51.2 MB): preprocessing finishes before layers
  int2*  btmp   = (int2*)bufB;

  // --- two-level binned sort of all 7 edge lists by dst ---
  hipMemsetAsync(bcnt, 0, sizeof(int)*LBUK, stream);
  hipMemsetAsync(stats, 0, sizeof(float)*(LL*256+32), stream);
  k_bhist<<<384,256,0,stream>>>(ei, bcnt);
  k_bscan<<<1,1024,0,stream>>>(bcnt, bbase, bcur);
  k_bin<<<(LE+255)/256,256,0,stream>>>(ei, ew, bcur, btmp);
  k_chist<<<LBUK,256,0,stream>>>(btmp, bbase, cnth);
  int nsb = (LN+1023)/1024;  // 342
  k_scan1<<<nsb,256,0,stream>>>(cnth, offs, bsums, LN);
  k_scan2<<<1,512,0,stream>>>(bsums, nsb);
  k_scan3<<<(LN+255)/256,256,0,stream>>>(offs, bsums, LN);
  k_csort<<<LBUK,256,0,stream>>>(btmp, bbase, offs, sedge);
  k_gather_emb<<<NN*32/256,256,0,stream>>>(verts, emb, x);

  // --- 6 hidden layers ---
  for (int i=0;i<6;i++){
    int j = (i==0)?5:(i-1);   // (i-1) % 6, Python semantics
    float* gsum = stats + i*256, *gsumsq = gsum + 128;
    k_gemm128v<<<(NN+63)/64,256,0,stream>>>(x, wh + (size_t)i*DIM*DIM, bufB, NN);
    k_spmm128<<<NN/2,256,0,stream>>>(bufB, sedge, offs, bufC, i*NN);
    k_bn_stats<128><<<512,256,0,stream>>>(bufC, NN, DIM, gsum, gsumsq, 98);
    k_gemm128v<<<(NN+63)/64,256,0,stream>>>(x, tewl + (size_t)j*DIM*DIM, bufB, NN);
    k_gemm_gate<<<(NN+63)/64,256,0,stream>>>(bufC, tewc + (size_t)j*DIM*DIM, bufB,
        teb + (size_t)j*DIM, gsum, gsumsq,
        bng_h+(size_t)i*DIM, bnb_h+(size_t)i*DIM, x, NN);
  }

  // --- output layer ---
  float* gsum = stats + 6*256, *gsumsq = gsum + 128;
  k_gemm_out<<<(NN+7)/8,256,0,stream>>>(x, w_out, bufB, NN);
  k_spmm_out<<<NN/4,256,0,stream>>>(bufB, sedge, offs, bufC, 6*NN);
  k_bn_stats<32><<<512,256,0,stream>>>(bufC, NN, OUTC, gsum, gsumsq, 98);
  k_bn_out<<<(NN*OUTC+255)/256,256,0,stream>>>(bufC, gsum, gsumsq, bng_o, bnb_o);
  k_reduce<<<512,256,0,stream>>>(bufC, verts, maskw, racc, 98);
  k_final<<<1,64,0,stream>>>(racc, maskb, out);
}

// Round 4
// 2390.067 us; speedup vs baseline: 1.2692x; 1.2692x over previous
//
#include <hip/hip_runtime.h>

#define NN 50000
#define EE 800000
#define DIM 128
#define OUTC 20
#define LL 7
#define LE (LL*EE)
#define LN (LL*NN)
#define BN_EPS 1e-5f

static __device__ __forceinline__ float sigm(float z){ return 1.0f/(1.0f+expf(-z)); }

// ---------------- preprocessing: counting sort of all 7 edge lists by dst ----------------
__global__ void k_hist(const int* __restrict__ ei, int* __restrict__ cnt){
  int gid = blockIdx.x*256 + threadIdx.x;
  if (gid >= LE) return;
  int l = gid / EE;
  int e = gid - l*EE;
  int dst = ei[(2*l+1)*EE + e];
  atomicAdd(&cnt[l*NN + dst], 1);
}

__global__ void k_scan1(const int* __restrict__ cnt, int* __restrict__ offs,
                        int* __restrict__ bsums, int n){
  __shared__ int s[256];
  int t = threadIdx.x;
  int base = blockIdx.x*1024 + t*4;
  int v[4]; int sum = 0;
  #pragma unroll
  for (int i=0;i<4;i++){ v[i] = (base+i<n)? cnt[base+i] : 0; sum += v[i]; }
  s[t]=sum; __syncthreads();
  for (int off=1; off<256; off<<=1){
    int x = (t>=off)? s[t-off] : 0;
    __syncthreads();
    s[t] += x;
    __syncthreads();
  }
  if (t==255) bsums[blockIdx.x] = s[255];
  int run = s[t]-sum;
  #pragma unroll
  for (int i=0;i<4;i++){ if (base+i<n) offs[base+i]=run; run += v[i]; }
}

__global__ void k_scan2(int* bsums, int nb){
  __shared__ int s[512];
  int t=threadIdx.x;
  int v = (t<nb)? bsums[t]:0;
  s[t]=v; __syncthreads();
  for (int off=1; off<512; off<<=1){
    int x=(t>=off)? s[t-off]:0; __syncthreads(); s[t]+=x; __syncthreads();
  }
  if (t<nb) bsums[t] = s[t]-v;
}

__global__ void k_scan3(int* __restrict__ offs, const int* __restrict__ bsums,
                        int* __restrict__ cursor, int n){
  int gid = blockIdx.x*256+threadIdx.x;
  if (gid < n){
    int val = offs[gid] + bsums[gid>>10];
    offs[gid]=val; cursor[gid]=val;
  }
  if (gid==0) offs[n]=LE;
}

// per-layer packed scatter: write frontier = 50k cursors over 6.4 MB -> L2-resident,
// each 64B line collects all its edges before eviction (one writeback per line)
__global__ void k_scatter(const int* __restrict__ ei, const float* __restrict__ ew,
                          int* __restrict__ cursor, int2* __restrict__ sedge, int l){
  int e = blockIdx.x*256+threadIdx.x;
  if (e>=EE) return;
  int src = ei[(2*l)*EE + e];
  int dst = ei[(2*l+1)*EE + e];
  int pos = atomicAdd(&cursor[l*NN+dst], 1);
  sedge[pos] = make_int2(src, __float_as_int(ew[(size_t)l*EE + e]));
}

__global__ void k_gather_emb(const int* __restrict__ verts, const float* __restrict__ emb,
                             float* __restrict__ x){
  int gid = blockIdx.x*256+threadIdx.x;   // over NN*32 float4s
  int n = gid>>5, q = gid&31;
  if (n>=NN) return;
  int v = verts[n];
  ((float4*)x)[gid] = ((const float4*)emb)[(size_t)v*32+q];
}

// ---------------- GEMM: Y[M,128] = X[M,128] @ W[128,128] ----------------
#define XS_STRIDE 68
__global__ __launch_bounds__(256) void k_gemm128v(const float* __restrict__ X,
    const float* __restrict__ W, float* __restrict__ Y, int M){
  __shared__ float Xs[128*XS_STRIDE];     // 34 KB
  int tid = threadIdx.x;
  int row0 = blockIdx.x*64;
  #pragma unroll
  for (int it=0; it<8; it++){
    int idx = tid + it*256;
    int r = idx>>5, kq = idx&31;
    float4 v = make_float4(0.f,0.f,0.f,0.f);
    if (row0+r < M) v = ((const float4*)X)[(size_t)(row0+r)*32 + kq];
    Xs[(kq*4+0)*XS_STRIDE+r]=v.x; Xs[(kq*4+1)*XS_STRIDE+r]=v.y;
    Xs[(kq*4+2)*XS_STRIDE+r]=v.z; Xs[(kq*4+3)*XS_STRIDE+r]=v.w;
  }
  __syncthreads();
  int ty = tid>>4, tx = tid&15;           // rows ty*4..+3, cols tx*8..+7
  float acc[4][8];
  #pragma unroll
  for (int i=0;i<4;i++){
    #pragma unroll
    for (int j=0;j<8;j++) acc[i][j]=0.f;
  }
  const float* Wp = W + tx*8;
  #pragma unroll 4
  for (int k=0;k<128;k++){
    float4 xv = *(const float4*)&Xs[k*XS_STRIDE + ty*4];
    float4 w0 = *(const float4*)(Wp + k*128);
    float4 w1 = *(const float4*)(Wp + k*128 + 4);
    float xr[4] = {xv.x, xv.y, xv.z, xv.w};
    #pragma unroll
    for (int i=0;i<4;i++){
      acc[i][0]+=xr[i]*w0.x; acc[i][1]+=xr[i]*w0.y; acc[i][2]+=xr[i]*w0.z; acc[i][3]+=xr[i]*w0.w;
      acc[i][4]+=xr[i]*w1.x; acc[i][5]+=xr[i]*w1.y; acc[i][6]+=xr[i]*w1.z; acc[i][7]+=xr[i]*w1.w;
    }
  }
  #pragma unroll
  for (int i=0;i<4;i++){
    int r = row0 + ty*4 + i;
    if (r<M){
      float* yp = Y + (size_t)r*128 + tx*8;
      *(float4*)yp     = make_float4(acc[i][0],acc[i][1],acc[i][2],acc[i][3]);
      *(float4*)(yp+4) = make_float4(acc[i][4],acc[i][5],acc[i][6],acc[i][7]);
    }
  }
}

// ---------------- fused: BN(h)+ReLU during staging, GEMM (hn @ te_wc), gate epilogue ----------------
__global__ __launch_bounds__(256) void k_gemm_gate(const float* __restrict__ H,
    const float* __restrict__ W, const float* __restrict__ D,
    const float* __restrict__ teb,
    const float* __restrict__ gsum, const float* __restrict__ gsumsq,
    const float* __restrict__ gamma, const float* __restrict__ beta,
    float* __restrict__ x, int M){
  __shared__ float Xs[128*XS_STRIDE];
  int tid = threadIdx.x;
  int row0 = blockIdx.x*64;
  const float invN = 1.0f/NN;
  #pragma unroll
  for (int it=0; it<8; it++){
    int idx = tid + it*256;
    int r = idx>>5, kq = idx&31;
    float4 v = make_float4(0.f,0.f,0.f,0.f);
    if (row0+r < M) v = ((const float4*)H)[(size_t)(row0+r)*32 + kq];
    float4 s  = ((const float4*)gsum)[kq];
    float4 sq = ((const float4*)gsumsq)[kq];
    float4 ga = ((const float4*)gamma)[kq];
    float4 be = ((const float4*)beta)[kq];
    float m, var, sc;
    m=s.x*invN; var=sq.x*invN-m*m; sc=rsqrtf(var+BN_EPS)*ga.x; v.x=fmaxf((v.x-m)*sc+be.x,0.f);
    m=s.y*invN; var=sq.y*invN-m*m; sc=rsqrtf(var+BN_EPS)*ga.y; v.y=fmaxf((v.y-m)*sc+be.y,0.f);
    m=s.z*invN; var=sq.z*invN-m*m; sc=rsqrtf(var+BN_EPS)*ga.z; v.z=fmaxf((v.z-m)*sc+be.z,0.f);
    m=s.w*invN; var=sq.w*invN-m*m; sc=rsqrtf(var+BN_EPS)*ga.w; v.w=fmaxf((v.w-m)*sc+be.w,0.f);
    Xs[(kq*4+0)*XS_STRIDE+r]=v.x; Xs[(kq*4+1)*XS_STRIDE+r]=v.y;
    Xs[(kq*4+2)*XS_STRIDE+r]=v.z; Xs[(kq*4+3)*XS_STRIDE+r]=v.w;
  }
  __syncthreads();
  int ty = tid>>4, tx = tid&15;
  float acc[4][8];
  #pragma unroll
  for (int i=0;i<4;i++){
    #pragma unroll
    for (int j=0;j<8;j++) acc[i][j]=0.f;
  }
  const float* Wp = W + tx*8;
  #pragma unroll 4
  for (int k=0;k<128;k++){
    float4 xv = *(const float4*)&Xs[k*XS_STRIDE + ty*4];
    float4 w0 = *(const float4*)(Wp + k*128);
    float4 w1 = *(const float4*)(Wp + k*128 + 4);
    float xr[4] = {xv.x, xv.y, xv.z, xv.w};
    #pragma unroll
    for (int i=0;i<4;i++){
      acc[i][0]+=xr[i]*w0.x; acc[i][1]+=xr[i]*w0.y; acc[i][2]+=xr[i]*w0.z; acc[i][3]+=xr[i]*w0.w;
      acc[i][4]+=xr[i]*w1.x; acc[i][5]+=xr[i]*w1.y; acc[i][6]+=xr[i]*w1.z; acc[i][7]+=xr[i]*w1.w;
    }
  }
  float4 b0 = ((const float4*)teb)[tx*2];
  float4 b1 = ((const float4*)teb)[tx*2+1];
  float hcol[8][4];     // hcol[j][i] = hn[row ty*4+i][col tx*8+j]
  #pragma unroll
  for (int j=0;j<8;j++){
    float4 hv = *(const float4*)&Xs[(tx*8+j)*XS_STRIDE + ty*4];
    hcol[j][0]=hv.x; hcol[j][1]=hv.y; hcol[j][2]=hv.z; hcol[j][3]=hv.w;
  }
  #pragma unroll
  for (int i=0;i<4;i++){
    int r = row0 + ty*4 + i;
    if (r<M){
      const float* dp = D + (size_t)r*128 + tx*8;
      float* xp = x + (size_t)r*128 + tx*8;
      float4 d0 = *(const float4*)dp, d1 = *(const float4*)(dp+4);
      float4 xo0 = *(const float4*)xp, xo1 = *(const float4*)(xp+4);
      float g;
      float4 n0, n1;
      g=sigm(acc[i][0]+d0.x+b0.x); n0.x = g*hcol[0][i] + (1.f-g)*xo0.x;
      g=sigm(acc[i][1]+d0.y+b0.y); n0.y = g*hcol[1][i] + (1.f-g)*xo0.y;
      g=sigm(acc[i][2]+d0.z+b0.z); n0.z = g*hcol[2][i] + (1.f-g)*xo0.z;
      g=sigm(acc[i][3]+d0.w+b0.w); n0.w = g*hcol[3][i] + (1.f-g)*xo0.w;
      g=sigm(acc[i][4]+d1.x+b1.x); n1.x = g*hcol[4][i] + (1.f-g)*xo1.x;
      g=sigm(acc[i][5]+d1.y+b1.y); n1.y = g*hcol[5][i] + (1.f-g)*xo1.y;
      g=sigm(acc[i][6]+d1.z+b1.z); n1.z = g*hcol[6][i] + (1.f-g)*xo1.z;
      g=sigm(acc[i][7]+d1.w+b1.w); n1.w = g*hcol[7][i] + (1.f-g)*xo1.w;
      *(float4*)xp = n0; *(float4*)(xp+4) = n1;
    }
  }
}

// ---------------- Y[M,20] = X[M,128] @ W[128,20] ----------------
__global__ __launch_bounds__(256) void k_gemm_out(const float* __restrict__ X,
    const float* __restrict__ W, float* __restrict__ Y, int M){
  __shared__ float Ws[DIM*OUTC];
  __shared__ float Xs2[8*DIM];
  int tid=threadIdx.x;
  for (int i=tid;i<DIM*OUTC;i+=256) Ws[i]=W[i];
  int row0=blockIdx.x*8;
  {
    int r = tid>>5, kq = tid&31;
    float4 v = make_float4(0.f,0.f,0.f,0.f);
    if (row0+r<M) v = ((const float4*)X)[(size_t)(row0+r)*32+kq];
    *(float4*)&Xs2[r*DIM+kq*4]=v;
  }
  __syncthreads();
  int c = tid&31, rl=tid>>5;
  if (c<OUTC && row0+rl<M){
    float acc=0.f;
    #pragma unroll 8
    for (int k=0;k<DIM;k++) acc += Xs2[rl*DIM+k]*Ws[k*OUTC+c];
    Y[(size_t)(row0+rl)*OUTC+c]=acc;
  }
}

// ---------------- SpMM gather: h[n] = sum_e w_e * sup[src_e] ----------------
__global__ __launch_bounds__(256) void k_spmm128(const float* __restrict__ sup,
    const int2* __restrict__ sedge, const int* __restrict__ offs,
    float* __restrict__ h, int base){
  int node = blockIdx.x*2 + (threadIdx.x>>7);
  int f = threadIdx.x & 127;
  int beg = offs[base+node], end = offs[base+node+1];
  float acc=0.f, acc2=0.f;
  int p=beg;
  for (; p+1<end; p+=2){
    int2 e0 = sedge[p], e1 = sedge[p+1];
    acc  += __int_as_float(e0.y) * sup[(size_t)e0.x*DIM + f];
    acc2 += __int_as_float(e1.y) * sup[(size_t)e1.x*DIM + f];
  }
  if (p<end){
    int2 e0 = sedge[p];
    acc += __int_as_float(e0.y) * sup[(size_t)e0.x*DIM + f];
  }
  h[(size_t)node*DIM+f]=acc+acc2;
}

__global__ __launch_bounds__(256) void k_spmm_out(const float* __restrict__ sup,
    const int2* __restrict__ sedge, const int* __restrict__ offs,
    float* __restrict__ h, int base){
  int node = blockIdx.x*4 + (threadIdx.x>>6);
  int f = threadIdx.x & 63;
  if (f >= OUTC) return;
  int beg=offs[base+node], end=offs[base+node+1];
  float acc=0.f;
  for (int p=beg;p<end;p++){
    int2 e = sedge[p];
    acc += __int_as_float(e.y)*sup[(size_t)e.x*OUTC+f];
  }
  h[(size_t)node*OUTC+f]=acc;
}

// ---------------- BatchNorm stats ----------------
template<int DP>
__global__ __launch_bounds__(256) void k_bn_stats(const float* __restrict__ h,
    int M, int D, float* __restrict__ gsum, float* __restrict__ gsumsq, int rpb){
  const int G = 256/DP;
  int f = threadIdx.x % DP;
  int g = threadIdx.x / DP;
  float s=0.f, ss=0.f;
  int r0 = blockIdx.x*rpb;
  int r1 = min(M, r0+rpb);
  if (f < D){
    for (int r=r0+g; r<r1; r+=G){ float v = h[(size_t)r*D+f]; s+=v; ss+=v*v; }
  }
  __shared__ float sh[256], sh2[256];
  sh[threadIdx.x]=s; sh2[threadIdx.x]=ss; __syncthreads();
  if (threadIdx.x < DP){
    #pragma unroll
    for (int i=1;i<G;i++){ s+=sh[threadIdx.x+i*DP]; ss+=sh2[threadIdx.x+i*DP]; }
    if (f<D){ atomicAdd(&gsum[f], s); atomicAdd(&gsumsq[f], ss); }
  }
}

__global__ void k_bn_out(float* __restrict__ h, const float* __restrict__ gsum,
    const float* __restrict__ gsumsq, const float* __restrict__ gamma,
    const float* __restrict__ beta){
  int gid = blockIdx.x*256+threadIdx.x;
  if (gid>=NN*OUTC) return;
  int f = gid % OUTC;
  const float invN = 1.0f/NN;
  float m = gsum[f]*invN;
  float var = gsumsq[f]*invN - m*m;
  float sc = rsqrtf(var+BN_EPS)*gamma[f];
  h[gid] = fmaxf((h[gid]-m)*sc + beta[f], 0.f);   // fused post-loop relu
}

// ---------------- final masked reduce ----------------
__global__ __launch_bounds__(256) void k_reduce(const float* __restrict__ xf,
    const int* __restrict__ verts, const float* __restrict__ mw,
    float* __restrict__ acc, int rpb){
  int c = threadIdx.x & 31, g = threadIdx.x >> 5;
  int r0 = blockIdx.x*rpb;
  int r1 = min(NN, r0+rpb);
  float s=0.f;
  for (int r=r0+g; r<r1; r+=8){
    float m = mw[verts[r]];
    if (c<OUTC) s += m * xf[(size_t)r*OUTC+c];
  }
  __shared__ float sh[256];
  sh[threadIdx.x]=s; __syncthreads();
  if (threadIdx.x<32){
    #pragma unroll
    for (int i=1;i<8;i++) s += sh[threadIdx.x + i*32];
    if (c<OUTC) atomicAdd(&acc[c], s);
  }
}

__global__ void k_final(const float* __restrict__ acc, const float* __restrict__ mb,
                        float* __restrict__ out){
  int c=threadIdx.x;
  if (c<OUTC) out[c] = sigm(acc[c]+mb[c]);
}

// ---------------- host ----------------
extern "C" void kernel_launch(void* const* d_in, const int* in_sizes, int n_in,
                              void* d_out, int out_size, void* d_ws, size_t ws_size,
                              hipStream_t stream){
  const int*   verts = (const int*)d_in[0];
  const int*   ei    = (const int*)d_in[1];
  const float* ew    = (const float*)d_in[2];
  const float* emb   = (const float*)d_in[3];
  const float* wh    = (const float*)d_in[4];
  // d_in[5] gcn_b_hidden, d_in[7] gcn_b_out: cancel exactly under batchnorm
  const float* w_out = (const float*)d_in[6];
  const float* bng_h = (const float*)d_in[8];
  const float* bnb_h = (const float*)d_in[9];
  const float* bng_o = (const float*)d_in[10];
  const float* bnb_o = (const float*)d_in[11];
  const float* tewl  = (const float*)d_in[12];
  const float* tewc  = (const float*)d_in[13];
  const float* teb   = (const float*)d_in[14];
  const float* maskw = (const float*)d_in[15];
  const float* maskb = (const float*)d_in[16];
  float* out = (float*)d_out;

  char* ws = (char*)d_ws;
  size_t off=0;
  auto alloc=[&](size_t bytes)->char*{ char* p = ws+off; off += (bytes+255)&~(size_t)255; return p; };
  int2*  sedge  = (int2*) alloc(sizeof(int2)*LE);         // 44.8 MB
  int*   offs   = (int*)  alloc(sizeof(int)*(LN+1));      // 1.4 MB
  int*   cursor = (int*)  alloc(sizeof(int)*LN);          // 1.4 MB (doubles as hist counts)
  int*   bsums  = (int*)  alloc(sizeof(int)*512);
  float* x      = (float*)alloc(sizeof(float)*NN*DIM);    // 25.6 MB
  float* bufB   = (float*)alloc(sizeof(float)*NN*DIM);    // 25.6 MB
  float* bufC   = (float*)alloc(sizeof(float)*NN*DIM);    // 25.6 MB
  float* stats  = (float*)alloc(sizeof(float)*(LL*256+32)); // per-layer gsum/gsumsq + racc
  float* racc   = stats + LL*256;

  // --- sort all 7 edge lists by dst; scatter per layer for L2-resident frontier ---
  hipMemsetAsync(cursor, 0, sizeof(int)*LN, stream);
  hipMemsetAsync(stats, 0, sizeof(float)*(LL*256+32), stream);
  k_hist<<<(LE+255)/256,256,0,stream>>>(ei, cursor);
  int nsb = (LN+1023)/1024;  // 342
  k_scan1<<<nsb,256,0,stream>>>(cursor, offs, bsums, LN);
  k_scan2<<<1,512,0,stream>>>(bsums, nsb);
  k_scan3<<<(LN+255)/256,256,0,stream>>>(offs, bsums, cursor, LN);
  for (int l=0;l<LL;l++)
    k_scatter<<<(EE+255)/256,256,0,stream>>>(ei, ew, cursor, sedge, l);
  k_gather_emb<<<NN*32/256,256,0,stream>>>(verts, emb, x);

  // --- 6 hidden layers ---
  for (int i=0;i<6;i++){
    int j = (i==0)?5:(i-1);   // (i-1) % 6, Python semantics
    float* gsum = stats + i*256, *gsumsq = gsum + 128;
    k_gemm128v<<<(NN+63)/64,256,0,stream>>>(x, wh + (size_t)i*DIM*DIM, bufB, NN);
    k_spmm128<<<NN/2,256,0,stream>>>(bufB, sedge, offs, bufC, i*NN);
    k_bn_stats<128><<<512,256,0,stream>>>(bufC, NN, DIM, gsum, gsumsq, 98);
    k_gemm128v<<<(NN+63)/64,256,0,stream>>>(x, tewl + (size_t)j*DIM*DIM, bufB, NN);
    k_gemm_gate<<<(NN+63)/64,256,0,stream>>>(bufC, tewc + (size_t)j*DIM*DIM, bufB,
        teb + (size_t)j*DIM, gsum, gsumsq,
        bng_h+(size_t)i*DIM, bnb_h+(size_t)i*DIM, x, NN);
  }

  // --- output layer ---
  float* gsum = stats + 6*256, *gsumsq = gsum + 128;
  k_gemm_out<<<(NN+7)/8,256,0,stream>>>(x, w_out, bufB, NN);
  k_spmm_out<<<NN/4,256,0,stream>>>(bufB, sedge, offs, bufC, 6*NN);
  k_bn_stats<32><<<512,256,0,stream>>>(bufC, NN, OUTC, gsum, gsumsq, 98);
  k_bn_out<<<(NN*OUTC+255)/256,256,0,stream>>>(bufC, gsum, gsumsq, bng_o, bnb_o);
  k_reduce<<<512,256,0,stream>>>(bufC, verts, maskw, racc, 98);
  k_final<<<1,64,0,stream>>>(racc, maskb, out);
}

// Round 5
// 2132.964 us; speedup vs baseline: 1.4222x; 1.1205x over previous
//
#include <hip/hip_runtime.h>

#define NN 50000
#define EE 800000
#define DIM 128
#define OUTC 20
#define LL 7
#define LE (LL*EE)
#define LN (LL*NN)
#define N8 (8*LN)             // 8 block-groups ("~XCDs") per layer
#define BN_EPS 1e-5f

static __device__ __forceinline__ float sigm(float z){ return 1.0f/(1.0f+expf(-z)); }
static __device__ __forceinline__ float4 f4fma(float w, float4 v, float4 a){
  a.x += w*v.x; a.y += w*v.y; a.z += w*v.z; a.w += w*v.w; return a;
}

// ======== preprocessing: counting sort by (layer, blockgroup, dst) ========
// g = blockIdx.x & 7 approximates the XCD (round-robin dispatch) -> counter/cursor
// lines are touched by one XCD only (no cross-XCD L2 bouncing), and g is a pure
// function of blockIdx so hist and scatter see the identical mapping (G16-safe).

__global__ __launch_bounds__(256) void k_hist8(const int* __restrict__ ei,
    int* __restrict__ cnt8, int l){
  int e = blockIdx.x*256 + threadIdx.x;
  if (e>=EE) return;
  int g = blockIdx.x & 7;
  int dst = ei[(2*l+1)*EE + e];
  atomicAdd(&cnt8[(l*8+g)*NN + dst], 1);
}

// exclusive scan over N8=2.8M counts: 4096/block -> 684 block sums -> scan -> add
__global__ __launch_bounds__(256) void k_scan1(const int* __restrict__ cnt,
    int* __restrict__ offs, int* __restrict__ bsums, int n){
  __shared__ int s[256];
  int t = threadIdx.x;
  int base = blockIdx.x*4096 + t*16;
  int v[16]; int sum = 0;
  #pragma unroll
  for (int i=0;i<16;i++){ v[i] = (base+i<n)? cnt[base+i] : 0; sum += v[i]; }
  s[t]=sum; __syncthreads();
  for (int off=1; off<256; off<<=1){
    int x = (t>=off)? s[t-off] : 0;
    __syncthreads(); s[t] += x; __syncthreads();
  }
  if (t==255) bsums[blockIdx.x] = s[255];
  int run = s[t]-sum;
  #pragma unroll
  for (int i=0;i<16;i++){ if (base+i<n) offs[base+i]=run; run += v[i]; }
}

__global__ __launch_bounds__(1024) void k_scan2(int* bsums, int nb){
  __shared__ int s[1024];
  int t=threadIdx.x;
  int v = (t<nb)? bsums[t]:0;
  s[t]=v; __syncthreads();
  for (int off=1; off<1024; off<<=1){
    int x=(t>=off)? s[t-off]:0; __syncthreads(); s[t]+=x; __syncthreads();
  }
  if (t<nb) bsums[t] = s[t]-v;
}

__global__ void k_scan3(int* __restrict__ offs, const int* __restrict__ bsums,
                        int* __restrict__ cur, int n){
  int gid = blockIdx.x*256+threadIdx.x;
  if (gid < n){
    int val = offs[gid] + bsums[gid>>12];
    offs[gid]=val; cur[gid]=val;
  }
  if (gid==0) offs[n]=LE;
}

__global__ __launch_bounds__(256) void k_scatter8(const int* __restrict__ ei,
    const float* __restrict__ ew, int* __restrict__ cur8,
    int2* __restrict__ sedge, int l){
  int e = blockIdx.x*256 + threadIdx.x;
  if (e>=EE) return;
  int g = blockIdx.x & 7;
  int src = ei[(2*l)*EE + e];
  int dst = ei[(2*l+1)*EE + e];
  int pos = atomicAdd(&cur8[(l*8+g)*NN + dst], 1);
  sedge[pos] = make_int2(src, __float_as_int(ew[(size_t)l*EE + e]));
}

__global__ void k_gather_emb(const int* __restrict__ verts, const float* __restrict__ emb,
                             float* __restrict__ x){
  int gid = blockIdx.x*256+threadIdx.x;   // over NN*32 float4s
  int n = gid>>5, q = gid&31;
  if (n>=NN) return;
  int v = verts[n];
  ((float4*)x)[gid] = ((const float4*)emb)[(size_t)v*32+q];
}

// ---------------- GEMM: Y[M,128] = X[M,128] @ W[128,128] ----------------
#define XS_STRIDE 68
__global__ __launch_bounds__(256) void k_gemm128v(const float* __restrict__ X,
    const float* __restrict__ W, float* __restrict__ Y, int M){
  __shared__ float Xs[128*XS_STRIDE];     // 34 KB
  int tid = threadIdx.x;
  int row0 = blockIdx.x*64;
  #pragma unroll
  for (int it=0; it<8; it++){
    int idx = tid + it*256;
    int r = idx>>5, kq = idx&31;
    float4 v = make_float4(0.f,0.f,0.f,0.f);
    if (row0+r < M) v = ((const float4*)X)[(size_t)(row0+r)*32 + kq];
    Xs[(kq*4+0)*XS_STRIDE+r]=v.x; Xs[(kq*4+1)*XS_STRIDE+r]=v.y;
    Xs[(kq*4+2)*XS_STRIDE+r]=v.z; Xs[(kq*4+3)*XS_STRIDE+r]=v.w;
  }
  __syncthreads();
  int ty = tid>>4, tx = tid&15;           // rows ty*4..+3, cols tx*8..+7
  float acc[4][8];
  #pragma unroll
  for (int i=0;i<4;i++){
    #pragma unroll
    for (int j=0;j<8;j++) acc[i][j]=0.f;
  }
  const float* Wp = W + tx*8;
  #pragma unroll 4
  for (int k=0;k<128;k++){
    float4 xv = *(const float4*)&Xs[k*XS_STRIDE + ty*4];
    float4 w0 = *(const float4*)(Wp + k*128);
    float4 w1 = *(const float4*)(Wp + k*128 + 4);
    float xr[4] = {xv.x, xv.y, xv.z, xv.w};
    #pragma unroll
    for (int i=0;i<4;i++){
      acc[i][0]+=xr[i]*w0.x; acc[i][1]+=xr[i]*w0.y; acc[i][2]+=xr[i]*w0.z; acc[i][3]+=xr[i]*w0.w;
      acc[i][4]+=xr[i]*w1.x; acc[i][5]+=xr[i]*w1.y; acc[i][6]+=xr[i]*w1.z; acc[i][7]+=xr[i]*w1.w;
    }
  }
  #pragma unroll
  for (int i=0;i<4;i++){
    int r = row0 + ty*4 + i;
    if (r<M){
      float* yp = Y + (size_t)r*128 + tx*8;
      *(float4*)yp     = make_float4(acc[i][0],acc[i][1],acc[i][2],acc[i][3]);
      *(float4*)(yp+4) = make_float4(acc[i][4],acc[i][5],acc[i][6],acc[i][7]);
    }
  }
}

// ---------------- fused: BN(h)+ReLU during staging, GEMM (hn @ te_wc), gate epilogue ----------------
__global__ __launch_bounds__(256) void k_gemm_gate(const float* __restrict__ H,
    const float* __restrict__ W, const float* __restrict__ D,
    const float* __restrict__ teb,
    const float* __restrict__ gsum, const float* __restrict__ gsumsq,
    const float* __restrict__ gamma, const float* __restrict__ beta,
    float* __restrict__ x, int M){
  __shared__ float Xs[128*XS_STRIDE];
  int tid = threadIdx.x;
  int row0 = blockIdx.x*64;
  const float invN = 1.0f/NN;
  #pragma unroll
  for (int it=0; it<8; it++){
    int idx = tid + it*256;
    int r = idx>>5, kq = idx&31;
    float4 v = make_float4(0.f,0.f,0.f,0.f);
    if (row0+r < M) v = ((const float4*)H)[(size_t)(row0+r)*32 + kq];
    float4 s  = ((const float4*)gsum)[kq];
    float4 sq = ((const float4*)gsumsq)[kq];
    float4 ga = ((const float4*)gamma)[kq];
    float4 be = ((const float4*)beta)[kq];
    float m, var, sc;
    m=s.x*invN; var=sq.x*invN-m*m; sc=rsqrtf(var+BN_EPS)*ga.x; v.x=fmaxf((v.x-m)*sc+be.x,0.f);
    m=s.y*invN; var=sq.y*invN-m*m; sc=rsqrtf(var+BN_EPS)*ga.y; v.y=fmaxf((v.y-m)*sc+be.y,0.f);
    m=s.z*invN; var=sq.z*invN-m*m; sc=rsqrtf(var+BN_EPS)*ga.z; v.z=fmaxf((v.z-m)*sc+be.z,0.f);
    m=s.w*invN; var=sq.w*invN-m*m; sc=rsqrtf(var+BN_EPS)*ga.w; v.w=fmaxf((v.w-m)*sc+be.w,0.f);
    Xs[(kq*4+0)*XS_STRIDE+r]=v.x; Xs[(kq*4+1)*XS_STRIDE+r]=v.y;
    Xs[(kq*4+2)*XS_STRIDE+r]=v.z; Xs[(kq*4+3)*XS_STRIDE+r]=v.w;
  }
  __syncthreads();
  int ty = tid>>4, tx = tid&15;
  float acc[4][8];
  #pragma unroll
  for (int i=0;i<4;i++){
    #pragma unroll
    for (int j=0;j<8;j++) acc[i][j]=0.f;
  }
  const float* Wp = W + tx*8;
  #pragma unroll 4
  for (int k=0;k<128;k++){
    float4 xv = *(const float4*)&Xs[k*XS_STRIDE + ty*4];
    float4 w0 = *(const float4*)(Wp + k*128);
    float4 w1 = *(const float4*)(Wp + k*128 + 4);
    float xr[4] = {xv.x, xv.y, xv.z, xv.w};
    #pragma unroll
    for (int i=0;i<4;i++){
      acc[i][0]+=xr[i]*w0.x; acc[i][1]+=xr[i]*w0.y; acc[i][2]+=xr[i]*w0.z; acc[i][3]+=xr[i]*w0.w;
      acc[i][4]+=xr[i]*w1.x; acc[i][5]+=xr[i]*w1.y; acc[i][6]+=xr[i]*w1.z; acc[i][7]+=xr[i]*w1.w;
    }
  }
  float4 b0 = ((const float4*)teb)[tx*2];
  float4 b1 = ((const float4*)teb)[tx*2+1];
  float hcol[8][4];     // hcol[j][i] = hn[row ty*4+i][col tx*8+j]
  #pragma unroll
  for (int j=0;j<8;j++){
    float4 hv = *(const float4*)&Xs[(tx*8+j)*XS_STRIDE + ty*4];
    hcol[j][0]=hv.x; hcol[j][1]=hv.y; hcol[j][2]=hv.z; hcol[j][3]=hv.w;
  }
  #pragma unroll
  for (int i=0;i<4;i++){
    int r = row0 + ty*4 + i;
    if (r<M){
      const float* dp = D + (size_t)r*128 + tx*8;
      float* xp = x + (size_t)r*128 + tx*8;
      float4 d0 = *(const float4*)dp, d1 = *(const float4*)(dp+4);
      float4 xo0 = *(const float4*)xp, xo1 = *(const float4*)(xp+4);
      float g;
      float4 n0, n1;
      g=sigm(acc[i][0]+d0.x+b0.x); n0.x = g*hcol[0][i] + (1.f-g)*xo0.x;
      g=sigm(acc[i][1]+d0.y+b0.y); n0.y = g*hcol[1][i] + (1.f-g)*xo0.y;
      g=sigm(acc[i][2]+d0.z+b0.z); n0.z = g*hcol[2][i] + (1.f-g)*xo0.z;
      g=sigm(acc[i][3]+d0.w+b0.w); n0.w = g*hcol[3][i] + (1.f-g)*xo0.w;
      g=sigm(acc[i][4]+d1.x+b1.x); n1.x = g*hcol[4][i] + (1.f-g)*xo1.x;
      g=sigm(acc[i][5]+d1.y+b1.y); n1.y = g*hcol[5][i] + (1.f-g)*xo1.y;
      g=sigm(acc[i][6]+d1.z+b1.z); n1.z = g*hcol[6][i] + (1.f-g)*xo1.z;
      g=sigm(acc[i][7]+d1.w+b1.w); n1.w = g*hcol[7][i] + (1.f-g)*xo1.w;
      *(float4*)xp = n0; *(float4*)(xp+4) = n1;
    }
  }
}

// ---------------- Y[M,20] = X[M,128] @ W[128,20] ----------------
__global__ __launch_bounds__(256) void k_gemm_out(const float* __restrict__ X,
    const float* __restrict__ W, float* __restrict__ Y, int M){
  __shared__ float Ws[DIM*OUTC];
  __shared__ float Xs2[8*DIM];
  int tid=threadIdx.x;
  for (int i=tid;i<DIM*OUTC;i+=256) Ws[i]=W[i];
  int row0=blockIdx.x*8;
  {
    int r = tid>>5, kq = tid&31;
    float4 v = make_float4(0.f,0.f,0.f,0.f);
    if (row0+r<M) v = ((const float4*)X)[(size_t)(row0+r)*32+kq];
    *(float4*)&Xs2[r*DIM+kq*4]=v;
  }
  __syncthreads();
  int c = tid&31, rl=tid>>5;
  if (c<OUTC && row0+rl<M){
    float acc=0.f;
    #pragma unroll 8
    for (int k=0;k<DIM;k++) acc += Xs2[rl*DIM+k]*Ws[k*OUTC+c];
    Y[(size_t)(row0+rl)*OUTC+c]=acc;
  }
}

// ---------------- SpMM gather (8 subsegments per node), float4 ----------------
__global__ __launch_bounds__(256) void k_spmm128(const float* __restrict__ sup,
    const int2* __restrict__ sedge, const int* __restrict__ offs8,
    float* __restrict__ h, int base8){   // base8 = l*8*NN
  int node = blockIdx.x*8 + (threadIdx.x>>5);
  int fq = threadIdx.x & 31;
  const float4* sup4 = (const float4*)sup;
  float4 a0 = make_float4(0.f,0.f,0.f,0.f), a1 = make_float4(0.f,0.f,0.f,0.f);
  #pragma unroll
  for (int g=0; g<8; g++){
    int idx = base8 + g*NN + node;
    int p = offs8[idx], end = offs8[idx+1];
    for (; p+1<end; p+=2){
      int2 e0 = sedge[p], e1 = sedge[p+1];
      a0 = f4fma(__int_as_float(e0.y), sup4[(size_t)e0.x*32+fq], a0);
      a1 = f4fma(__int_as_float(e1.y), sup4[(size_t)e1.x*32+fq], a1);
    }
    if (p<end){
      int2 e0 = sedge[p];
      a0 = f4fma(__int_as_float(e0.y), sup4[(size_t)e0.x*32+fq], a0);
    }
  }
  a0.x+=a1.x; a0.y+=a1.y; a0.z+=a1.z; a0.w+=a1.w;
  ((float4*)h)[(size_t)node*32+fq] = a0;
}

__global__ __launch_bounds__(256) void k_spmm_out(const float* __restrict__ sup,
    const int2* __restrict__ sedge, const int* __restrict__ offs8,
    float* __restrict__ h, int base8){
  int node = blockIdx.x*8 + (threadIdx.x>>5);
  int c = threadIdx.x & 31;
  float acc=0.f;
  #pragma unroll
  for (int g=0; g<8; g++){
    int idx = base8 + g*NN + node;
    int p = offs8[idx], end = offs8[idx+1];
    for (; p<end; p++){
      int2 e = sedge[p];
      if (c<OUTC) acc += __int_as_float(e.y)*sup[(size_t)e.x*OUTC+c];
    }
  }
  if (c<OUTC) h[(size_t)node*OUTC+c]=acc;
}

// ---------------- BatchNorm stats ----------------
template<int DP>
__global__ __launch_bounds__(256) void k_bn_stats(const float* __restrict__ h,
    int M, int D, float* __restrict__ gsum, float* __restrict__ gsumsq, int rpb){
  const int G = 256/DP;
  int f = threadIdx.x % DP;
  int g = threadIdx.x / DP;
  float s=0.f, ss=0.f;
  int r0 = blockIdx.x*rpb;
  int r1 = min(M, r0+rpb);
  if (f < D){
    for (int r=r0+g; r<r1; r+=G){ float v = h[(size_t)r*D+f]; s+=v; ss+=v*v; }
  }
  __shared__ float sh[256], sh2[256];
  sh[threadIdx.x]=s; sh2[threadIdx.x]=ss; __syncthreads();
  if (threadIdx.x < DP){
    #pragma unroll
    for (int i=1;i<G;i++){ s+=sh[threadIdx.x+i*DP]; ss+=sh2[threadIdx.x+i*DP]; }
    if (f<D){ atomicAdd(&gsum[f], s); atomicAdd(&gsumsq[f], ss); }
  }
}

__global__ void k_bn_out(float* __restrict__ h, const float* __restrict__ gsum,
    const float* __restrict__ gsumsq, const float* __restrict__ gamma,
    const float* __restrict__ beta){
  int gid = blockIdx.x*256+threadIdx.x;
  if (gid>=NN*OUTC) return;
  int f = gid % OUTC;
  const float invN = 1.0f/NN;
  float m = gsum[f]*invN;
  float var = gsumsq[f]*invN - m*m;
  float sc = rsqrtf(var+BN_EPS)*gamma[f];
  h[gid] = fmaxf((h[gid]-m)*sc + beta[f], 0.f);   // fused post-loop relu
}

// ---------------- final masked reduce ----------------
__global__ __launch_bounds__(256) void k_reduce(const float* __restrict__ xf,
    const int* __restrict__ verts, const float* __restrict__ mw,
    float* __restrict__ acc, int rpb){
  int c = threadIdx.x & 31, g = threadIdx.x >> 5;
  int r0 = blockIdx.x*rpb;
  int r1 = min(NN, r0+rpb);
  float s=0.f;
  for (int r=r0+g; r<r1; r+=8){
    float m = mw[verts[r]];
    if (c<OUTC) s += m * xf[(size_t)r*OUTC+c];
  }
  __shared__ float sh[256];
  sh[threadIdx.x]=s; __syncthreads();
  if (threadIdx.x<32){
    #pragma unroll
    for (int i=1;i<8;i++) s += sh[threadIdx.x + i*32];
    if (c<OUTC) atomicAdd(&acc[c], s);
  }
}

__global__ void k_final(const float* __restrict__ acc, const float* __restrict__ mb,
                        float* __restrict__ out){
  int c=threadIdx.x;
  if (c<OUTC) out[c] = sigm(acc[c]+mb[c]);
}

// ---------------- host ----------------
extern "C" void kernel_launch(void* const* d_in, const int* in_sizes, int n_in,
                              void* d_out, int out_size, void* d_ws, size_t ws_size,
                              hipStream_t stream){
  const int*   verts = (const int*)d_in[0];
  const int*   ei    = (const int*)d_in[1];
  const float* ew    = (const float*)d_in[2];
  const float* emb   = (const float*)d_in[3];
  const float* wh    = (const float*)d_in[4];
  // d_in[5] gcn_b_hidden, d_in[7] gcn_b_out: cancel exactly under batchnorm
  const float* w_out = (const float*)d_in[6];
  const float* bng_h = (const float*)d_in[8];
  const float* bnb_h = (const float*)d_in[9];
  const float* bng_o = (const float*)d_in[10];
  const float* bnb_o = (const float*)d_in[11];
  const float* tewl  = (const float*)d_in[12];
  const float* tewc  = (const float*)d_in[13];
  const float* teb   = (const float*)d_in[14];
  const float* maskw = (const float*)d_in[15];
  const float* maskb = (const float*)d_in[16];
  float* out = (float*)d_out;

  char* ws = (char*)d_ws;
  size_t off=0;
  auto alloc=[&](size_t bytes)->char*{ char* p = ws+off; off += (bytes+255)&~(size_t)255; return p; };
  int2*  sedge  = (int2*) alloc(sizeof(int2)*LE);         // 44.8 MB
  int*   offs8  = (int*)  alloc(sizeof(int)*(N8+1));      // 11.2 MB
  int*   cnt8   = (int*)  alloc(sizeof(int)*N8);          // 11.2 MB (then reused as cursors)
  int*   bsums  = (int*)  alloc(sizeof(int)*1024);
  float* x      = (float*)alloc(sizeof(float)*NN*DIM);    // 25.6 MB
  float* bufB   = (float*)alloc(sizeof(float)*NN*DIM);    // 25.6 MB
  float* bufC   = (float*)alloc(sizeof(float)*NN*DIM);    // 25.6 MB
  float* stats  = (float*)alloc(sizeof(float)*(LL*256+32)); // per-layer gsum/gsumsq + racc
  float* racc   = stats + LL*256;

  // --- counting sort of all 7 edge lists by (layer, blockgroup, dst) ---
  hipMemsetAsync(cnt8, 0, sizeof(int)*N8, stream);
  hipMemsetAsync(stats, 0, sizeof(float)*(LL*256+32), stream);
  for (int l=0;l<LL;l++)
    k_hist8<<<(EE+255)/256,256,0,stream>>>(ei, cnt8, l);
  int nsb = (N8+4095)/4096;  // 684
  k_scan1<<<nsb,256,0,stream>>>(cnt8, offs8, bsums, N8);
  k_scan2<<<1,1024,0,stream>>>(bsums, nsb);
  k_scan3<<<(N8+255)/256,256,0,stream>>>(offs8, bsums, cnt8, N8);
  for (int l=0;l<LL;l++)
    k_scatter8<<<(EE+255)/256,256,0,stream>>>(ei, ew, cnt8, sedge, l);
  k_gather_emb<<<NN*32/256,256,0,stream>>>(verts, emb, x);

  // --- 6 hidden layers ---
  for (int i=0;i<6;i++){
    int j = (i==0)?5:(i-1);   // (i-1) % 6, Python semantics
    float* gsum = stats + i*256, *gsumsq = gsum + 128;
    k_gemm128v<<<(NN+63)/64,256,0,stream>>>(x, wh + (size_t)i*DIM*DIM, bufB, NN);
    k_spmm128<<<NN/8,256,0,stream>>>(bufB, sedge, offs8, bufC, i*8*NN);
    k_bn_stats<128><<<512,256,0,stream>>>(bufC, NN, DIM, gsum, gsumsq, 98);
    k_gemm128v<<<(NN+63)/64,256,0,stream>>>(x, tewl + (size_t)j*DIM*DIM, bufB, NN);
    k_gemm_gate<<<(NN+63)/64,256,0,stream>>>(bufC, tewc + (size_t)j*DIM*DIM, bufB,
        teb + (size_t)j*DIM, gsum, gsumsq,
        bng_h+(size_t)i*DIM, bnb_h+(size_t)i*DIM, x, NN);
  }

  // --- output layer ---
  float* gsum = stats + 6*256, *gsumsq = gsum + 128;
  k_gemm_out<<<(NN+7)/8,256,0,stream>>>(x, w_out, bufB, NN);
  k_spmm_out<<<NN/8,256,0,stream>>>(bufB, sedge, offs8, bufC, 6*8*NN);
  k_bn_stats<32><<<512,256,0,stream>>>(bufC, NN, OUTC, gsum, gsumsq, 98);
  k_bn_out<<<(NN*OUTC+255)/256,256,0,stream>>>(bufC, gsum, gsumsq, bng_o, bnb_o);
  k_reduce<<<512,256,0,stream>>>(bufC, verts, maskw, racc, 98);
  k_final<<<1,64,0,stream>>>(racc, maskb, out);
}

// Round 6
// 1580.339 us; speedup vs baseline: 1.9195x; 1.3497x over previous
//
#include <hip/hip_runtime.h>

#define NN 50000
#define EE 800000
#define DIM 128
#define OUTC 20
#define LL 7
#define LE (LL*EE)
#define LN (LL*NN)
#define N8 (8*LN)
#define BN_EPS 1e-5f
#define LSTRIDE 136     // bf16 elems per LDS row: 16B-aligned, balanced banks

typedef __attribute__((ext_vector_type(8))) short short8;
typedef __attribute__((ext_vector_type(4))) float f32x4;

static __device__ __forceinline__ float sigm(float z){ return 1.0f/(1.0f+expf(-z)); }
static __device__ __forceinline__ unsigned short f2bf(float f){
  unsigned int u = __float_as_uint(f);
  u += 0x7FFF + ((u>>16)&1);            // RNE
  return (unsigned short)(u>>16);
}
static __device__ __forceinline__ float bf2f(unsigned short s){
  return __uint_as_float(((unsigned int)s)<<16);
}

// ======== preprocessing: counting sort by (layer, blockgroup&7, dst) ========
__global__ __launch_bounds__(256) void k_hist8(const int* __restrict__ ei,
    int* __restrict__ cnt8){
  int l = blockIdx.x/3125;                       // EE = 3125*256
  int e = (blockIdx.x - l*3125)*256 + threadIdx.x;
  int g = blockIdx.x & 7;
  int dst = ei[(2*l+1)*EE + e];
  atomicAdd(&cnt8[(l*8+g)*NN + dst], 1);
}

__global__ __launch_bounds__(256) void k_scan1(const int* __restrict__ cnt,
    int* __restrict__ offs, int* __restrict__ bsums, int n){
  __shared__ int s[256];
  int t = threadIdx.x;
  int base = blockIdx.x*4096 + t*16;
  int v[16]; int sum = 0;
  #pragma unroll
  for (int i=0;i<16;i++){ v[i] = (base+i<n)? cnt[base+i] : 0; sum += v[i]; }
  s[t]=sum; __syncthreads();
  for (int off=1; off<256; off<<=1){
    int x = (t>=off)? s[t-off] : 0;
    __syncthreads(); s[t] += x; __syncthreads();
  }
  if (t==255) bsums[blockIdx.x] = s[255];
  int run = s[t]-sum;
  #pragma unroll
  for (int i=0;i<16;i++){ if (base+i<n) offs[base+i]=run; run += v[i]; }
}

__global__ __launch_bounds__(1024) void k_scan2(int* bsums, int nb){
  __shared__ int s[1024];
  int t=threadIdx.x;
  int v = (t<nb)? bsums[t]:0;
  s[t]=v; __syncthreads();
  for (int off=1; off<1024; off<<=1){
    int x=(t>=off)? s[t-off]:0; __syncthreads(); s[t]+=x; __syncthreads();
  }
  if (t<nb) bsums[t] = s[t]-v;
}

__global__ void k_scan3(int* __restrict__ offs, const int* __restrict__ bsums,
                        int* __restrict__ cur, int n){
  int gid = blockIdx.x*256+threadIdx.x;
  if (gid < n){
    int val = offs[gid] + bsums[gid>>12];
    offs[gid]=val; cur[gid]=val;
  }
  if (gid==0) offs[n]=LE;
}

__global__ __launch_bounds__(256) void k_scatter8(const int* __restrict__ ei,
    const float* __restrict__ ew, int* __restrict__ cur8,
    int2* __restrict__ sedge){
  int l = blockIdx.x/3125;
  int e = (blockIdx.x - l*3125)*256 + threadIdx.x;
  int g = blockIdx.x & 7;
  int src = ei[(2*l)*EE + e];
  int dst = ei[(2*l+1)*EE + e];
  int pos = atomicAdd(&cur8[(l*8+g)*NN + dst], 1);
  sedge[pos] = make_int2(src, __float_as_int(ew[(size_t)l*EE + e]));
}

__global__ void k_gather_emb(const int* __restrict__ verts, const float* __restrict__ emb,
                             float* __restrict__ x){
  int gid = blockIdx.x*256+threadIdx.x;
  int n = gid>>5, q = gid&31;
  if (n>=NN) return;
  int v = verts[n];
  ((float4*)x)[gid] = ((const float4*)emb)[(size_t)v*32+q];
}

// ---- transpose + bf16-convert all 18 hidden weight matrices: Wt[m][n][k] ----
__global__ __launch_bounds__(256) void k_prep_w(const float* __restrict__ wh,
    const float* __restrict__ tewl, const float* __restrict__ tewc,
    unsigned short* __restrict__ Wt){
  int gid = blockIdx.x*256+threadIdx.x;          // 18*16384
  int m = gid>>14; int idx = gid&16383;
  int n = idx>>7, k = idx&127;
  const float* src = (m<6)? wh + (size_t)m*16384
                   : (m<12)? tewl + (size_t)(m-6)*16384
                   : tewc + (size_t)(m-12)*16384;
  Wt[gid] = f2bf(src[k*128+n]);
}

// stage 64 fp32 rows -> bf16 LDS tile [64][LSTRIDE]
static __device__ __forceinline__ void stage64(const float* __restrict__ src,
    int row0, int M, unsigned short* Xs, int tid){
  #pragma unroll
  for (int it=0; it<4; it++){
    int idx = tid + it*256;                      // 1024 groups of 8
    int r = idx>>4, k8 = idx&15;
    float4 v0 = make_float4(0.f,0.f,0.f,0.f), v1 = v0;
    if (row0+r < M){
      const float4* p = (const float4*)src + (size_t)(row0+r)*32 + k8*2;
      v0 = p[0]; v1 = p[1];
    }
    short8 w;
    w[0]=(short)f2bf(v0.x); w[1]=(short)f2bf(v0.y); w[2]=(short)f2bf(v0.z); w[3]=(short)f2bf(v0.w);
    w[4]=(short)f2bf(v1.x); w[5]=(short)f2bf(v1.y); w[6]=(short)f2bf(v1.z); w[7]=(short)f2bf(v1.w);
    *(short8*)&Xs[r*LSTRIDE + k8*8] = w;
  }
}

// ---------------- MFMA GEMM: Ybf16[M,128] = bf16(X[M,128]) @ Wt ----------------
__global__ __launch_bounds__(256) void k_gemm_sup(const float* __restrict__ X,
    const unsigned short* __restrict__ Wt, unsigned short* __restrict__ Y, int M){
  __shared__ unsigned short Xs[64*LSTRIDE];
  int tid = threadIdx.x;
  int row0 = blockIdx.x*64;
  stage64(X, row0, M, Xs, tid);
  __syncthreads();
  int w = tid>>6, lane = tid&63, m = lane&15, q = lane>>4;
  f32x4 acc[8];
  #pragma unroll
  for (int nt=0;nt<8;nt++){ acc[nt][0]=0.f; acc[nt][1]=0.f; acc[nt][2]=0.f; acc[nt][3]=0.f; }
  #pragma unroll
  for (int kc=0; kc<4; kc++){
    short8 a = *(const short8*)&Xs[(16*w+m)*LSTRIDE + kc*32 + 8*q];
    #pragma unroll
    for (int nt=0; nt<8; nt++){
      short8 b = *(const short8*)&Wt[(size_t)(nt*16+m)*128 + kc*32 + 8*q];
      acc[nt] = __builtin_amdgcn_mfma_f32_16x16x32_bf16(a, b, acc[nt], 0,0,0);
    }
  }
  #pragma unroll
  for (int nt=0; nt<8; nt++){
    #pragma unroll
    for (int i=0;i<4;i++){
      int rr = row0 + 16*w + 4*q + i;
      if (rr<M) Y[(size_t)rr*128 + nt*16 + m] = f2bf(acc[nt][i]);
    }
  }
}

// ------- fused: BN(h)+ReLU -> bf16 LDS; dual MFMA (x@te_wl + hn@te_wc); gate -------
__global__ __launch_bounds__(256) void k_gemm_gate2(const float* __restrict__ H,
    const float* __restrict__ stL,            // 8 replicas [g][sum128|sq128]
    const float* __restrict__ gamma, const float* __restrict__ beta,
    const unsigned short* __restrict__ Wl, const unsigned short* __restrict__ Wc,
    const float* __restrict__ teb, float* __restrict__ x, int M){
  __shared__ unsigned short XsX[64*LSTRIDE];
  __shared__ unsigned short XsH[64*LSTRIDE];
  __shared__ float sSc[128], sOff[128];
  int tid = threadIdx.x;
  int row0 = blockIdx.x*64;
  if (tid<128){
    float s=0.f, sq=0.f;
    #pragma unroll
    for (int g=0; g<8; g++){ s += stL[g*256+tid]; sq += stL[g*256+128+tid]; }
    float mean = s*(1.0f/NN);
    float var = sq*(1.0f/NN) - mean*mean;
    float sc = rsqrtf(var+BN_EPS)*gamma[tid];
    sSc[tid]=sc; sOff[tid]=beta[tid]-mean*sc;
  }
  stage64(x, row0, M, XsX, tid);
  __syncthreads();                 // sSc ready before H staging uses it
  #pragma unroll
  for (int it=0; it<4; it++){
    int idx = tid + it*256;
    int r = idx>>4, k8 = idx&15;
    float4 v0 = make_float4(0.f,0.f,0.f,0.f), v1 = v0;
    if (row0+r < M){
      const float4* p = (const float4*)H + (size_t)(row0+r)*32 + k8*2;
      v0 = p[0]; v1 = p[1];
    }
    int k = k8*8;
    float o[8] = {v0.x,v0.y,v0.z,v0.w,v1.x,v1.y,v1.z,v1.w};
    short8 w;
    #pragma unroll
    for (int j=0;j<8;j++){
      float hn = fmaxf(fmaf(o[j], sSc[k+j], sOff[k+j]), 0.f);
      w[j] = (short)f2bf(hn);
    }
    *(short8*)&XsH[r*LSTRIDE + k8*8] = w;
  }
  __syncthreads();
  int w = tid>>6, lane = tid&63, m = lane&15, q = lane>>4;
  f32x4 acc[8];
  #pragma unroll
  for (int nt=0;nt<8;nt++){ acc[nt][0]=0.f; acc[nt][1]=0.f; acc[nt][2]=0.f; acc[nt][3]=0.f; }
  #pragma unroll
  for (int kc=0; kc<4; kc++){
    short8 a = *(const short8*)&XsX[(16*w+m)*LSTRIDE + kc*32 + 8*q];
    #pragma unroll
    for (int nt=0; nt<8; nt++){
      short8 b = *(const short8*)&Wl[(size_t)(nt*16+m)*128 + kc*32 + 8*q];
      acc[nt] = __builtin_amdgcn_mfma_f32_16x16x32_bf16(a, b, acc[nt], 0,0,0);
    }
  }
  #pragma unroll
  for (int kc=0; kc<4; kc++){
    short8 a = *(const short8*)&XsH[(16*w+m)*LSTRIDE + kc*32 + 8*q];
    #pragma unroll
    for (int nt=0; nt<8; nt++){
      short8 b = *(const short8*)&Wc[(size_t)(nt*16+m)*128 + kc*32 + 8*q];
      acc[nt] = __builtin_amdgcn_mfma_f32_16x16x32_bf16(a, b, acc[nt], 0,0,0);
    }
  }
  #pragma unroll
  for (int nt=0; nt<8; nt++){
    int col = nt*16 + m;
    float bias = teb[col];
    #pragma unroll
    for (int i=0;i<4;i++){
      int lr = 16*w + 4*q + i;
      int rr = row0 + lr;
      if (rr<M){
        float hv = bf2f(XsH[lr*LSTRIDE + col]);
        float xo = bf2f(XsX[lr*LSTRIDE + col]);
        float g = sigm(acc[nt][i] + bias);
        x[(size_t)rr*128 + col] = g*hv + (1.f-g)*xo;
      }
    }
  }
}

// ---------------- Y[M,20] = X[M,128] @ W[128,20] (fp32) ----------------
__global__ __launch_bounds__(256) void k_gemm_out(const float* __restrict__ X,
    const float* __restrict__ W, float* __restrict__ Y, int M){
  __shared__ float Ws[DIM*OUTC];
  __shared__ float Xs2[8*DIM];
  int tid=threadIdx.x;
  for (int i=tid;i<DIM*OUTC;i+=256) Ws[i]=W[i];
  int row0=blockIdx.x*8;
  {
    int r = tid>>5, kq = tid&31;
    float4 v = make_float4(0.f,0.f,0.f,0.f);
    if (row0+r<M) v = ((const float4*)X)[(size_t)(row0+r)*32+kq];
    *(float4*)&Xs2[r*DIM+kq*4]=v;
  }
  __syncthreads();
  int c = tid&31, rl=tid>>5;
  if (c<OUTC && row0+rl<M){
    float acc=0.f;
    #pragma unroll 8
    for (int k=0;k<DIM;k++) acc += Xs2[rl*DIM+k]*Ws[k*OUTC+c];
    Y[(size_t)(row0+rl)*OUTC+c]=acc;
  }
}

// ---------------- SpMM gather over bf16 support ----------------
__global__ __launch_bounds__(256) void k_spmm128(const unsigned short* __restrict__ sup,
    const int2* __restrict__ sedge, const int* __restrict__ offs8,
    float* __restrict__ h, int base8){
  int node = blockIdx.x*8 + (threadIdx.x>>5);
  int fq = threadIdx.x & 31;
  float4 a0 = make_float4(0.f,0.f,0.f,0.f), a1 = a0;
  #pragma unroll
  for (int g=0; g<8; g++){
    int idx = base8 + g*NN + node;
    int p = offs8[idx], end = offs8[idx+1];
    for (; p+1<end; p+=2){
      int2 e0 = sedge[p], e1 = sedge[p+1];
      float w0 = __int_as_float(e0.y), w1 = __int_as_float(e1.y);
      ushort4 s0 = *(const ushort4*)(sup + (size_t)e0.x*128 + fq*4);
      ushort4 s1 = *(const ushort4*)(sup + (size_t)e1.x*128 + fq*4);
      a0.x += w0*bf2f(s0.x); a0.y += w0*bf2f(s0.y); a0.z += w0*bf2f(s0.z); a0.w += w0*bf2f(s0.w);
      a1.x += w1*bf2f(s1.x); a1.y += w1*bf2f(s1.y); a1.z += w1*bf2f(s1.z); a1.w += w1*bf2f(s1.w);
    }
    if (p<end){
      int2 e0 = sedge[p];
      float w0 = __int_as_float(e0.y);
      ushort4 s0 = *(const ushort4*)(sup + (size_t)e0.x*128 + fq*4);
      a0.x += w0*bf2f(s0.x); a0.y += w0*bf2f(s0.y); a0.z += w0*bf2f(s0.z); a0.w += w0*bf2f(s0.w);
    }
  }
  a0.x+=a1.x; a0.y+=a1.y; a0.z+=a1.z; a0.w+=a1.w;
  ((float4*)h)[(size_t)node*32+fq] = a0;
}

__global__ __launch_bounds__(256) void k_spmm_out(const float* __restrict__ sup,
    const int2* __restrict__ sedge, const int* __restrict__ offs8,
    float* __restrict__ h, int base8){
  int node = blockIdx.x*8 + (threadIdx.x>>5);
  int c = threadIdx.x & 31;
  float acc=0.f;
  #pragma unroll
  for (int g=0; g<8; g++){
    int idx = base8 + g*NN + node;
    int p = offs8[idx], end = offs8[idx+1];
    for (; p<end; p++){
      int2 e = sedge[p];
      if (c<OUTC) acc += __int_as_float(e.y)*sup[(size_t)e.x*OUTC+c];
    }
  }
  if (c<OUTC) h[(size_t)node*OUTC+c]=acc;
}

// ---------------- BatchNorm stats (8-way replicated atomics) ----------------
template<int DP>
__global__ __launch_bounds__(256) void k_bn_stats(const float* __restrict__ h,
    int M, int D, float* __restrict__ st8, int stride, int rpb){
  const int G = 256/DP;
  int f = threadIdx.x % DP;
  int g = threadIdx.x / DP;
  float s=0.f, ss=0.f;
  int r0 = blockIdx.x*rpb;
  int r1 = min(M, r0+rpb);
  if (f < D){
    for (int r=r0+g; r<r1; r+=G){ float v = h[(size_t)r*D+f]; s+=v; ss+=v*v; }
  }
  __shared__ float sh[256], sh2[256];
  sh[threadIdx.x]=s; sh2[threadIdx.x]=ss; __syncthreads();
  if (threadIdx.x < DP){
    #pragma unroll
    for (int i=1;i<G;i++){ s+=sh[threadIdx.x+i*DP]; ss+=sh2[threadIdx.x+i*DP]; }
    if (f<D){
      float* base = st8 + (blockIdx.x&7)*stride;
      atomicAdd(&base[f], s); atomicAdd(&base[stride/2+f], ss);
    }
  }
}

__global__ void k_bn_reduce8(const float* __restrict__ st8, float* __restrict__ st){
  int f = threadIdx.x;          // 64: [sum20|pad, sq20|pad] stride 64
  float s=0.f;
  #pragma unroll
  for (int g=0; g<8; g++) s += st8[g*64+f];
  st[f]=s;
}

__global__ void k_bn_out(float* __restrict__ h, const float* __restrict__ st,
    const float* __restrict__ gamma, const float* __restrict__ beta){
  int gid = blockIdx.x*256+threadIdx.x;
  if (gid>=NN*OUTC) return;
  int f = gid % OUTC;
  const float invN = 1.0f/NN;
  float m = st[f]*invN;
  float var = st[32+f]*invN - m*m;
  float sc = rsqrtf(var+BN_EPS)*gamma[f];
  h[gid] = fmaxf((h[gid]-m)*sc + beta[f], 0.f);
}

// ---------------- final masked reduce (8-way replicated) ----------------
__global__ __launch_bounds__(256) void k_reduce(const float* __restrict__ xf,
    const int* __restrict__ verts, const float* __restrict__ mw,
    float* __restrict__ acc8, int rpb){
  int c = threadIdx.x & 31, g = threadIdx.x >> 5;
  int r0 = blockIdx.x*rpb;
  int r1 = min(NN, r0+rpb);
  float s=0.f;
  for (int r=r0+g; r<r1; r+=8){
    float m = mw[verts[r]];
    if (c<OUTC) s += m * xf[(size_t)r*OUTC+c];
  }
  __shared__ float sh[256];
  sh[threadIdx.x]=s; __syncthreads();
  if (threadIdx.x<32){
    #pragma unroll
    for (int i=1;i<8;i++) s += sh[threadIdx.x + i*32];
    if (c<OUTC) atomicAdd(&acc8[(blockIdx.x&7)*32 + c], s);
  }
}

__global__ void k_final(const float* __restrict__ acc8, const float* __restrict__ mb,
                        float* __restrict__ out){
  int c=threadIdx.x;
  if (c<OUTC){
    float s=0.f;
    #pragma unroll
    for (int g=0; g<8; g++) s += acc8[g*32+c];
    out[c] = sigm(s+mb[c]);
  }
}

// ---------------- host ----------------
extern "C" void kernel_launch(void* const* d_in, const int* in_sizes, int n_in,
                              void* d_out, int out_size, void* d_ws, size_t ws_size,
                              hipStream_t stream){
  const int*   verts = (const int*)d_in[0];
  const int*   ei    = (const int*)d_in[1];
  const float* ew    = (const float*)d_in[2];
  const float* emb   = (const float*)d_in[3];
  const float* wh    = (const float*)d_in[4];
  const float* w_out = (const float*)d_in[6];
  const float* bng_h = (const float*)d_in[8];
  const float* bnb_h = (const float*)d_in[9];
  const float* bng_o = (const float*)d_in[10];
  const float* bnb_o = (const float*)d_in[11];
  const float* tewl  = (const float*)d_in[12];
  const float* tewc  = (const float*)d_in[13];
  const float* teb   = (const float*)d_in[14];
  const float* maskw = (const float*)d_in[15];
  const float* maskb = (const float*)d_in[16];
  float* out = (float*)d_out;

  char* ws = (char*)d_ws;
  size_t off=0;
  auto alloc=[&](size_t bytes)->char*{ char* p = ws+off; off += (bytes+255)&~(size_t)255; return p; };
  int2*  sedge  = (int2*) alloc(sizeof(int2)*LE);              // 44.8 MB
  int*   offs8  = (int*)  alloc(sizeof(int)*(N8+1));           // 11.2 MB
  int*   cnt8   = (int*)  alloc(sizeof(int)*N8);               // 11.2 MB
  int*   bsums  = (int*)  alloc(sizeof(int)*1024);
  float* x      = (float*)alloc(sizeof(float)*NN*DIM);         // 25.6 MB
  unsigned short* supbf = (unsigned short*)alloc(sizeof(short)*NN*DIM); // 12.8 MB
  float* bufC   = (float*)alloc(sizeof(float)*NN*DIM);         // 25.6 MB
  float* buf20  = (float*)alloc(sizeof(float)*NN*OUTC);        // 4 MB
  unsigned short* Wt = (unsigned short*)alloc(sizeof(short)*18*DIM*DIM); // 0.6 MB
  float* stats  = (float*)alloc(sizeof(float)*(6*2048 + 8*64 + 64 + 8*32));
  float* ostat8 = stats + 6*2048;      // [8][64]
  float* ostat  = ostat8 + 8*64;       // [64]
  float* racc8  = ostat + 64;          // [8][32]

  // --- preprocessing ---
  hipMemsetAsync(cnt8, 0, sizeof(int)*N8, stream);
  hipMemsetAsync(stats, 0, sizeof(float)*(6*2048 + 8*64 + 64 + 8*32), stream);
  k_prep_w<<<1152,256,0,stream>>>(wh, tewl, tewc, Wt);
  k_hist8<<<LL*3125,256,0,stream>>>(ei, cnt8);
  int nsb = (N8+4095)/4096;  // 684
  k_scan1<<<nsb,256,0,stream>>>(cnt8, offs8, bsums, N8);
  k_scan2<<<1,1024,0,stream>>>(bsums, nsb);
  k_scan3<<<(N8+255)/256,256,0,stream>>>(offs8, bsums, cnt8, N8);
  k_scatter8<<<LL*3125,256,0,stream>>>(ei, ew, cnt8, sedge);
  k_gather_emb<<<NN*32/256,256,0,stream>>>(verts, emb, x);

  // --- 6 hidden layers ---
  for (int i=0;i<6;i++){
    int j = (i==0)?5:(i-1);
    float* stL = stats + i*2048;
    k_gemm_sup<<<(NN+63)/64,256,0,stream>>>(x, Wt + (size_t)i*DIM*DIM, supbf, NN);
    k_spmm128<<<NN/8,256,0,stream>>>(supbf, sedge, offs8, bufC, i*8*NN);
    k_bn_stats<128><<<512,256,0,stream>>>(bufC, NN, DIM, stL, 256, 98);
    k_gemm_gate2<<<(NN+63)/64,256,0,stream>>>(bufC, stL,
        bng_h+(size_t)i*DIM, bnb_h+(size_t)i*DIM,
        Wt + (size_t)(6+j)*DIM*DIM, Wt + (size_t)(12+j)*DIM*DIM,
        teb + (size_t)j*DIM, x, NN);
  }

  // --- output layer (fp32 throughout) ---
  k_gemm_out<<<(NN+7)/8,256,0,stream>>>(x, w_out, buf20, NN);
  k_spmm_out<<<NN/8,256,0,stream>>>(buf20, sedge, offs8, bufC, 6*8*NN);
  k_bn_stats<32><<<512,256,0,stream>>>(bufC, NN, OUTC, ostat8, 64, 98);
  k_bn_reduce8<<<1,64,0,stream>>>(ostat8, ostat);
  k_bn_out<<<(NN*OUTC+255)/256,256,0,stream>>>(bufC, ostat, bng_o, bnb_o);
  k_reduce<<<512,256,0,stream>>>(bufC, verts, maskw, racc8, 98);
  k_final<<<1,64,0,stream>>>(racc8, maskb, out);
}

// Round 7
// 1338.714 us; speedup vs baseline: 2.2659x; 1.1805x over previous
//
#include <hip/hip_runtime.h>
#include <hip/hip_fp16.h>

#define NN 50000
#define EE 800000
#define DIM 128
#define OUTC 20
#define LL 7
#define LE (LL*EE)
#define LN (LL*NN)
#define N8 (8*LN)
#define BN_EPS 1e-5f
#define LSTRIDE 136     // bf16 elems per LDS row
#define NREP 64         // stat replicas

typedef __attribute__((ext_vector_type(8))) short short8;
typedef __attribute__((ext_vector_type(4))) float f32x4;

static __device__ __forceinline__ float sigm(float z){ return 1.0f/(1.0f+expf(-z)); }
static __device__ __forceinline__ unsigned short f2bf(float f){
  unsigned int u = __float_as_uint(f);
  u += 0x7FFF + ((u>>16)&1);            // RNE
  return (unsigned short)(u>>16);
}
static __device__ __forceinline__ float bf2f(unsigned short s){
  return __uint_as_float(((unsigned int)s)<<16);
}

// ======== preprocessing ========
// counters g-major ([l][g][dst], XCD-local atomics via g=blockIdx&7);
// hist's atomicAdd return value IS the edge rank -> scatter needs no atomics.
__global__ __launch_bounds__(256) void k_hist8(const int* __restrict__ ei,
    int* __restrict__ cnt8, unsigned short* __restrict__ rk){
  int l = blockIdx.x/3125;                       // EE = 3125*256
  int e = (blockIdx.x - l*3125)*256 + threadIdx.x;
  int g = blockIdx.x & 7;
  int dst = ei[(2*l+1)*EE + e];
  int r = atomicAdd(&cnt8[(l*8+g)*NN + dst], 1);
  rk[(size_t)l*EE + e] = (unsigned short)r;
}

// scan enumerates segments g-MINOR: seg i = (l*NN+dst)*8+g  ->  per-node edges contiguous
static __device__ __forceinline__ int permAddr(int i){
  int l = i/(NN*8);
  int rem = i - l*NN*8;
  return (l*8 + (rem&7))*NN + (rem>>3);
}

__global__ __launch_bounds__(256) void k_scan1(const int* __restrict__ cnt,
    int* __restrict__ offs, int* __restrict__ bsums, int n){
  __shared__ int s[256];
  int t = threadIdx.x;
  int base = blockIdx.x*4096 + t*16;
  int v[16]; int sum = 0;
  #pragma unroll
  for (int i=0;i<16;i++){ v[i] = (base+i<n)? cnt[permAddr(base+i)] : 0; sum += v[i]; }
  s[t]=sum; __syncthreads();
  for (int off=1; off<256; off<<=1){
    int x = (t>=off)? s[t-off] : 0;
    __syncthreads(); s[t] += x; __syncthreads();
  }
  if (t==255) bsums[blockIdx.x] = s[255];
  int run = s[t]-sum;
  #pragma unroll
  for (int i=0;i<16;i++){ if (base+i<n) offs[base+i]=run; run += v[i]; }
}

__global__ __launch_bounds__(1024) void k_scan2(int* bsums, int nb){
  __shared__ int s[1024];
  int t=threadIdx.x;
  int v = (t<nb)? bsums[t]:0;
  s[t]=v; __syncthreads();
  for (int off=1; off<1024; off<<=1){
    int x=(t>=off)? s[t-off]:0; __syncthreads(); s[t]+=x; __syncthreads();
  }
  if (t<nb) bsums[t] = s[t]-v;
}

__global__ void k_scan3(int* __restrict__ offs, const int* __restrict__ bsums, int n){
  int gid = blockIdx.x*256+threadIdx.x;
  if (gid < n) offs[gid] += bsums[gid>>12];
  if (gid==0) offs[n]=LE;
}

// atomic-free scatter of 4B packed edges (src16 | fp16 weight)
__global__ __launch_bounds__(256) void k_scatter_nr(const int* __restrict__ ei,
    const float* __restrict__ ew, const unsigned short* __restrict__ rk,
    const int* __restrict__ offs8, unsigned int* __restrict__ sedge){
  int l = blockIdx.x/3125;
  int e = (blockIdx.x - l*3125)*256 + threadIdx.x;
  int g = blockIdx.x & 7;
  int src = __builtin_nontemporal_load(ei + (size_t)(2*l)*EE + e);
  int dst = __builtin_nontemporal_load(ei + (size_t)(2*l+1)*EE + e);
  int r   = __builtin_nontemporal_load(rk + (size_t)l*EE + e);
  float w = __builtin_nontemporal_load(ew + (size_t)l*EE + e);
  int pos = offs8[(l*NN + dst)*8 + g] + r;
  unsigned short hw = __half_as_ushort(__float2half(w));
  sedge[pos] = (unsigned int)src | ((unsigned int)hw << 16);
}

__global__ void k_gather_emb(const int* __restrict__ verts, const float* __restrict__ emb,
                             float* __restrict__ x){
  int gid = blockIdx.x*256+threadIdx.x;
  int n = gid>>5, q = gid&31;
  if (n>=NN) return;
  int v = verts[n];
  ((float4*)x)[gid] = ((const float4*)emb)[(size_t)v*32+q];
}

// ---- transpose + bf16-convert all 18 hidden weight matrices: Wt[m][n][k] ----
__global__ __launch_bounds__(256) void k_prep_w(const float* __restrict__ wh,
    const float* __restrict__ tewl, const float* __restrict__ tewc,
    unsigned short* __restrict__ Wt){
  int gid = blockIdx.x*256+threadIdx.x;          // 18*16384
  int m = gid>>14; int idx = gid&16383;
  int n = idx>>7, k = idx&127;
  const float* src = (m<6)? wh + (size_t)m*16384
                   : (m<12)? tewl + (size_t)(m-6)*16384
                   : tewc + (size_t)(m-12)*16384;
  Wt[gid] = f2bf(src[k*128+n]);
}

// stage 64 fp32 rows -> bf16 LDS tile [64][LSTRIDE]
static __device__ __forceinline__ void stage64(const float* __restrict__ src,
    int row0, int M, unsigned short* Xs, int tid){
  #pragma unroll
  for (int it=0; it<4; it++){
    int idx = tid + it*256;
    int r = idx>>4, k8 = idx&15;
    float4 v0 = make_float4(0.f,0.f,0.f,0.f), v1 = v0;
    if (row0+r < M){
      const float4* p = (const float4*)src + (size_t)(row0+r)*32 + k8*2;
      v0 = p[0]; v1 = p[1];
    }
    short8 w;
    w[0]=(short)f2bf(v0.x); w[1]=(short)f2bf(v0.y); w[2]=(short)f2bf(v0.z); w[3]=(short)f2bf(v0.w);
    w[4]=(short)f2bf(v1.x); w[5]=(short)f2bf(v1.y); w[6]=(short)f2bf(v1.z); w[7]=(short)f2bf(v1.w);
    *(short8*)&Xs[r*LSTRIDE + k8*8] = w;
  }
}

// ---------------- MFMA GEMM: Ybf16[M,128] = bf16(X[M,128]) @ Wt ----------------
__global__ __launch_bounds__(256) void k_gemm_sup(const float* __restrict__ X,
    const unsigned short* __restrict__ Wt, unsigned short* __restrict__ Y, int M){
  __shared__ unsigned short Xs[64*LSTRIDE];
  int tid = threadIdx.x;
  int row0 = blockIdx.x*64;
  stage64(X, row0, M, Xs, tid);
  __syncthreads();
  int w = tid>>6, lane = tid&63, m = lane&15, q = lane>>4;
  f32x4 acc[8];
  #pragma unroll
  for (int nt=0;nt<8;nt++){ acc[nt][0]=0.f; acc[nt][1]=0.f; acc[nt][2]=0.f; acc[nt][3]=0.f; }
  #pragma unroll
  for (int kc=0; kc<4; kc++){
    short8 a = *(const short8*)&Xs[(16*w+m)*LSTRIDE + kc*32 + 8*q];
    #pragma unroll
    for (int nt=0; nt<8; nt++){
      short8 b = *(const short8*)&Wt[(size_t)(nt*16+m)*128 + kc*32 + 8*q];
      acc[nt] = __builtin_amdgcn_mfma_f32_16x16x32_bf16(a, b, acc[nt], 0,0,0);
    }
  }
  #pragma unroll
  for (int nt=0; nt<8; nt++){
    #pragma unroll
    for (int i=0;i<4;i++){
      int rr = row0 + 16*w + 4*q + i;
      if (rr<M) Y[(size_t)rr*128 + nt*16 + m] = f2bf(acc[nt][i]);
    }
  }
}

// ------- fused: BN(h)+ReLU -> bf16 LDS; dual MFMA (x@te_wl + hn@te_wc); gate -------
__global__ __launch_bounds__(256) void k_gemm_gate2(const float* __restrict__ H,
    const float* __restrict__ stL,            // NREP replicas [rep][sum128|sq128]
    const float* __restrict__ gamma, const float* __restrict__ beta,
    const unsigned short* __restrict__ Wl, const unsigned short* __restrict__ Wc,
    const float* __restrict__ teb, float* __restrict__ x, int M){
  __shared__ unsigned short XsX[64*LSTRIDE];
  __shared__ unsigned short XsH[64*LSTRIDE];
  __shared__ float sSc[128], sOff[128];
  int tid = threadIdx.x;
  int row0 = blockIdx.x*64;
  if (tid<128){
    float s=0.f, sq=0.f;
    #pragma unroll 8
    for (int g=0; g<NREP; g++){ s += stL[g*256+tid]; sq += stL[g*256+128+tid]; }
    float mean = s*(1.0f/NN);
    float var = sq*(1.0f/NN) - mean*mean;
    float sc = rsqrtf(var+BN_EPS)*gamma[tid];
    sSc[tid]=sc; sOff[tid]=beta[tid]-mean*sc;
  }
  stage64(x, row0, M, XsX, tid);
  __syncthreads();
  #pragma unroll
  for (int it=0; it<4; it++){
    int idx = tid + it*256;
    int r = idx>>4, k8 = idx&15;
    float4 v0 = make_float4(0.f,0.f,0.f,0.f), v1 = v0;
    if (row0+r < M){
      const float4* p = (const float4*)H + (size_t)(row0+r)*32 + k8*2;
      v0 = p[0]; v1 = p[1];
    }
    int k = k8*8;
    float o[8] = {v0.x,v0.y,v0.z,v0.w,v1.x,v1.y,v1.z,v1.w};
    short8 w;
    #pragma unroll
    for (int j=0;j<8;j++){
      float hn = fmaxf(fmaf(o[j], sSc[k+j], sOff[k+j]), 0.f);
      w[j] = (short)f2bf(hn);
    }
    *(short8*)&XsH[r*LSTRIDE + k8*8] = w;
  }
  __syncthreads();
  int w = tid>>6, lane = tid&63, m = lane&15, q = lane>>4;
  f32x4 acc[8];
  #pragma unroll
  for (int nt=0;nt<8;nt++){ acc[nt][0]=0.f; acc[nt][1]=0.f; acc[nt][2]=0.f; acc[nt][3]=0.f; }
  #pragma unroll
  for (int kc=0; kc<4; kc++){
    short8 a = *(const short8*)&XsX[(16*w+m)*LSTRIDE + kc*32 + 8*q];
    #pragma unroll
    for (int nt=0; nt<8; nt++){
      short8 b = *(const short8*)&Wl[(size_t)(nt*16+m)*128 + kc*32 + 8*q];
      acc[nt] = __builtin_amdgcn_mfma_f32_16x16x32_bf16(a, b, acc[nt], 0,0,0);
    }
  }
  #pragma unroll
  for (int kc=0; kc<4; kc++){
    short8 a = *(const short8*)&XsH[(16*w+m)*LSTRIDE + kc*32 + 8*q];
    #pragma unroll
    for (int nt=0; nt<8; nt++){
      short8 b = *(const short8*)&Wc[(size_t)(nt*16+m)*128 + kc*32 + 8*q];
      acc[nt] = __builtin_amdgcn_mfma_f32_16x16x32_bf16(a, b, acc[nt], 0,0,0);
    }
  }
  #pragma unroll
  for (int nt=0; nt<8; nt++){
    int col = nt*16 + m;
    float bias = teb[col];
    #pragma unroll
    for (int i=0;i<4;i++){
      int lr = 16*w + 4*q + i;
      int rr = row0 + lr;
      if (rr<M){
        float hv = bf2f(XsH[lr*LSTRIDE + col]);
        float xo = bf2f(XsX[lr*LSTRIDE + col]);
        float g = sigm(acc[nt][i] + bias);
        x[(size_t)rr*128 + col] = g*hv + (1.f-g)*xo;
      }
    }
  }
}

// ---------------- Y[M,20] = X[M,128] @ W[128,20] (fp32) ----------------
__global__ __launch_bounds__(256) void k_gemm_out(const float* __restrict__ X,
    const float* __restrict__ W, float* __restrict__ Y, int M){
  __shared__ float Ws[DIM*OUTC];
  __shared__ float Xs2[8*DIM];
  int tid=threadIdx.x;
  for (int i=tid;i<DIM*OUTC;i+=256) Ws[i]=W[i];
  int row0=blockIdx.x*8;
  {
    int r = tid>>5, kq = tid&31;
    float4 v = make_float4(0.f,0.f,0.f,0.f);
    if (row0+r<M) v = ((const float4*)X)[(size_t)(row0+r)*32+kq];
    *(float4*)&Xs2[r*DIM+kq*4]=v;
  }
  __syncthreads();
  int c = tid&31, rl=tid>>5;
  if (c<OUTC && row0+rl<M){
    float acc=0.f;
    #pragma unroll 8
    for (int k=0;k<DIM;k++) acc += Xs2[rl*DIM+k]*Ws[k*OUTC+c];
    Y[(size_t)(row0+rl)*OUTC+c]=acc;
  }
}

// -------- SpMM gather (contiguous per-node edges) + fused BN stats --------
__global__ __launch_bounds__(256) void k_spmm128(const unsigned short* __restrict__ sup,
    const unsigned int* __restrict__ sedge, const int* __restrict__ offs8,
    float* __restrict__ h, int lbase, float* __restrict__ stL){
  int nl = threadIdx.x>>5;
  int node = blockIdx.x*8 + nl;
  int fq = threadIdx.x & 31;
  int seg = (lbase + node)*8;
  int p = offs8[seg], end = offs8[seg+8];
  float4 a0 = make_float4(0.f,0.f,0.f,0.f), a1 = a0;
  for (; p+1<end; p+=2){
    unsigned int e0 = __builtin_nontemporal_load(sedge+p);
    unsigned int e1 = __builtin_nontemporal_load(sedge+p+1);
    float w0 = __half2float(__ushort_as_half((unsigned short)(e0>>16)));
    float w1 = __half2float(__ushort_as_half((unsigned short)(e1>>16)));
    ushort4 s0 = *(const ushort4*)(sup + (size_t)(e0&0xFFFFu)*128 + fq*4);
    ushort4 s1 = *(const ushort4*)(sup + (size_t)(e1&0xFFFFu)*128 + fq*4);
    a0.x += w0*bf2f(s0.x); a0.y += w0*bf2f(s0.y); a0.z += w0*bf2f(s0.z); a0.w += w0*bf2f(s0.w);
    a1.x += w1*bf2f(s1.x); a1.y += w1*bf2f(s1.y); a1.z += w1*bf2f(s1.z); a1.w += w1*bf2f(s1.w);
  }
  if (p<end){
    unsigned int e0 = __builtin_nontemporal_load(sedge+p);
    float w0 = __half2float(__ushort_as_half((unsigned short)(e0>>16)));
    ushort4 s0 = *(const ushort4*)(sup + (size_t)(e0&0xFFFFu)*128 + fq*4);
    a0.x += w0*bf2f(s0.x); a0.y += w0*bf2f(s0.y); a0.z += w0*bf2f(s0.z); a0.w += w0*bf2f(s0.w);
  }
  a0.x+=a1.x; a0.y+=a1.y; a0.z+=a1.z; a0.w+=a1.w;
  ((float4*)h)[(size_t)node*32+fq] = a0;
  // fused BN stats: block partials over its 8 nodes, then replicated atomics
  __shared__ float sP[8][132], sQ[8][132];
  int f0 = fq*4;
  sP[nl][f0+0]=a0.x; sP[nl][f0+1]=a0.y; sP[nl][f0+2]=a0.z; sP[nl][f0+3]=a0.w;
  sQ[nl][f0+0]=a0.x*a0.x; sQ[nl][f0+1]=a0.y*a0.y; sQ[nl][f0+2]=a0.z*a0.z; sQ[nl][f0+3]=a0.w*a0.w;
  __syncthreads();
  if (threadIdx.x < 128){
    int f = threadIdx.x;
    float s=0.f, sq=0.f;
    #pragma unroll
    for (int n=0;n<8;n++){ s += sP[n][f]; sq += sQ[n][f]; }
    float* base = stL + (blockIdx.x & (NREP-1))*256;
    atomicAdd(&base[f], s); atomicAdd(&base[128+f], sq);
  }
}

__global__ __launch_bounds__(256) void k_spmm_out(const float* __restrict__ sup,
    const unsigned int* __restrict__ sedge, const int* __restrict__ offs8,
    float* __restrict__ h, int lbase){
  int node = blockIdx.x*8 + (threadIdx.x>>5);
  int c = threadIdx.x & 31;
  int seg = (lbase + node)*8;
  int p = offs8[seg], end = offs8[seg+8];
  float acc=0.f;
  for (; p<end; p++){
    unsigned int e = __builtin_nontemporal_load(sedge+p);
    float w = __half2float(__ushort_as_half((unsigned short)(e>>16)));
    if (c<OUTC) acc += w*sup[(size_t)(e&0xFFFFu)*OUTC+c];
  }
  if (c<OUTC) h[(size_t)node*OUTC+c]=acc;
}

// ---------------- output-layer BN stats (8-way replicated) ----------------
__global__ __launch_bounds__(256) void k_bn_stats_out(const float* __restrict__ h,
    float* __restrict__ st8, int rpb){
  int f = threadIdx.x % 32;
  int g = threadIdx.x / 32;
  float s=0.f, ss=0.f;
  int r0 = blockIdx.x*rpb;
  int r1 = min(NN, r0+rpb);
  if (f < OUTC){
    for (int r=r0+g; r<r1; r+=8){ float v = h[(size_t)r*OUTC+f]; s+=v; ss+=v*v; }
  }
  __shared__ float sh[256], sh2[256];
  sh[threadIdx.x]=s; sh2[threadIdx.x]=ss; __syncthreads();
  if (threadIdx.x < 32){
    #pragma unroll
    for (int i=1;i<8;i++){ s+=sh[threadIdx.x+i*32]; ss+=sh2[threadIdx.x+i*32]; }
    if (f<OUTC){
      float* base = st8 + (blockIdx.x&7)*64;
      atomicAdd(&base[f], s); atomicAdd(&base[32+f], ss);
    }
  }
}

__global__ void k_bn_reduce8(const float* __restrict__ st8, float* __restrict__ st){
  int f = threadIdx.x;          // 64
  float s=0.f;
  #pragma unroll
  for (int g=0; g<8; g++) s += st8[g*64+f];
  st[f]=s;
}

__global__ void k_bn_out(float* __restrict__ h, const float* __restrict__ st,
    const float* __restrict__ gamma, const float* __restrict__ beta){
  int gid = blockIdx.x*256+threadIdx.x;
  if (gid>=NN*OUTC) return;
  int f = gid % OUTC;
  const float invN = 1.0f/NN;
  float m = st[f]*invN;
  float var = st[32+f]*invN - m*m;
  float sc = rsqrtf(var+BN_EPS)*gamma[f];
  h[gid] = fmaxf((h[gid]-m)*sc + beta[f], 0.f);
}

// ---------------- final masked reduce (8-way replicated) ----------------
__global__ __launch_bounds__(256) void k_reduce(const float* __restrict__ xf,
    const int* __restrict__ verts, const float* __restrict__ mw,
    float* __restrict__ acc8, int rpb){
  int c = threadIdx.x & 31, g = threadIdx.x >> 5;
  int r0 = blockIdx.x*rpb;
  int r1 = min(NN, r0+rpb);
  float s=0.f;
  for (int r=r0+g; r<r1; r+=8){
    float m = mw[verts[r]];
    if (c<OUTC) s += m * xf[(size_t)r*OUTC+c];
  }
  __shared__ float sh[256];
  sh[threadIdx.x]=s; __syncthreads();
  if (threadIdx.x<32){
    #pragma unroll
    for (int i=1;i<8;i++) s += sh[threadIdx.x + i*32];
    if (c<OUTC) atomicAdd(&acc8[(blockIdx.x&7)*32 + c], s);
  }
}

__global__ void k_final(const float* __restrict__ acc8, const float* __restrict__ mb,
                        float* __restrict__ out){
  int c=threadIdx.x;
  if (c<OUTC){
    float s=0.f;
    #pragma unroll
    for (int g=0; g<8; g++) s += acc8[g*32+c];
    out[c] = sigm(s+mb[c]);
  }
}

// ---------------- host ----------------
extern "C" void kernel_launch(void* const* d_in, const int* in_sizes, int n_in,
                              void* d_out, int out_size, void* d_ws, size_t ws_size,
                              hipStream_t stream){
  const int*   verts = (const int*)d_in[0];
  const int*   ei    = (const int*)d_in[1];
  const float* ew    = (const float*)d_in[2];
  const float* emb   = (const float*)d_in[3];
  const float* wh    = (const float*)d_in[4];
  const float* w_out = (const float*)d_in[6];
  const float* bng_h = (const float*)d_in[8];
  const float* bnb_h = (const float*)d_in[9];
  const float* bng_o = (const float*)d_in[10];
  const float* bnb_o = (const float*)d_in[11];
  const float* tewl  = (const float*)d_in[12];
  const float* tewc  = (const float*)d_in[13];
  const float* teb   = (const float*)d_in[14];
  const float* maskw = (const float*)d_in[15];
  const float* maskb = (const float*)d_in[16];
  float* out = (float*)d_out;

  char* ws = (char*)d_ws;
  size_t off=0;
  auto alloc=[&](size_t bytes)->char*{ char* p = ws+off; off += (bytes+255)&~(size_t)255; return p; };
  unsigned int* sedge = (unsigned int*)alloc(sizeof(int)*LE);   // 22.4 MB
  int*   offs8  = (int*)  alloc(sizeof(int)*(N8+1));            // 11.2 MB
  int*   cnt8   = (int*)  alloc(sizeof(int)*N8);                // 11.2 MB
  unsigned short* rk = (unsigned short*)alloc(sizeof(short)*LE);// 11.2 MB
  int*   bsums  = (int*)  alloc(sizeof(int)*1024);
  float* x      = (float*)alloc(sizeof(float)*NN*DIM);          // 25.6 MB
  unsigned short* supbf = (unsigned short*)alloc(sizeof(short)*NN*DIM); // 12.8 MB
  float* bufC   = (float*)alloc(sizeof(float)*NN*DIM);          // 25.6 MB
  float* buf20  = (float*)alloc(sizeof(float)*NN*OUTC);         // 4 MB
  unsigned short* Wt = (unsigned short*)alloc(sizeof(short)*18*DIM*DIM);
  const int STATSZ = 6*NREP*256 + 8*64 + 64 + 8*32;
  float* stats  = (float*)alloc(sizeof(float)*STATSZ);
  float* ostat8 = stats + 6*NREP*256;  // [8][64]
  float* ostat  = ostat8 + 8*64;       // [64]
  float* racc8  = ostat + 64;          // [8][32]

  // --- preprocessing ---
  hipMemsetAsync(cnt8, 0, sizeof(int)*N8, stream);
  hipMemsetAsync(stats, 0, sizeof(float)*STATSZ, stream);
  k_prep_w<<<1152,256,0,stream>>>(wh, tewl, tewc, Wt);
  k_hist8<<<LL*3125,256,0,stream>>>(ei, cnt8, rk);
  int nsb = (N8+4095)/4096;  // 684
  k_scan1<<<nsb,256,0,stream>>>(cnt8, offs8, bsums, N8);
  k_scan2<<<1,1024,0,stream>>>(bsums, nsb);
  k_scan3<<<(N8+255)/256,256,0,stream>>>(offs8, bsums, N8);
  k_scatter_nr<<<LL*3125,256,0,stream>>>(ei, ew, rk, offs8, sedge);
  k_gather_emb<<<NN*32/256,256,0,stream>>>(verts, emb, x);

  // --- 6 hidden layers ---
  for (int i=0;i<6;i++){
    int j = (i==0)?5:(i-1);
    float* stL = stats + i*NREP*256;
    k_gemm_sup<<<(NN+63)/64,256,0,stream>>>(x, Wt + (size_t)i*DIM*DIM, supbf, NN);
    k_spmm128<<<NN/8,256,0,stream>>>(supbf, sedge, offs8, bufC, i*NN, stL);
    k_gemm_gate2<<<(NN+63)/64,256,0,stream>>>(bufC, stL,
        bng_h+(size_t)i*DIM, bnb_h+(size_t)i*DIM,
        Wt + (size_t)(6+j)*DIM*DIM, Wt + (size_t)(12+j)*DIM*DIM,
        teb + (size_t)j*DIM, x, NN);
  }

  // --- output layer (fp32 throughout) ---
  k_gemm_out<<<(NN+7)/8,256,0,stream>>>(x, w_out, buf20, NN);
  k_spmm_out<<<NN/8,256,0,stream>>>(buf20, sedge, offs8, bufC, 6*NN);
  k_bn_stats_out<<<512,256,0,stream>>>(bufC, ostat8, 98);
  k_bn_reduce8<<<1,64,0,stream>>>(ostat8, ostat);
  k_bn_out<<<(NN*OUTC+255)/256,256,0,stream>>>(bufC, ostat, bng_o, bnb_o);
  k_reduce<<<512,256,0,stream>>>(bufC, verts, maskw, racc8, 98);
  k_final<<<1,64,0,stream>>>(racc8, maskb, out);
}

// Round 8
// 1144.776 us; speedup vs baseline: 2.6498x; 1.1694x over previous
//
#include <hip/hip_runtime.h>
#include <hip/hip_fp16.h>

#define NN 50000
#define EE 800000
#define DIM 128
#define OUTC 20
#define LL 7
#define LE (LL*EE)
#define LN (LL*NN)
#define BN_EPS 1e-5f
#define LSTRIDE 136     // bf16 elems per LDS row
#define NREP 64         // BN stat replicas
#define NBUK 391        // coarse buckets of 128 dsts per layer
#define NBLK 128        // edge-blocks per layer (EE/NBLK = 6250)
#define CH   6250
#define SCN  (LL*NBUK*NBLK)   // 350336 scan entries

typedef __attribute__((ext_vector_type(8))) short short8;
typedef __attribute__((ext_vector_type(4))) float f32x4;

static __device__ __forceinline__ float sigm(float z){ return 1.0f/(1.0f+expf(-z)); }
static __device__ __forceinline__ unsigned short f2bf(float f){
  unsigned int u = __float_as_uint(f);
  u += 0x7FFF + ((u>>16)&1);            // RNE
  return (unsigned short)(u>>16);
}
static __device__ __forceinline__ float bf2f(unsigned short s){
  return __uint_as_float(((unsigned int)s)<<16);
}

// ======== preprocessing: counting sort, ALL atomics in LDS ========

// P1: per-(layer,block) LDS histogram over 391 coarse buckets
__global__ __launch_bounds__(256) void k_bh(const int* __restrict__ ei,
    int* __restrict__ Gm){
  int l = blockIdx.x >> 7, b = blockIdx.x & 127;
  int t = threadIdx.x;
  __shared__ int h[392];
  for (int i=t;i<392;i+=256) h[i]=0;
  __syncthreads();
  const int* dsts = ei + (size_t)(2*l+1)*EE + b*CH;
  for (int k=t; k<CH; k+=256) atomicAdd(&h[dsts[k]>>7], 1);
  __syncthreads();
  int* g = Gm + (size_t)(l*NBLK+b)*392;
  for (int i=t;i<NBUK;i+=256) g[i]=h[i];
}

// P2: exclusive scan over (l,buk,b) enumeration of Gm[(l,b),buk]
__global__ __launch_bounds__(256) void k_scan1p(const int* __restrict__ Gm,
    int* __restrict__ part, int* __restrict__ bsums){
  __shared__ int s[256];
  int t = threadIdx.x;
  int base = blockIdx.x*4096 + t*16;
  int v[16]; int sum = 0;
  #pragma unroll
  for (int i=0;i<16;i++){
    int idx = base+i; int val = 0;
    if (idx < SCN){
      int l = idx/(NBUK*NBLK);
      int r = idx - l*(NBUK*NBLK);
      int buk = r>>7, b = r&127;
      val = Gm[(size_t)(l*NBLK+b)*392 + buk];
    }
    v[i]=val; sum+=val;
  }
  s[t]=sum; __syncthreads();
  for (int off=1; off<256; off<<=1){
    int x = (t>=off)? s[t-off] : 0;
    __syncthreads(); s[t]+=x; __syncthreads();
  }
  if (t==255) bsums[blockIdx.x] = s[255];
  int run = s[t]-sum;
  #pragma unroll
  for (int i=0;i<16;i++){ if (base+i<SCN) part[base+i]=run; run += v[i]; }
}

__global__ __launch_bounds__(1024) void k_scan2(int* bsums, int nb){
  __shared__ int s[1024];
  int t=threadIdx.x;
  int v = (t<nb)? bsums[t]:0;
  s[t]=v; __syncthreads();
  for (int off=1; off<1024; off<<=1){
    int x=(t>=off)? s[t-off]:0; __syncthreads(); s[t]+=x; __syncthreads();
  }
  if (t<nb) bsums[t] = s[t]-v;
}

__global__ void k_scan3(int* __restrict__ S, const int* __restrict__ bsums){
  int gid = blockIdx.x*256+threadIdx.x;
  if (gid < SCN) S[gid] += bsums[gid>>12];
  if (gid==0) S[SCN]=LE;
}

// P3: bin edges to bucket-major btmp via LDS cursors (atomic-free in global)
__global__ __launch_bounds__(256) void k_bscatter(const int* __restrict__ ei,
    const float* __restrict__ ew, const int* __restrict__ S,
    uint2* __restrict__ btmp){
  int l = blockIdx.x >> 7, b = blockIdx.x & 127;
  int t = threadIdx.x;
  __shared__ int cur[392];
  for (int i=t;i<NBUK;i+=256) cur[i] = S[(size_t)(l*NBUK+i)*128 + b];
  __syncthreads();
  const int* srcs = ei + (size_t)(2*l)*EE + b*CH;
  const int* dsts = ei + (size_t)(2*l+1)*EE + b*CH;
  const float* ws = ew + (size_t)l*EE + b*CH;
  for (int k=t; k<CH; k+=256){
    int dst = dsts[k];
    int src = srcs[k];
    float w = ws[k];
    int p = atomicAdd(&cur[dst>>7], 1);
    btmp[p] = make_uint2((unsigned int)src | ((unsigned int)(dst&127)<<16),
                         __float_as_uint(w));
  }
}

// P4: per-bucket final sort in LDS -> sedge (4B packed) + offs (contiguous CSR)
__global__ __launch_bounds__(256) void k_fsort(const uint2* __restrict__ btmp,
    const int* __restrict__ S, unsigned int* __restrict__ sedge,
    int* __restrict__ offs){
  int lbuk = blockIdx.x;                 // 0..2736
  int l = lbuk/NBUK, bl = lbuk - l*NBUK;
  int t = threadIdx.x;
  int base = S[(size_t)lbuk*128];
  int end  = S[(size_t)(lbuk+1)*128];
  int nE = end - base;
  __shared__ uint2 eb[4096];             // 32 KB; mean 2046, +45 sigma safe
  __shared__ int cnt[132], sc[132];
  if (t<132){ cnt[t]=0; }
  __syncthreads();
  for (int k=t; k<nE; k+=256){
    uint2 v = btmp[base+k];
    eb[k]=v;
    atomicAdd(&cnt[(v.x>>16)&127], 1);
  }
  __syncthreads();
  int c = (t<128)? cnt[t] : 0;
  if (t<128) sc[t]=c;
  __syncthreads();
  for (int o=1;o<128;o<<=1){
    int v = (t<128 && t>=o)? sc[t-o]:0;
    __syncthreads();
    if (t<128) sc[t]+=v;
    __syncthreads();
  }
  if (t<128){
    int excl = sc[t]-c;
    int node = bl*128+t;
    if (node<NN) offs[(size_t)l*NN+node] = base + excl;
    cnt[t] = base + excl;                // becomes cursor
  }
  if (lbuk==0 && t==255) offs[LN]=LE;
  __syncthreads();
  for (int k=t; k<nE; k+=256){
    uint2 v = eb[k];
    int d = (v.x>>16)&127;
    int r = atomicAdd(&cnt[d],1);
    unsigned short hw = __half_as_ushort(__float2half(__uint_as_float(v.y)));
    sedge[r] = (v.x & 0xFFFFu) | ((unsigned int)hw<<16);
  }
}

__global__ void k_gather_emb(const int* __restrict__ verts, const float* __restrict__ emb,
                             float* __restrict__ x){
  int gid = blockIdx.x*256+threadIdx.x;
  int n = gid>>5, q = gid&31;
  if (n>=NN) return;
  int v = verts[n];
  ((float4*)x)[gid] = ((const float4*)emb)[(size_t)v*32+q];
}

// ---- transpose + bf16-convert all 18 hidden weight matrices: Wt[m][n][k] ----
__global__ __launch_bounds__(256) void k_prep_w(const float* __restrict__ wh,
    const float* __restrict__ tewl, const float* __restrict__ tewc,
    unsigned short* __restrict__ Wt){
  int gid = blockIdx.x*256+threadIdx.x;          // 18*16384
  int m = gid>>14; int idx = gid&16383;
  int n = idx>>7, k = idx&127;
  const float* src = (m<6)? wh + (size_t)m*16384
                   : (m<12)? tewl + (size_t)(m-6)*16384
                   : tewc + (size_t)(m-12)*16384;
  Wt[gid] = f2bf(src[k*128+n]);
}

// stage 64 fp32 rows -> bf16 LDS tile [64][LSTRIDE]
static __device__ __forceinline__ void stage64(const float* __restrict__ src,
    int row0, int M, unsigned short* Xs, int tid){
  #pragma unroll
  for (int it=0; it<4; it++){
    int idx = tid + it*256;
    int r = idx>>4, k8 = idx&15;
    float4 v0 = make_float4(0.f,0.f,0.f,0.f), v1 = v0;
    if (row0+r < M){
      const float4* p = (const float4*)src + (size_t)(row0+r)*32 + k8*2;
      v0 = p[0]; v1 = p[1];
    }
    short8 w;
    w[0]=(short)f2bf(v0.x); w[1]=(short)f2bf(v0.y); w[2]=(short)f2bf(v0.z); w[3]=(short)f2bf(v0.w);
    w[4]=(short)f2bf(v1.x); w[5]=(short)f2bf(v1.y); w[6]=(short)f2bf(v1.z); w[7]=(short)f2bf(v1.w);
    *(short8*)&Xs[r*LSTRIDE + k8*8] = w;
  }
}

// ---------------- MFMA GEMM: Ybf16[M,128] = bf16(X[M,128]) @ Wt ----------------
__global__ __launch_bounds__(256) void k_gemm_sup(const float* __restrict__ X,
    const unsigned short* __restrict__ Wt, unsigned short* __restrict__ Y, int M){
  __shared__ unsigned short Xs[64*LSTRIDE];
  int tid = threadIdx.x;
  int row0 = blockIdx.x*64;
  stage64(X, row0, M, Xs, tid);
  __syncthreads();
  int w = tid>>6, lane = tid&63, m = lane&15, q = lane>>4;
  f32x4 acc[8];
  #pragma unroll
  for (int nt=0;nt<8;nt++){ acc[nt][0]=0.f; acc[nt][1]=0.f; acc[nt][2]=0.f; acc[nt][3]=0.f; }
  #pragma unroll
  for (int kc=0; kc<4; kc++){
    short8 a = *(const short8*)&Xs[(16*w+m)*LSTRIDE + kc*32 + 8*q];
    #pragma unroll
    for (int nt=0; nt<8; nt++){
      short8 b = *(const short8*)&Wt[(size_t)(nt*16+m)*128 + kc*32 + 8*q];
      acc[nt] = __builtin_amdgcn_mfma_f32_16x16x32_bf16(a, b, acc[nt], 0,0,0);
    }
  }
  #pragma unroll
  for (int nt=0; nt<8; nt++){
    #pragma unroll
    for (int i=0;i<4;i++){
      int rr = row0 + 16*w + 4*q + i;
      if (rr<M) Y[(size_t)rr*128 + nt*16 + m] = f2bf(acc[nt][i]);
    }
  }
}

// ------- fused: BN(h)+ReLU -> bf16 LDS; dual MFMA (x@te_wl + hn@te_wc); gate -------
__global__ __launch_bounds__(256) void k_gemm_gate2(const float* __restrict__ H,
    const float* __restrict__ stL,            // NREP replicas [rep][sum128|sq128]
    const float* __restrict__ gamma, const float* __restrict__ beta,
    const unsigned short* __restrict__ Wl, const unsigned short* __restrict__ Wc,
    const float* __restrict__ teb, float* __restrict__ x, int M){
  __shared__ unsigned short XsX[64*LSTRIDE];
  __shared__ unsigned short XsH[64*LSTRIDE];
  __shared__ float sSc[128], sOff[128];
  int tid = threadIdx.x;
  int row0 = blockIdx.x*64;
  if (tid<128){
    float s=0.f, sq=0.f;
    #pragma unroll 8
    for (int g=0; g<NREP; g++){ s += stL[g*256+tid]; sq += stL[g*256+128+tid]; }
    float mean = s*(1.0f/NN);
    float var = sq*(1.0f/NN) - mean*mean;
    float sc = rsqrtf(var+BN_EPS)*gamma[tid];
    sSc[tid]=sc; sOff[tid]=beta[tid]-mean*sc;
  }
  stage64(x, row0, M, XsX, tid);
  __syncthreads();
  #pragma unroll
  for (int it=0; it<4; it++){
    int idx = tid + it*256;
    int r = idx>>4, k8 = idx&15;
    float4 v0 = make_float4(0.f,0.f,0.f,0.f), v1 = v0;
    if (row0+r < M){
      const float4* p = (const float4*)H + (size_t)(row0+r)*32 + k8*2;
      v0 = p[0]; v1 = p[1];
    }
    int k = k8*8;
    float o[8] = {v0.x,v0.y,v0.z,v0.w,v1.x,v1.y,v1.z,v1.w};
    short8 w;
    #pragma unroll
    for (int j=0;j<8;j++){
      float hn = fmaxf(fmaf(o[j], sSc[k+j], sOff[k+j]), 0.f);
      w[j] = (short)f2bf(hn);
    }
    *(short8*)&XsH[r*LSTRIDE + k8*8] = w;
  }
  __syncthreads();
  int w = tid>>6, lane = tid&63, m = lane&15, q = lane>>4;
  f32x4 acc[8];
  #pragma unroll
  for (int nt=0;nt<8;nt++){ acc[nt][0]=0.f; acc[nt][1]=0.f; acc[nt][2]=0.f; acc[nt][3]=0.f; }
  #pragma unroll
  for (int kc=0; kc<4; kc++){
    short8 a = *(const short8*)&XsX[(16*w+m)*LSTRIDE + kc*32 + 8*q];
    #pragma unroll
    for (int nt=0; nt<8; nt++){
      short8 b = *(const short8*)&Wl[(size_t)(nt*16+m)*128 + kc*32 + 8*q];
      acc[nt] = __builtin_amdgcn_mfma_f32_16x16x32_bf16(a, b, acc[nt], 0,0,0);
    }
  }
  #pragma unroll
  for (int kc=0; kc<4; kc++){
    short8 a = *(const short8*)&XsH[(16*w+m)*LSTRIDE + kc*32 + 8*q];
    #pragma unroll
    for (int nt=0; nt<8; nt++){
      short8 b = *(const short8*)&Wc[(size_t)(nt*16+m)*128 + kc*32 + 8*q];
      acc[nt] = __builtin_amdgcn_mfma_f32_16x16x32_bf16(a, b, acc[nt], 0,0,0);
    }
  }
  #pragma unroll
  for (int nt=0; nt<8; nt++){
    int col = nt*16 + m;
    float bias = teb[col];
    #pragma unroll
    for (int i=0;i<4;i++){
      int lr = 16*w + 4*q + i;
      int rr = row0 + lr;
      if (rr<M){
        float hv = bf2f(XsH[lr*LSTRIDE + col]);
        float xo = bf2f(XsX[lr*LSTRIDE + col]);
        float g = sigm(acc[nt][i] + bias);
        x[(size_t)rr*128 + col] = g*hv + (1.f-g)*xo;
      }
    }
  }
}

// ---------------- Y[M,20] = X[M,128] @ W[128,20] (fp32) ----------------
__global__ __launch_bounds__(256) void k_gemm_out(const float* __restrict__ X,
    const float* __restrict__ W, float* __restrict__ Y, int M){
  __shared__ float Ws[DIM*OUTC];
  __shared__ float Xs2[8*DIM];
  int tid=threadIdx.x;
  for (int i=tid;i<DIM*OUTC;i+=256) Ws[i]=W[i];
  int row0=blockIdx.x*8;
  {
    int r = tid>>5, kq = tid&31;
    float4 v = make_float4(0.f,0.f,0.f,0.f);
    if (row0+r<M) v = ((const float4*)X)[(size_t)(row0+r)*32+kq];
    *(float4*)&Xs2[r*DIM+kq*4]=v;
  }
  __syncthreads();
  int c = tid&31, rl=tid>>5;
  if (c<OUTC && row0+rl<M){
    float acc=0.f;
    #pragma unroll 8
    for (int k=0;k<DIM;k++) acc += Xs2[rl*DIM+k]*Ws[k*OUTC+c];
    Y[(size_t)(row0+rl)*OUTC+c]=acc;
  }
}

// -------- SpMM gather (contiguous per-node edges) + fused BN stats --------
__global__ __launch_bounds__(256) void k_spmm128(const unsigned short* __restrict__ sup,
    const unsigned int* __restrict__ sedge, const int* __restrict__ offs,
    float* __restrict__ h, int lbase, float* __restrict__ stL){
  int nl = threadIdx.x>>5;
  int node = blockIdx.x*8 + nl;
  int fq = threadIdx.x & 31;
  int p = offs[lbase+node], end = offs[lbase+node+1];
  float4 a0 = make_float4(0.f,0.f,0.f,0.f), a1 = a0;
  for (; p+1<end; p+=2){
    unsigned int e0 = __builtin_nontemporal_load(sedge+p);
    unsigned int e1 = __builtin_nontemporal_load(sedge+p+1);
    float w0 = __half2float(__ushort_as_half((unsigned short)(e0>>16)));
    float w1 = __half2float(__ushort_as_half((unsigned short)(e1>>16)));
    ushort4 s0 = *(const ushort4*)(sup + (size_t)(e0&0xFFFFu)*128 + fq*4);
    ushort4 s1 = *(const ushort4*)(sup + (size_t)(e1&0xFFFFu)*128 + fq*4);
    a0.x += w0*bf2f(s0.x); a0.y += w0*bf2f(s0.y); a0.z += w0*bf2f(s0.z); a0.w += w0*bf2f(s0.w);
    a1.x += w1*bf2f(s1.x); a1.y += w1*bf2f(s1.y); a1.z += w1*bf2f(s1.z); a1.w += w1*bf2f(s1.w);
  }
  if (p<end){
    unsigned int e0 = __builtin_nontemporal_load(sedge+p);
    float w0 = __half2float(__ushort_as_half((unsigned short)(e0>>16)));
    ushort4 s0 = *(const ushort4*)(sup + (size_t)(e0&0xFFFFu)*128 + fq*4);
    a0.x += w0*bf2f(s0.x); a0.y += w0*bf2f(s0.y); a0.z += w0*bf2f(s0.z); a0.w += w0*bf2f(s0.w);
  }
  a0.x+=a1.x; a0.y+=a1.y; a0.z+=a1.z; a0.w+=a1.w;
  ((float4*)h)[(size_t)node*32+fq] = a0;
  // fused BN stats: block partials over its 8 nodes, then replicated atomics
  __shared__ float sP[8][132], sQ[8][132];
  int f0 = fq*4;
  sP[nl][f0+0]=a0.x; sP[nl][f0+1]=a0.y; sP[nl][f0+2]=a0.z; sP[nl][f0+3]=a0.w;
  sQ[nl][f0+0]=a0.x*a0.x; sQ[nl][f0+1]=a0.y*a0.y; sQ[nl][f0+2]=a0.z*a0.z; sQ[nl][f0+3]=a0.w*a0.w;
  __syncthreads();
  if (threadIdx.x < 128){
    int f = threadIdx.x;
    float s=0.f, sq=0.f;
    #pragma unroll
    for (int n=0;n<8;n++){ s += sP[n][f]; sq += sQ[n][f]; }
    float* base = stL + (blockIdx.x & (NREP-1))*256;
    atomicAdd(&base[f], s); atomicAdd(&base[128+f], sq);
  }
}

__global__ __launch_bounds__(256) void k_spmm_out(const float* __restrict__ sup,
    const unsigned int* __restrict__ sedge, const int* __restrict__ offs,
    float* __restrict__ h, int lbase){
  int node = blockIdx.x*8 + (threadIdx.x>>5);
  int c = threadIdx.x & 31;
  int p = offs[lbase+node], end = offs[lbase+node+1];
  float acc=0.f;
  for (; p<end; p++){
    unsigned int e = __builtin_nontemporal_load(sedge+p);
    float w = __half2float(__ushort_as_half((unsigned short)(e>>16)));
    if (c<OUTC) acc += w*sup[(size_t)(e&0xFFFFu)*OUTC+c];
  }
  if (c<OUTC) h[(size_t)node*OUTC+c]=acc;
}

// ---------------- output-layer BN stats (8-way replicated) ----------------
__global__ __launch_bounds__(256) void k_bn_stats_out(const float* __restrict__ h,
    float* __restrict__ st8, int rpb){
  int f = threadIdx.x % 32;
  int g = threadIdx.x / 32;
  float s=0.f, ss=0.f;
  int r0 = blockIdx.x*rpb;
  int r1 = min(NN, r0+rpb);
  if (f < OUTC){
    for (int r=r0+g; r<r1; r+=8){ float v = h[(size_t)r*OUTC+f]; s+=v; ss+=v*v; }
  }
  __shared__ float sh[256], sh2[256];
  sh[threadIdx.x]=s; sh2[threadIdx.x]=ss; __syncthreads();
  if (threadIdx.x < 32){
    #pragma unroll
    for (int i=1;i<8;i++){ s+=sh[threadIdx.x+i*32]; ss+=sh2[threadIdx.x+i*32]; }
    if (f<OUTC){
      float* base = st8 + (blockIdx.x&7)*64;
      atomicAdd(&base[f], s); atomicAdd(&base[32+f], ss);
    }
  }
}

__global__ void k_bn_reduce8(const float* __restrict__ st8, float* __restrict__ st){
  int f = threadIdx.x;          // 64
  float s=0.f;
  #pragma unroll
  for (int g=0; g<8; g++) s += st8[g*64+f];
  st[f]=s;
}

__global__ void k_bn_out(float* __restrict__ h, const float* __restrict__ st,
    const float* __restrict__ gamma, const float* __restrict__ beta){
  int gid = blockIdx.x*256+threadIdx.x;
  if (gid>=NN*OUTC) return;
  int f = gid % OUTC;
  const float invN = 1.0f/NN;
  float m = st[f]*invN;
  float var = st[32+f]*invN - m*m;
  float sc = rsqrtf(var+BN_EPS)*gamma[f];
  h[gid] = fmaxf((h[gid]-m)*sc + beta[f], 0.f);
}

// ---------------- final masked reduce (8-way replicated) ----------------
__global__ __launch_bounds__(256) void k_reduce(const float* __restrict__ xf,
    const int* __restrict__ verts, const float* __restrict__ mw,
    float* __restrict__ acc8, int rpb){
  int c = threadIdx.x & 31, g = threadIdx.x >> 5;
  int r0 = blockIdx.x*rpb;
  int r1 = min(NN, r0+rpb);
  float s=0.f;
  for (int r=r0+g; r<r1; r+=8){
    float m = mw[verts[r]];
    if (c<OUTC) s += m * xf[(size_t)r*OUTC+c];
  }
  __shared__ float sh[256];
  sh[threadIdx.x]=s; __syncthreads();
  if (threadIdx.x<32){
    #pragma unroll
    for (int i=1;i<8;i++) s += sh[threadIdx.x + i*32];
    if (c<OUTC) atomicAdd(&acc8[(blockIdx.x&7)*32 + c], s);
  }
}

__global__ void k_final(const float* __restrict__ acc8, const float* __restrict__ mb,
                        float* __restrict__ out){
  int c=threadIdx.x;
  if (c<OUTC){
    float s=0.f;
    #pragma unroll
    for (int g=0; g<8; g++) s += acc8[g*32+c];
    out[c] = sigm(s+mb[c]);
  }
}

// ---------------- host ----------------
extern "C" void kernel_launch(void* const* d_in, const int* in_sizes, int n_in,
                              void* d_out, int out_size, void* d_ws, size_t ws_size,
                              hipStream_t stream){
  const int*   verts = (const int*)d_in[0];
  const int*   ei    = (const int*)d_in[1];
  const float* ew    = (const float*)d_in[2];
  const float* emb   = (const float*)d_in[3];
  const float* wh    = (const float*)d_in[4];
  const float* w_out = (const float*)d_in[6];
  const float* bng_h = (const float*)d_in[8];
  const float* bnb_h = (const float*)d_in[9];
  const float* bng_o = (const float*)d_in[10];
  const float* bnb_o = (const float*)d_in[11];
  const float* tewl  = (const float*)d_in[12];
  const float* tewc  = (const float*)d_in[13];
  const float* teb   = (const float*)d_in[14];
  const float* maskw = (const float*)d_in[15];
  const float* maskb = (const float*)d_in[16];
  float* out = (float*)d_out;

  char* ws = (char*)d_ws;
  size_t off=0;
  auto alloc=[&](size_t bytes)->char*{ char* p = ws+off; off += (bytes+255)&~(size_t)255; return p; };
  unsigned int* sedge = (unsigned int*)alloc(sizeof(int)*LE);   // 22.4 MB
  int*   offs   = (int*)  alloc(sizeof(int)*(LN+1));            // 1.4 MB
  int*   Gm     = (int*)  alloc(sizeof(int)*LL*NBLK*392);       // 1.4 MB
  int*   S      = (int*)  alloc(sizeof(int)*(SCN+1));           // 1.4 MB
  int*   bsums  = (int*)  alloc(sizeof(int)*1024);
  float* x      = (float*)alloc(sizeof(float)*NN*DIM);          // 25.6 MB (exact 256-mult)
  unsigned short* supbf = (unsigned short*)alloc(sizeof(short)*NN*DIM); // 12.8 MB
  float* bufC   = (float*)alloc(sizeof(float)*NN*DIM);          // 25.6 MB
  float* buf20  = (float*)alloc(sizeof(float)*NN*OUTC);         // 4 MB
  unsigned short* Wt = (unsigned short*)alloc(sizeof(short)*18*DIM*DIM);
  const int STATSZ = 6*NREP*256 + 8*64 + 64 + 8*32;
  float* stats  = (float*)alloc(sizeof(float)*STATSZ);
  float* ostat8 = stats + 6*NREP*256;  // [8][64]
  float* ostat  = ostat8 + 8*64;       // [64]
  float* racc8  = ostat + 64;          // [8][32]
  // btmp (44.8 MB) aliases x+supbf+bufC head (64 MB contiguous; dead during preproc)
  uint2* btmp   = (uint2*)x;

  // --- preprocessing: 4-pass LDS-atomic counting sort ---
  hipMemsetAsync(stats, 0, sizeof(float)*STATSZ, stream);
  k_prep_w<<<1152,256,0,stream>>>(wh, tewl, tewc, Wt);
  k_bh<<<LL*NBLK,256,0,stream>>>(ei, Gm);
  int nsb = (SCN+4095)/4096;  // 86
  k_scan1p<<<nsb,256,0,stream>>>(Gm, S, bsums);
  k_scan2<<<1,1024,0,stream>>>(bsums, nsb);
  k_scan3<<<(SCN+256)/256,256,0,stream>>>(S, bsums);
  k_bscatter<<<LL*NBLK,256,0,stream>>>(ei, ew, S, btmp);
  k_fsort<<<LL*NBUK,256,0,stream>>>(btmp, S, sedge, offs);
  k_gather_emb<<<NN*32/256,256,0,stream>>>(verts, emb, x);

  // --- 6 hidden layers ---
  for (int i=0;i<6;i++){
    int j = (i==0)?5:(i-1);
    float* stL = stats + i*NREP*256;
    k_gemm_sup<<<(NN+63)/64,256,0,stream>>>(x, Wt + (size_t)i*DIM*DIM, supbf, NN);
    k_spmm128<<<NN/8,256,0,stream>>>(supbf, sedge, offs, bufC, i*NN, stL);
    k_gemm_gate2<<<(NN+63)/64,256,0,stream>>>(bufC, stL,
        bng_h+(size_t)i*DIM, bnb_h+(size_t)i*DIM,
        Wt + (size_t)(6+j)*DIM*DIM, Wt + (size_t)(12+j)*DIM*DIM,
        teb + (size_t)j*DIM, x, NN);
  }

  // --- output layer (fp32 throughout) ---
  k_gemm_out<<<(NN+7)/8,256,0,stream>>>(x, w_out, buf20, NN);
  k_spmm_out<<<NN/8,256,0,stream>>>(buf20, sedge, offs, bufC, 6*NN);
  k_bn_stats_out<<<512,256,0,stream>>>(bufC, ostat8, 98);
  k_bn_reduce8<<<1,64,0,stream>>>(ostat8, ostat);
  k_bn_out<<<(NN*OUTC+255)/256,256,0,stream>>>(bufC, ostat, bng_o, bnb_o);
  k_reduce<<<512,256,0,stream>>>(bufC, verts, maskw, racc8, 98);
  k_final<<<1,64,0,stream>>>(racc8, maskb, out);
}

// Round 9
// 1073.174 us; speedup vs baseline: 2.8266x; 1.0667x over previous
//
#include <hip/hip_runtime.h>
#include <hip/hip_fp16.h>

#define NN 50000
#define EE 800000
#define DIM 128
#define OUTC 20
#define LL 7
#define LE (LL*EE)
#define LN (LL*NN)
#define BN_EPS 1e-5f
#define LSTRIDE 136     // bf16 elems per LDS row
#define NREP 64         // BN stat replicas
#define NBUK 391        // coarse buckets of 128 dsts per layer
#define NBLK 128        // edge-blocks per layer (EE/NBLK = 6250)
#define CH   6250
#define SCN  (LL*NBUK*NBLK)   // 350336 scan entries

typedef __attribute__((ext_vector_type(8))) short short8;
typedef __attribute__((ext_vector_type(4))) float f32x4;

static __device__ __forceinline__ float sigm(float z){ return 1.0f/(1.0f+expf(-z)); }
static __device__ __forceinline__ unsigned short f2bf(float f){
  unsigned int u = __float_as_uint(f);
  u += 0x7FFF + ((u>>16)&1);            // RNE
  return (unsigned short)(u>>16);
}
static __device__ __forceinline__ float bf2f(unsigned short s){
  return __uint_as_float(((unsigned int)s)<<16);
}

// ======== preprocessing: counting sort, all atomics in LDS, streaming writes ========

// P1: per-(layer,block) LDS histogram over 391 coarse buckets
__global__ __launch_bounds__(256) void k_bh(const int* __restrict__ ei,
    int* __restrict__ Gm){
  int l = blockIdx.x >> 7, b = blockIdx.x & 127;
  int t = threadIdx.x;
  __shared__ int h[392];
  for (int i=t;i<392;i+=256) h[i]=0;
  __syncthreads();
  const int* dsts = ei + (size_t)(2*l+1)*EE + b*CH;
  for (int k=t; k<CH; k+=256) atomicAdd(&h[__builtin_nontemporal_load(dsts+k)>>7], 1);
  __syncthreads();
  int* g = Gm + (size_t)(l*NBLK+b)*392;
  for (int i=t;i<NBUK;i+=256) g[i]=h[i];
}

// P2: exclusive scan over (l,buk,b) enumeration of Gm[(l,b),buk]
__global__ __launch_bounds__(256) void k_scan1p(const int* __restrict__ Gm,
    int* __restrict__ part, int* __restrict__ bsums){
  __shared__ int s[256];
  int t = threadIdx.x;
  int base = blockIdx.x*4096 + t*16;
  int v[16]; int sum = 0;
  #pragma unroll
  for (int i=0;i<16;i++){
    int idx = base+i; int val = 0;
    if (idx < SCN){
      int l = idx/(NBUK*NBLK);
      int r = idx - l*(NBUK*NBLK);
      int buk = r>>7, b = r&127;
      val = Gm[(size_t)(l*NBLK+b)*392 + buk];
    }
    v[i]=val; sum+=val;
  }
  s[t]=sum; __syncthreads();
  for (int off=1; off<256; off<<=1){
    int x = (t>=off)? s[t-off] : 0;
    __syncthreads(); s[t]+=x; __syncthreads();
  }
  if (t==255) bsums[blockIdx.x] = s[255];
  int run = s[t]-sum;
  #pragma unroll
  for (int i=0;i<16;i++){ if (base+i<SCN) part[base+i]=run; run += v[i]; }
}

__global__ __launch_bounds__(1024) void k_scan2(int* bsums, int nb){
  __shared__ int s[1024];
  int t=threadIdx.x;
  int v = (t<nb)? bsums[t]:0;
  s[t]=v; __syncthreads();
  for (int off=1; off<1024; off<<=1){
    int x=(t>=off)? s[t-off]:0; __syncthreads(); s[t]+=x; __syncthreads();
  }
  if (t<nb) bsums[t] = s[t]-v;
}

__global__ void k_scan3(int* __restrict__ S, const int* __restrict__ bsums){
  int gid = blockIdx.x*256+threadIdx.x;
  if (gid < SCN) S[gid] += bsums[gid>>12];
  if (gid==0) S[SCN]=LE;
}

// P3: LDS counting-sort by bucket, then contiguous streaming writes per run
__global__ __launch_bounds__(256) void k_bscatter(const int* __restrict__ ei,
    const float* __restrict__ ew, const int* __restrict__ S,
    unsigned int* __restrict__ btmp1, unsigned short* __restrict__ btmp2){
  int l = blockIdx.x >> 7, b = blockIdx.x & 127;
  int t = threadIdx.x;
  __shared__ int cnt[392], bstart[392], cur[392], runb[392];
  __shared__ int ps[256];
  __shared__ unsigned int  eb1[CH];
  __shared__ unsigned short eb2[CH];
  for (int i=t;i<392;i+=256) cnt[i]=0;
  __syncthreads();
  const int* srcs = ei + (size_t)(2*l)*EE + b*CH;
  const int* dsts = ei + (size_t)(2*l+1)*EE + b*CH;
  const float* wsrc = ew + (size_t)l*EE + b*CH;
  for (int k=t;k<CH;k+=256) atomicAdd(&cnt[__builtin_nontemporal_load(dsts+k)>>7],1);
  __syncthreads();
  // exclusive scan over 392 counts (2 per thread)
  int v0 = (2*t<392)? cnt[2*t]:0;
  int v1 = (2*t+1<392)? cnt[2*t+1]:0;
  int sum = v0+v1;
  ps[t]=sum; __syncthreads();
  for (int o=1;o<256;o<<=1){ int x=(t>=o)?ps[t-o]:0; __syncthreads(); ps[t]+=x; __syncthreads(); }
  int run = ps[t]-sum;
  if (2*t<392){ bstart[2*t]=run; cur[2*t]=run; }
  if (2*t+1<392){ bstart[2*t+1]=run+v0; cur[2*t+1]=run+v0; }
  for (int i=t;i<NBUK;i+=256) runb[i] = S[(size_t)(l*NBUK+i)*128 + b];
  __syncthreads();
  // place edges into LDS in bucket order
  for (int k=t;k<CH;k+=256){
    int dst = dsts[k];
    int src = srcs[k];
    float w = wsrc[k];
    int buk = dst>>7;
    int pos = atomicAdd(&cur[buk],1);
    eb1[pos] = (unsigned)src | ((unsigned)(dst&127)<<16) | ((unsigned)buk<<23);
    eb2[pos] = __half_as_ushort(__float2half(w));
  }
  __syncthreads();
  // streaming write: each bucket run is contiguous in both LDS and global
  for (int k=t;k<CH;k+=256){
    unsigned e1 = eb1[k];
    int buk = e1>>23;
    int gp = runb[buk] + (k - bstart[buk]);
    btmp1[gp] = e1;
    btmp2[gp] = eb2[k];
  }
}

// P4: per-bucket final sort in LDS -> sedge (4B packed) + offs (contiguous CSR)
__global__ __launch_bounds__(256) void k_fsort(const unsigned int* __restrict__ btmp1,
    const unsigned short* __restrict__ btmp2, const int* __restrict__ S,
    unsigned int* __restrict__ sedge, int* __restrict__ offs){
  int lbuk = blockIdx.x;                 // 0..2736
  int l = lbuk/NBUK, bl = lbuk - l*NBUK;
  int t = threadIdx.x;
  int base = S[(size_t)lbuk*128];
  int end  = S[(size_t)(lbuk+1)*128];
  int nE = end - base;
  __shared__ unsigned int  eb1[4096];    // 16 KB; mean 2046, +45 sigma safe
  __shared__ unsigned short eb2[4096];   // 8 KB
  __shared__ int cnt[132], sc[132];
  if (t<132){ cnt[t]=0; }
  __syncthreads();
  for (int k=t; k<nE; k+=256){
    unsigned v = btmp1[base+k];
    eb1[k]=v; eb2[k]=btmp2[base+k];
    atomicAdd(&cnt[(v>>16)&127], 1);
  }
  __syncthreads();
  int c = (t<128)? cnt[t] : 0;
  if (t<128) sc[t]=c;
  __syncthreads();
  for (int o=1;o<128;o<<=1){
    int v = (t<128 && t>=o)? sc[t-o]:0;
    __syncthreads();
    if (t<128) sc[t]+=v;
    __syncthreads();
  }
  if (t<128){
    int excl = sc[t]-c;
    int node = bl*128+t;
    if (node<NN) offs[(size_t)l*NN+node] = base + excl;
    cnt[t] = base + excl;                // becomes cursor
  }
  if (lbuk==0 && t==255) offs[LN]=LE;
  __syncthreads();
  for (int k=t; k<nE; k+=256){
    unsigned v = eb1[k];
    int d = (v>>16)&127;
    int r = atomicAdd(&cnt[d],1);
    sedge[r] = (v & 0xFFFFu) | ((unsigned)eb2[k]<<16);
  }
}

__global__ void k_gather_emb(const int* __restrict__ verts, const float* __restrict__ emb,
                             float* __restrict__ x){
  int gid = blockIdx.x*256+threadIdx.x;
  int n = gid>>5, q = gid&31;
  if (n>=NN) return;
  int v = verts[n];
  ((float4*)x)[gid] = ((const float4*)emb)[(size_t)v*32+q];
}

// ---- transpose + bf16-convert all 18 hidden weight matrices: Wt[m][n][k] ----
__global__ __launch_bounds__(256) void k_prep_w(const float* __restrict__ wh,
    const float* __restrict__ tewl, const float* __restrict__ tewc,
    unsigned short* __restrict__ Wt){
  int gid = blockIdx.x*256+threadIdx.x;          // 18*16384
  int m = gid>>14; int idx = gid&16383;
  int n = idx>>7, k = idx&127;
  const float* src = (m<6)? wh + (size_t)m*16384
                   : (m<12)? tewl + (size_t)(m-6)*16384
                   : tewc + (size_t)(m-12)*16384;
  Wt[gid] = f2bf(src[k*128+n]);
}

// stage 64 fp32 rows -> bf16 LDS tile [64][LSTRIDE]
static __device__ __forceinline__ void stage64(const float* __restrict__ src,
    int row0, int M, unsigned short* Xs, int tid){
  #pragma unroll
  for (int it=0; it<4; it++){
    int idx = tid + it*256;
    int r = idx>>4, k8 = idx&15;
    float4 v0 = make_float4(0.f,0.f,0.f,0.f), v1 = v0;
    if (row0+r < M){
      const float4* p = (const float4*)src + (size_t)(row0+r)*32 + k8*2;
      v0 = p[0]; v1 = p[1];
    }
    short8 w;
    w[0]=(short)f2bf(v0.x); w[1]=(short)f2bf(v0.y); w[2]=(short)f2bf(v0.z); w[3]=(short)f2bf(v0.w);
    w[4]=(short)f2bf(v1.x); w[5]=(short)f2bf(v1.y); w[6]=(short)f2bf(v1.z); w[7]=(short)f2bf(v1.w);
    *(short8*)&Xs[r*LSTRIDE + k8*8] = w;
  }
}

// ---------------- MFMA GEMM: Ybf16[M,128] = bf16(X[M,128]) @ Wt ----------------
__global__ __launch_bounds__(256) void k_gemm_sup(const float* __restrict__ X,
    const unsigned short* __restrict__ Wt, unsigned short* __restrict__ Y, int M){
  __shared__ unsigned short Xs[64*LSTRIDE];
  int tid = threadIdx.x;
  int row0 = blockIdx.x*64;
  stage64(X, row0, M, Xs, tid);
  __syncthreads();
  int w = tid>>6, lane = tid&63, m = lane&15, q = lane>>4;
  f32x4 acc[8];
  #pragma unroll
  for (int nt=0;nt<8;nt++){ acc[nt][0]=0.f; acc[nt][1]=0.f; acc[nt][2]=0.f; acc[nt][3]=0.f; }
  #pragma unroll
  for (int kc=0; kc<4; kc++){
    short8 a = *(const short8*)&Xs[(16*w+m)*LSTRIDE + kc*32 + 8*q];
    #pragma unroll
    for (int nt=0; nt<8; nt++){
      short8 b = *(const short8*)&Wt[(size_t)(nt*16+m)*128 + kc*32 + 8*q];
      acc[nt] = __builtin_amdgcn_mfma_f32_16x16x32_bf16(a, b, acc[nt], 0,0,0);
    }
  }
  #pragma unroll
  for (int nt=0; nt<8; nt++){
    #pragma unroll
    for (int i=0;i<4;i++){
      int rr = row0 + 16*w + 4*q + i;
      if (rr<M) Y[(size_t)rr*128 + nt*16 + m] = f2bf(acc[nt][i]);
    }
  }
}

// ------- fused: BN(bf16 h)+ReLU -> bf16 LDS; dual MFMA (x@te_wl + hn@te_wc); gate -------
__global__ __launch_bounds__(256) void k_gemm_gate2(const unsigned short* __restrict__ H,
    const float* __restrict__ stL,            // NREP replicas [rep][sum128|sq128]
    const float* __restrict__ gamma, const float* __restrict__ beta,
    const unsigned short* __restrict__ Wl, const unsigned short* __restrict__ Wc,
    const float* __restrict__ teb, float* __restrict__ x, int M){
  __shared__ unsigned short XsX[64*LSTRIDE];
  __shared__ unsigned short XsH[64*LSTRIDE];
  __shared__ float sSc[128], sOff[128];
  int tid = threadIdx.x;
  int row0 = blockIdx.x*64;
  if (tid<128){
    float s=0.f, sq=0.f;
    #pragma unroll 8
    for (int g=0; g<NREP; g++){ s += stL[g*256+tid]; sq += stL[g*256+128+tid]; }
    float mean = s*(1.0f/NN);
    float var = sq*(1.0f/NN) - mean*mean;
    float sc = rsqrtf(var+BN_EPS)*gamma[tid];
    sSc[tid]=sc; sOff[tid]=beta[tid]-mean*sc;
  }
  stage64(x, row0, M, XsX, tid);
  __syncthreads();
  #pragma unroll
  for (int it=0; it<4; it++){
    int idx = tid + it*256;
    int r = idx>>4, k8 = idx&15;
    short8 hv8 = short8(0);
    if (row0+r < M) hv8 = *(const short8*)(H + (size_t)(row0+r)*128 + k8*8);
    int k = k8*8;
    short8 w;
    #pragma unroll
    for (int j=0;j<8;j++){
      float o = bf2f((unsigned short)hv8[j]);
      float hn = fmaxf(fmaf(o, sSc[k+j], sOff[k+j]), 0.f);
      w[j] = (short)f2bf(hn);
    }
    *(short8*)&XsH[r*LSTRIDE + k8*8] = w;
  }
  __syncthreads();
  int w = tid>>6, lane = tid&63, m = lane&15, q = lane>>4;
  f32x4 acc[8];
  #pragma unroll
  for (int nt=0;nt<8;nt++){ acc[nt][0]=0.f; acc[nt][1]=0.f; acc[nt][2]=0.f; acc[nt][3]=0.f; }
  #pragma unroll
  for (int kc=0; kc<4; kc++){
    short8 a = *(const short8*)&XsX[(16*w+m)*LSTRIDE + kc*32 + 8*q];
    #pragma unroll
    for (int nt=0; nt<8; nt++){
      short8 b = *(const short8*)&Wl[(size_t)(nt*16+m)*128 + kc*32 + 8*q];
      acc[nt] = __builtin_amdgcn_mfma_f32_16x16x32_bf16(a, b, acc[nt], 0,0,0);
    }
  }
  #pragma unroll
  for (int kc=0; kc<4; kc++){
    short8 a = *(const short8*)&XsH[(16*w+m)*LSTRIDE + kc*32 + 8*q];
    #pragma unroll
    for (int nt=0; nt<8; nt++){
      short8 b = *(const short8*)&Wc[(size_t)(nt*16+m)*128 + kc*32 + 8*q];
      acc[nt] = __builtin_amdgcn_mfma_f32_16x16x32_bf16(a, b, acc[nt], 0,0,0);
    }
  }
  #pragma unroll
  for (int nt=0; nt<8; nt++){
    int col = nt*16 + m;
    float bias = teb[col];
    #pragma unroll
    for (int i=0;i<4;i++){
      int lr = 16*w + 4*q + i;
      int rr = row0 + lr;
      if (rr<M){
        float hv = bf2f(XsH[lr*LSTRIDE + col]);
        float xo = bf2f(XsX[lr*LSTRIDE + col]);
        float g = sigm(acc[nt][i] + bias);
        x[(size_t)rr*128 + col] = g*hv + (1.f-g)*xo;
      }
    }
  }
}

// ---------------- Y[M,20] = X[M,128] @ W[128,20] (fp32) ----------------
__global__ __launch_bounds__(256) void k_gemm_out(const float* __restrict__ X,
    const float* __restrict__ W, float* __restrict__ Y, int M){
  __shared__ float Ws[DIM*OUTC];
  __shared__ float Xs2[8*DIM];
  int tid=threadIdx.x;
  for (int i=tid;i<DIM*OUTC;i+=256) Ws[i]=W[i];
  int row0=blockIdx.x*8;
  {
    int r = tid>>5, kq = tid&31;
    float4 v = make_float4(0.f,0.f,0.f,0.f);
    if (row0+r<M) v = ((const float4*)X)[(size_t)(row0+r)*32+kq];
    *(float4*)&Xs2[r*DIM+kq*4]=v;
  }
  __syncthreads();
  int c = tid&31, rl=tid>>5;
  if (c<OUTC && row0+rl<M){
    float acc=0.f;
    #pragma unroll 8
    for (int k=0;k<DIM;k++) acc += Xs2[rl*DIM+k]*Ws[k*OUTC+c];
    Y[(size_t)(row0+rl)*OUTC+c]=acc;
  }
}

// -------- SpMM gather (contiguous per-node edges) + fused BN stats; bf16 out --------
__global__ __launch_bounds__(256) void k_spmm128(const unsigned short* __restrict__ sup,
    const unsigned int* __restrict__ sedge, const int* __restrict__ offs,
    unsigned short* __restrict__ h, int lbase, float* __restrict__ stL){
  int nl = threadIdx.x>>5;
  int node = blockIdx.x*8 + nl;
  int fq = threadIdx.x & 31;
  int p = offs[lbase+node], end = offs[lbase+node+1];
  float4 a0 = make_float4(0.f,0.f,0.f,0.f), a1 = a0;
  for (; p+1<end; p+=2){
    unsigned int e0 = __builtin_nontemporal_load(sedge+p);
    unsigned int e1 = __builtin_nontemporal_load(sedge+p+1);
    float w0 = __half2float(__ushort_as_half((unsigned short)(e0>>16)));
    float w1 = __half2float(__ushort_as_half((unsigned short)(e1>>16)));
    ushort4 s0 = *(const ushort4*)(sup + (size_t)(e0&0xFFFFu)*128 + fq*4);
    ushort4 s1 = *(const ushort4*)(sup + (size_t)(e1&0xFFFFu)*128 + fq*4);
    a0.x += w0*bf2f(s0.x); a0.y += w0*bf2f(s0.y); a0.z += w0*bf2f(s0.z); a0.w += w0*bf2f(s0.w);
    a1.x += w1*bf2f(s1.x); a1.y += w1*bf2f(s1.y); a1.z += w1*bf2f(s1.z); a1.w += w1*bf2f(s1.w);
  }
  if (p<end){
    unsigned int e0 = __builtin_nontemporal_load(sedge+p);
    float w0 = __half2float(__ushort_as_half((unsigned short)(e0>>16)));
    ushort4 s0 = *(const ushort4*)(sup + (size_t)(e0&0xFFFFu)*128 + fq*4);
    a0.x += w0*bf2f(s0.x); a0.y += w0*bf2f(s0.y); a0.z += w0*bf2f(s0.z); a0.w += w0*bf2f(s0.w);
  }
  a0.x+=a1.x; a0.y+=a1.y; a0.z+=a1.z; a0.w+=a1.w;
  ushort4 ov;
  ov.x=f2bf(a0.x); ov.y=f2bf(a0.y); ov.z=f2bf(a0.z); ov.w=f2bf(a0.w);
  *(ushort4*)(h + (size_t)node*128 + fq*4) = ov;
  // fused BN stats from fp32 registers
  __shared__ float sP[8][132], sQ[8][132];
  int f0 = fq*4;
  sP[nl][f0+0]=a0.x; sP[nl][f0+1]=a0.y; sP[nl][f0+2]=a0.z; sP[nl][f0+3]=a0.w;
  sQ[nl][f0+0]=a0.x*a0.x; sQ[nl][f0+1]=a0.y*a0.y; sQ[nl][f0+2]=a0.z*a0.z; sQ[nl][f0+3]=a0.w*a0.w;
  __syncthreads();
  if (threadIdx.x < 128){
    int f = threadIdx.x;
    float s=0.f, sq=0.f;
    #pragma unroll
    for (int n=0;n<8;n++){ s += sP[n][f]; sq += sQ[n][f]; }
    float* base = stL + (blockIdx.x & (NREP-1))*256;
    atomicAdd(&base[f], s); atomicAdd(&base[128+f], sq);
  }
}

__global__ __launch_bounds__(256) void k_spmm_out(const float* __restrict__ sup,
    const unsigned int* __restrict__ sedge, const int* __restrict__ offs,
    float* __restrict__ h, int lbase){
  int node = blockIdx.x*8 + (threadIdx.x>>5);
  int c = threadIdx.x & 31;
  int p = offs[lbase+node], end = offs[lbase+node+1];
  float acc=0.f;
  for (; p<end; p++){
    unsigned int e = __builtin_nontemporal_load(sedge+p);
    float w = __half2float(__ushort_as_half((unsigned short)(e>>16)));
    if (c<OUTC) acc += w*sup[(size_t)(e&0xFFFFu)*OUTC+c];
  }
  if (c<OUTC) h[(size_t)node*OUTC+c]=acc;
}

// ---------------- output-layer BN stats (8-way replicated) ----------------
__global__ __launch_bounds__(256) void k_bn_stats_out(const float* __restrict__ h,
    float* __restrict__ st8, int rpb){
  int f = threadIdx.x % 32;
  int g = threadIdx.x / 32;
  float s=0.f, ss=0.f;
  int r0 = blockIdx.x*rpb;
  int r1 = min(NN, r0+rpb);
  if (f < OUTC){
    for (int r=r0+g; r<r1; r+=8){ float v = h[(size_t)r*OUTC+f]; s+=v; ss+=v*v; }
  }
  __shared__ float sh[256], sh2[256];
  sh[threadIdx.x]=s; sh2[threadIdx.x]=ss; __syncthreads();
  if (threadIdx.x < 32){
    #pragma unroll
    for (int i=1;i<8;i++){ s+=sh[threadIdx.x+i*32]; ss+=sh2[threadIdx.x+i*32]; }
    if (f<OUTC){
      float* base = st8 + (blockIdx.x&7)*64;
      atomicAdd(&base[f], s); atomicAdd(&base[32+f], ss);
    }
  }
}

__global__ void k_bn_reduce8(const float* __restrict__ st8, float* __restrict__ st){
  int f = threadIdx.x;          // 64
  float s=0.f;
  #pragma unroll
  for (int g=0; g<8; g++) s += st8[g*64+f];
  st[f]=s;
}

__global__ void k_bn_out(float* __restrict__ h, const float* __restrict__ st,
    const float* __restrict__ gamma, const float* __restrict__ beta){
  int gid = blockIdx.x*256+threadIdx.x;
  if (gid>=NN*OUTC) return;
  int f = gid % OUTC;
  const float invN = 1.0f/NN;
  float m = st[f]*invN;
  float var = st[32+f]*invN - m*m;
  float sc = rsqrtf(var+BN_EPS)*gamma[f];
  h[gid] = fmaxf((h[gid]-m)*sc + beta[f], 0.f);
}

// ---------------- final masked reduce (8-way replicated) ----------------
__global__ __launch_bounds__(256) void k_reduce(const float* __restrict__ xf,
    const int* __restrict__ verts, const float* __restrict__ mw,
    float* __restrict__ acc8, int rpb){
  int c = threadIdx.x & 31, g = threadIdx.x >> 5;
  int r0 = blockIdx.x*rpb;
  int r1 = min(NN, r0+rpb);
  float s=0.f;
  for (int r=r0+g; r<r1; r+=8){
    float m = mw[verts[r]];
    if (c<OUTC) s += m * xf[(size_t)r*OUTC+c];
  }
  __shared__ float sh[256];
  sh[threadIdx.x]=s; __syncthreads();
  if (threadIdx.x<32){
    #pragma unroll
    for (int i=1;i<8;i++) s += sh[threadIdx.x + i*32];
    if (c<OUTC) atomicAdd(&acc8[(blockIdx.x&7)*32 + c], s);
  }
}

__global__ void k_final(const float* __restrict__ acc8, const float* __restrict__ mb,
                        float* __restrict__ out){
  int c=threadIdx.x;
  if (c<OUTC){
    float s=0.f;
    #pragma unroll
    for (int g=0; g<8; g++) s += acc8[g*32+c];
    out[c] = sigm(s+mb[c]);
  }
}

// ---------------- host ----------------
extern "C" void kernel_launch(void* const* d_in, const int* in_sizes, int n_in,
                              void* d_out, int out_size, void* d_ws, size_t ws_size,
                              hipStream_t stream){
  const int*   verts = (const int*)d_in[0];
  const int*   ei    = (const int*)d_in[1];
  const float* ew    = (const float*)d_in[2];
  const float* emb   = (const float*)d_in[3];
  const float* wh    = (const float*)d_in[4];
  const float* w_out = (const float*)d_in[6];
  const float* bng_h = (const float*)d_in[8];
  const float* bnb_h = (const float*)d_in[9];
  const float* bng_o = (const float*)d_in[10];
  const float* bnb_o = (const float*)d_in[11];
  const float* tewl  = (const float*)d_in[12];
  const float* tewc  = (const float*)d_in[13];
  const float* teb   = (const float*)d_in[14];
  const float* maskw = (const float*)d_in[15];
  const float* maskb = (const float*)d_in[16];
  float* out = (float*)d_out;

  char* ws = (char*)d_ws;
  size_t off=0;
  auto alloc=[&](size_t bytes)->char*{ char* p = ws+off; off += (bytes+255)&~(size_t)255; return p; };
  unsigned int* sedge = (unsigned int*)alloc(sizeof(int)*LE);   // 22.4 MB
  int*   offs   = (int*)  alloc(sizeof(int)*(LN+1));            // 1.4 MB
  int*   Gm     = (int*)  alloc(sizeof(int)*LL*NBLK*392);       // 1.4 MB
  int*   S      = (int*)  alloc(sizeof(int)*(SCN+1));           // 1.4 MB
  int*   bsums  = (int*)  alloc(sizeof(int)*1024);
  float* x      = (float*)alloc(sizeof(float)*NN*DIM);          // 25.6 MB
  unsigned short* supbf = (unsigned short*)alloc(sizeof(short)*NN*DIM); // 12.8 MB
  unsigned short* hbf   = (unsigned short*)alloc(sizeof(short)*NN*DIM); // 12.8 MB
  float* buf20  = (float*)alloc(sizeof(float)*NN*OUTC);         // 4 MB
  unsigned short* Wt = (unsigned short*)alloc(sizeof(short)*18*DIM*DIM);
  const int STATSZ = 6*NREP*256 + 8*64 + 64 + 8*32;
  float* stats  = (float*)alloc(sizeof(float)*STATSZ);
  float* ostat8 = stats + 6*NREP*256;  // [8][64]
  float* ostat  = ostat8 + 8*64;       // [64]
  float* racc8  = ostat + 64;          // [8][32]
  // btmp1 (22.4 MB) aliases x; btmp2 (11.2 MB) aliases supbf (dead during preproc)
  unsigned int*  btmp1 = (unsigned int*)x;
  unsigned short* btmp2 = (unsigned short*)supbf;

  // --- preprocessing: 4-pass LDS-atomic counting sort ---
  hipMemsetAsync(stats, 0, sizeof(float)*STATSZ, stream);
  k_prep_w<<<1152,256,0,stream>>>(wh, tewl, tewc, Wt);
  k_bh<<<LL*NBLK,256,0,stream>>>(ei, Gm);
  int nsb = (SCN+4095)/4096;  // 86
  k_scan1p<<<nsb,256,0,stream>>>(Gm, S, bsums);
  k_scan2<<<1,1024,0,stream>>>(bsums, nsb);
  k_scan3<<<(SCN+256)/256,256,0,stream>>>(S, bsums);
  k_bscatter<<<LL*NBLK,256,0,stream>>>(ei, ew, S, btmp1, btmp2);
  k_fsort<<<LL*NBUK,256,0,stream>>>(btmp1, btmp2, S, sedge, offs);
  k_gather_emb<<<NN*32/256,256,0,stream>>>(verts, emb, x);

  // --- 6 hidden layers ---
  for (int i=0;i<6;i++){
    int j = (i==0)?5:(i-1);
    float* stL = stats + i*NREP*256;
    k_gemm_sup<<<(NN+63)/64,256,0,stream>>>(x, Wt + (size_t)i*DIM*DIM, supbf, NN);
    k_spmm128<<<NN/8,256,0,stream>>>(supbf, sedge, offs, hbf, i*NN, stL);
    k_gemm_gate2<<<(NN+63)/64,256,0,stream>>>(hbf, stL,
        bng_h+(size_t)i*DIM, bnb_h+(size_t)i*DIM,
        Wt + (size_t)(6+j)*DIM*DIM, Wt + (size_t)(12+j)*DIM*DIM,
        teb + (size_t)j*DIM, x, NN);
  }

  // --- output layer (fp32 throughout) ---
  k_gemm_out<<<(NN+7)/8,256,0,stream>>>(x, w_out, buf20, NN);
  k_spmm_out<<<NN/8,256,0,stream>>>(buf20, sedge, offs, (float*)hbf, 6*NN);
  float* bufO = (float*)hbf;   // NN*OUTC fp32 = 4 MB <= 12.8 MB
  k_bn_stats_out<<<512,256,0,stream>>>(bufO, ostat8, 98);
  k_bn_reduce8<<<1,64,0,stream>>>(ostat8, ostat);
  k_bn_out<<<(NN*OUTC+255)/256,256,0,stream>>>(bufO, ostat, bng_o, bnb_o);
  k_reduce<<<512,256,0,stream>>>(bufO, verts, maskw, racc8, 98);
  k_final<<<1,64,0,stream>>>(racc8, maskb, out);
}

// Round 10
// 1030.886 us; speedup vs baseline: 2.9425x; 1.0410x over previous
//
#include <hip/hip_runtime.h>
#include <hip/hip_fp16.h>

#define NN 50000
#define EE 800000
#define DIM 128
#define OUTC 20
#define LL 7
#define LE (LL*EE)
#define LN (LL*NN)
#define BN_EPS 1e-5f
#define LSTRIDE 136     // bf16 elems per LDS row
#define NREP 64         // BN stat replicas
#define NBUK 391        // coarse buckets of 128 dsts per layer
#define NBLK 128        // edge-blocks per layer (EE/NBLK = 6250)
#define CH   6250
#define SCN  (LL*NBUK*NBLK)   // 350336 scan entries

typedef __attribute__((ext_vector_type(8))) short short8;
typedef __attribute__((ext_vector_type(4))) float f32x4;

static __device__ __forceinline__ float sigm(float z){ return 1.0f/(1.0f+expf(-z)); }
static __device__ __forceinline__ unsigned short f2bf(float f){
  unsigned int u = __float_as_uint(f);
  u += 0x7FFF + ((u>>16)&1);            // RNE
  return (unsigned short)(u>>16);
}
static __device__ __forceinline__ float bf2f(unsigned short s){
  return __uint_as_float(((unsigned int)s)<<16);
}

// ======== preprocessing: counting sort, all atomics in LDS, streaming writes ========

// P1: per-(layer,block) LDS histogram over 391 coarse buckets
__global__ __launch_bounds__(256) void k_bh(const int* __restrict__ ei,
    int* __restrict__ Gm){
  int l = blockIdx.x >> 7, b = blockIdx.x & 127;
  int t = threadIdx.x;
  __shared__ int h[392];
  for (int i=t;i<392;i+=256) h[i]=0;
  __syncthreads();
  const int* dsts = ei + (size_t)(2*l+1)*EE + b*CH;
  for (int k=t; k<CH; k+=256) atomicAdd(&h[__builtin_nontemporal_load(dsts+k)>>7], 1);
  __syncthreads();
  int* g = Gm + (size_t)(l*NBLK+b)*392;
  for (int i=t;i<NBUK;i+=256) g[i]=h[i];
}

// P2: exclusive scan over (l,buk,b) enumeration of Gm[(l,b),buk]
__global__ __launch_bounds__(256) void k_scan1p(const int* __restrict__ Gm,
    int* __restrict__ part, int* __restrict__ bsums){
  __shared__ int s[256];
  int t = threadIdx.x;
  int base = blockIdx.x*4096 + t*16;
  int v[16]; int sum = 0;
  #pragma unroll
  for (int i=0;i<16;i++){
    int idx = base+i; int val = 0;
    if (idx < SCN){
      int l = idx/(NBUK*NBLK);
      int r = idx - l*(NBUK*NBLK);
      int buk = r>>7, b = r&127;
      val = Gm[(size_t)(l*NBLK+b)*392 + buk];
    }
    v[i]=val; sum+=val;
  }
  s[t]=sum; __syncthreads();
  for (int off=1; off<256; off<<=1){
    int x = (t>=off)? s[t-off] : 0;
    __syncthreads(); s[t]+=x; __syncthreads();
  }
  if (t==255) bsums[blockIdx.x] = s[255];
  int run = s[t]-sum;
  #pragma unroll
  for (int i=0;i<16;i++){ if (base+i<SCN) part[base+i]=run; run += v[i]; }
}

__global__ __launch_bounds__(1024) void k_scan2(int* bsums, int nb){
  __shared__ int s[1024];
  int t=threadIdx.x;
  int v = (t<nb)? bsums[t]:0;
  s[t]=v; __syncthreads();
  for (int off=1; off<1024; off<<=1){
    int x=(t>=off)? s[t-off]:0; __syncthreads(); s[t]+=x; __syncthreads();
  }
  if (t<nb) bsums[t] = s[t]-v;
}

__global__ void k_scan3(int* __restrict__ S, const int* __restrict__ bsums){
  int gid = blockIdx.x*256+threadIdx.x;
  if (gid < SCN) S[gid] += bsums[gid>>12];
  if (gid==0) S[SCN]=LE;
}

// P3: LDS counting-sort by bucket (record = origk|dst7|buk), contiguous run writes
// of FINAL packed edges (src16|halfw16) + 1B dst array. LDS 32.3 KB -> 4 blocks/CU.
__global__ __launch_bounds__(256) void k_bscatter(const int* __restrict__ ei,
    const float* __restrict__ ew, const int* __restrict__ S,
    unsigned int* __restrict__ btmpP, unsigned char* __restrict__ btmpD){
  int l = blockIdx.x >> 7, b = blockIdx.x & 127;
  int t = threadIdx.x;
  __shared__ int cnt[392], bstart[392], cur[392], runb[392];
  __shared__ int ps[256];
  __shared__ unsigned int eb[CH];       // 25 KB
  for (int i=t;i<392;i+=256) cnt[i]=0;
  __syncthreads();
  const int* srcs = ei + (size_t)(2*l)*EE + b*CH;
  const int* dsts = ei + (size_t)(2*l+1)*EE + b*CH;
  const float* wsrc = ew + (size_t)l*EE + b*CH;
  for (int k=t;k<CH;k+=256) atomicAdd(&cnt[dsts[k]>>7],1);
  __syncthreads();
  // exclusive scan over 392 counts (2 per thread)
  int v0 = (2*t<392)? cnt[2*t]:0;
  int v1 = (2*t+1<392)? cnt[2*t+1]:0;
  int sum = v0+v1;
  ps[t]=sum; __syncthreads();
  for (int o=1;o<256;o<<=1){ int x=(t>=o)?ps[t-o]:0; __syncthreads(); ps[t]+=x; __syncthreads(); }
  int run = ps[t]-sum;
  if (2*t<392){ bstart[2*t]=run; cur[2*t]=run; }
  if (2*t+1<392){ bstart[2*t+1]=run+v0; cur[2*t+1]=run+v0; }
  for (int i=t;i<NBUK;i+=256) runb[i] = S[(size_t)(l*NBUK+i)*128 + b];
  __syncthreads();
  // place records into LDS in bucket order (L1 re-read of dsts)
  for (int k=t;k<CH;k+=256){
    int dst = dsts[k];
    int buk = dst>>7;
    int pos = atomicAdd(&cur[buk],1);
    eb[pos] = (unsigned)k | ((unsigned)(dst&127)<<16) | ((unsigned)buk<<23);
  }
  __syncthreads();
  // streaming write; src/w fetched from the block's L1-hot 25 KB input slice
  for (int k=t;k<CH;k+=256){
    unsigned e = eb[k];
    int buk = e>>23;
    int origk = e & 0x1FFF;
    int src = srcs[origk];
    float w = wsrc[origk];
    int gp = runb[buk] + (k - bstart[buk]);
    unsigned short hw = __half_as_ushort(__float2half(w));
    btmpP[gp] = (unsigned)src | ((unsigned)hw<<16);
    btmpD[gp] = (unsigned char)((e>>16)&127);
  }
}

// P4: per-bucket count+scan from 1B dst array, then direct scatter of packed edges
// into the bucket's L2-resident sedge window. LDS ~1 KB.
__global__ __launch_bounds__(256) void k_fsort(const unsigned int* __restrict__ btmpP,
    const unsigned char* __restrict__ btmpD, const int* __restrict__ S,
    unsigned int* __restrict__ sedge, int* __restrict__ offs){
  int lbuk = blockIdx.x;                 // 0..2736
  int l = lbuk/NBUK, bl = lbuk - l*NBUK;
  int t = threadIdx.x;
  int base = S[(size_t)lbuk*128];
  int end  = S[(size_t)(lbuk+1)*128];
  int nE = end - base;
  __shared__ int cnt[132], sc[132];
  if (t<132) cnt[t]=0;
  __syncthreads();
  for (int k=t; k<nE; k+=256) atomicAdd(&cnt[btmpD[base+k]], 1);
  __syncthreads();
  int c = (t<128)? cnt[t] : 0;
  if (t<128) sc[t]=c;
  __syncthreads();
  for (int o=1;o<128;o<<=1){
    int v = (t<128 && t>=o)? sc[t-o]:0;
    __syncthreads();
    if (t<128) sc[t]+=v;
    __syncthreads();
  }
  if (t<128){
    int excl = sc[t]-c;
    int node = bl*128+t;
    if (node<NN) offs[(size_t)l*NN+node] = base + excl;
    cnt[t] = base + excl;                // becomes cursor
  }
  if (lbuk==0 && t==255) offs[LN]=LE;
  __syncthreads();
  for (int k=t; k<nE; k+=256){
    int d = btmpD[base+k];
    int r = atomicAdd(&cnt[d],1);
    sedge[r] = btmpP[base+k];
  }
}

__global__ void k_gather_emb(const int* __restrict__ verts, const float* __restrict__ emb,
                             float* __restrict__ x){
  int gid = blockIdx.x*256+threadIdx.x;
  int n = gid>>5, q = gid&31;
  if (n>=NN) return;
  int v = verts[n];
  ((float4*)x)[gid] = ((const float4*)emb)[(size_t)v*32+q];
}

// ---- transpose + bf16-convert all 18 hidden weight matrices: Wt[m][n][k] ----
__global__ __launch_bounds__(256) void k_prep_w(const float* __restrict__ wh,
    const float* __restrict__ tewl, const float* __restrict__ tewc,
    unsigned short* __restrict__ Wt){
  int gid = blockIdx.x*256+threadIdx.x;          // 18*16384
  int m = gid>>14; int idx = gid&16383;
  int n = idx>>7, k = idx&127;
  const float* src = (m<6)? wh + (size_t)m*16384
                   : (m<12)? tewl + (size_t)(m-6)*16384
                   : tewc + (size_t)(m-12)*16384;
  Wt[gid] = f2bf(src[k*128+n]);
}

// stage 64 fp32 rows -> bf16 LDS tile [64][LSTRIDE]
static __device__ __forceinline__ void stage64(const float* __restrict__ src,
    int row0, int M, unsigned short* Xs, int tid){
  #pragma unroll
  for (int it=0; it<4; it++){
    int idx = tid + it*256;
    int r = idx>>4, k8 = idx&15;
    float4 v0 = make_float4(0.f,0.f,0.f,0.f), v1 = v0;
    if (row0+r < M){
      const float4* p = (const float4*)src + (size_t)(row0+r)*32 + k8*2;
      v0 = p[0]; v1 = p[1];
    }
    short8 w;
    w[0]=(short)f2bf(v0.x); w[1]=(short)f2bf(v0.y); w[2]=(short)f2bf(v0.z); w[3]=(short)f2bf(v0.w);
    w[4]=(short)f2bf(v1.x); w[5]=(short)f2bf(v1.y); w[6]=(short)f2bf(v1.z); w[7]=(short)f2bf(v1.w);
    *(short8*)&Xs[r*LSTRIDE + k8*8] = w;
  }
}

// ---------------- MFMA GEMM: Ybf16[M,128] = bf16(X[M,128]) @ Wt (layer 0 only) ----------------
__global__ __launch_bounds__(256) void k_gemm_sup(const float* __restrict__ X,
    const unsigned short* __restrict__ Wt, unsigned short* __restrict__ Y, int M){
  __shared__ unsigned short Xs[64*LSTRIDE];
  int tid = threadIdx.x;
  int row0 = blockIdx.x*64;
  stage64(X, row0, M, Xs, tid);
  __syncthreads();
  int w = tid>>6, lane = tid&63, m = lane&15, q = lane>>4;
  f32x4 acc[8];
  #pragma unroll
  for (int nt=0;nt<8;nt++){ acc[nt][0]=0.f; acc[nt][1]=0.f; acc[nt][2]=0.f; acc[nt][3]=0.f; }
  #pragma unroll
  for (int kc=0; kc<4; kc++){
    short8 a = *(const short8*)&Xs[(16*w+m)*LSTRIDE + kc*32 + 8*q];
    #pragma unroll
    for (int nt=0; nt<8; nt++){
      short8 b = *(const short8*)&Wt[(size_t)(nt*16+m)*128 + kc*32 + 8*q];
      acc[nt] = __builtin_amdgcn_mfma_f32_16x16x32_bf16(a, b, acc[nt], 0,0,0);
    }
  }
  #pragma unroll
  for (int nt=0; nt<8; nt++){
    #pragma unroll
    for (int i=0;i<4;i++){
      int rr = row0 + 16*w + 4*q + i;
      if (rr<M) Y[(size_t)rr*128 + nt*16 + m] = f2bf(acc[nt][i]);
    }
  }
}

// ------- fused: BN(bf16 h)+ReLU -> bf16 LDS; dual MFMA; gate; [+ next-layer sup MFMA] -------
template<int FUSE>
__global__ __launch_bounds__(256) void k_gemm_gate2(const unsigned short* __restrict__ H,
    const float* __restrict__ stL,            // NREP replicas [rep][sum128|sq128]
    const float* __restrict__ gamma, const float* __restrict__ beta,
    const unsigned short* __restrict__ Wl, const unsigned short* __restrict__ Wc,
    const unsigned short* __restrict__ Wn, const float* __restrict__ teb,
    float* __restrict__ x, unsigned short* __restrict__ supY, int M){
  __shared__ unsigned short XsX[64*LSTRIDE];
  __shared__ unsigned short XsH[64*LSTRIDE];
  __shared__ float sSc[128], sOff[128];
  int tid = threadIdx.x;
  int row0 = blockIdx.x*64;
  if (tid<128){
    float s=0.f, sq=0.f;
    #pragma unroll 8
    for (int g=0; g<NREP; g++){ s += stL[g*256+tid]; sq += stL[g*256+128+tid]; }
    float mean = s*(1.0f/NN);
    float var = sq*(1.0f/NN) - mean*mean;
    float sc = rsqrtf(var+BN_EPS)*gamma[tid];
    sSc[tid]=sc; sOff[tid]=beta[tid]-mean*sc;
  }
  stage64(x, row0, M, XsX, tid);
  __syncthreads();
  #pragma unroll
  for (int it=0; it<4; it++){
    int idx = tid + it*256;
    int r = idx>>4, k8 = idx&15;
    short8 hv8 = short8(0);
    if (row0+r < M) hv8 = *(const short8*)(H + (size_t)(row0+r)*128 + k8*8);
    int k = k8*8;
    short8 w;
    #pragma unroll
    for (int j=0;j<8;j++){
      float o = bf2f((unsigned short)hv8[j]);
      float hn = fmaxf(fmaf(o, sSc[k+j], sOff[k+j]), 0.f);
      w[j] = (short)f2bf(hn);
    }
    *(short8*)&XsH[r*LSTRIDE + k8*8] = w;
  }
  __syncthreads();
  int w = tid>>6, lane = tid&63, m = lane&15, q = lane>>4;
  f32x4 acc[8];
  #pragma unroll
  for (int nt=0;nt<8;nt++){ acc[nt][0]=0.f; acc[nt][1]=0.f; acc[nt][2]=0.f; acc[nt][3]=0.f; }
  #pragma unroll
  for (int kc=0; kc<4; kc++){
    short8 a = *(const short8*)&XsX[(16*w+m)*LSTRIDE + kc*32 + 8*q];
    #pragma unroll
    for (int nt=0; nt<8; nt++){
      short8 b = *(const short8*)&Wl[(size_t)(nt*16+m)*128 + kc*32 + 8*q];
      acc[nt] = __builtin_amdgcn_mfma_f32_16x16x32_bf16(a, b, acc[nt], 0,0,0);
    }
  }
  #pragma unroll
  for (int kc=0; kc<4; kc++){
    short8 a = *(const short8*)&XsH[(16*w+m)*LSTRIDE + kc*32 + 8*q];
    #pragma unroll
    for (int nt=0; nt<8; nt++){
      short8 b = *(const short8*)&Wc[(size_t)(nt*16+m)*128 + kc*32 + 8*q];
      acc[nt] = __builtin_amdgcn_mfma_f32_16x16x32_bf16(a, b, acc[nt], 0,0,0);
    }
  }
  // gate epilogue; each (row,col) owned by exactly one thread -> in-place XsX update safe
  #pragma unroll
  for (int nt=0; nt<8; nt++){
    int col = nt*16 + m;
    float bias = teb[col];
    #pragma unroll
    for (int i=0;i<4;i++){
      int lr = 16*w + 4*q + i;
      int rr = row0 + lr;
      if (rr<M){
        float hv = bf2f(XsH[lr*LSTRIDE + col]);
        float xo = bf2f(XsX[lr*LSTRIDE + col]);
        float g = sigm(acc[nt][i] + bias);
        float xn = g*hv + (1.f-g)*xo;
        x[(size_t)rr*128 + col] = xn;
        if (FUSE) XsX[lr*LSTRIDE + col] = f2bf(xn);
      }
    }
  }
  if (FUSE){
    __syncthreads();
    #pragma unroll
    for (int nt=0;nt<8;nt++){ acc[nt][0]=0.f; acc[nt][1]=0.f; acc[nt][2]=0.f; acc[nt][3]=0.f; }
    #pragma unroll
    for (int kc=0; kc<4; kc++){
      short8 a = *(const short8*)&XsX[(16*w+m)*LSTRIDE + kc*32 + 8*q];
      #pragma unroll
      for (int nt=0; nt<8; nt++){
        short8 b = *(const short8*)&Wn[(size_t)(nt*16+m)*128 + kc*32 + 8*q];
        acc[nt] = __builtin_amdgcn_mfma_f32_16x16x32_bf16(a, b, acc[nt], 0,0,0);
      }
    }
    #pragma unroll
    for (int nt=0; nt<8; nt++){
      #pragma unroll
      for (int i=0;i<4;i++){
        int rr = row0 + 16*w + 4*q + i;
        if (rr<M) supY[(size_t)rr*128 + nt*16 + m] = f2bf(acc[nt][i]);
      }
    }
  }
}

// ---------------- Y[M,20] = X[M,128] @ W[128,20] (fp32) ----------------
__global__ __launch_bounds__(256) void k_gemm_out(const float* __restrict__ X,
    const float* __restrict__ W, float* __restrict__ Y, int M){
  __shared__ float Ws[DIM*OUTC];
  __shared__ float Xs2[8*DIM];
  int tid=threadIdx.x;
  for (int i=tid;i<DIM*OUTC;i+=256) Ws[i]=W[i];
  int row0=blockIdx.x*8;
  {
    int r = tid>>5, kq = tid&31;
    float4 v = make_float4(0.f,0.f,0.f,0.f);
    if (row0+r<M) v = ((const float4*)X)[(size_t)(row0+r)*32+kq];
    *(float4*)&Xs2[r*DIM+kq*4]=v;
  }
  __syncthreads();
  int c = tid&31, rl=tid>>5;
  if (c<OUTC && row0+rl<M){
    float acc=0.f;
    #pragma unroll 8
    for (int k=0;k<DIM;k++) acc += Xs2[rl*DIM+k]*Ws[k*OUTC+c];
    Y[(size_t)(row0+rl)*OUTC+c]=acc;
  }
}

// -------- SpMM gather (contiguous per-node edges) + fused BN stats; bf16 out --------
__global__ __launch_bounds__(256) void k_spmm128(const unsigned short* __restrict__ sup,
    const unsigned int* __restrict__ sedge, const int* __restrict__ offs,
    unsigned short* __restrict__ h, int lbase, float* __restrict__ stL){
  int nl = threadIdx.x>>5;
  int node = blockIdx.x*8 + nl;
  int fq = threadIdx.x & 31;
  int p = offs[lbase+node], end = offs[lbase+node+1];
  float4 a0 = make_float4(0.f,0.f,0.f,0.f), a1 = a0;
  for (; p+1<end; p+=2){
    unsigned int e0 = __builtin_nontemporal_load(sedge+p);
    unsigned int e1 = __builtin_nontemporal_load(sedge+p+1);
    float w0 = __half2float(__ushort_as_half((unsigned short)(e0>>16)));
    float w1 = __half2float(__ushort_as_half((unsigned short)(e1>>16)));
    ushort4 s0 = *(const ushort4*)(sup + (size_t)(e0&0xFFFFu)*128 + fq*4);
    ushort4 s1 = *(const ushort4*)(sup + (size_t)(e1&0xFFFFu)*128 + fq*4);
    a0.x += w0*bf2f(s0.x); a0.y += w0*bf2f(s0.y); a0.z += w0*bf2f(s0.z); a0.w += w0*bf2f(s0.w);
    a1.x += w1*bf2f(s1.x); a1.y += w1*bf2f(s1.y); a1.z += w1*bf2f(s1.z); a1.w += w1*bf2f(s1.w);
  }
  if (p<end){
    unsigned int e0 = __builtin_nontemporal_load(sedge+p);
    float w0 = __half2float(__ushort_as_half((unsigned short)(e0>>16)));
    ushort4 s0 = *(const ushort4*)(sup + (size_t)(e0&0xFFFFu)*128 + fq*4);
    a0.x += w0*bf2f(s0.x); a0.y += w0*bf2f(s0.y); a0.z += w0*bf2f(s0.z); a0.w += w0*bf2f(s0.w);
  }
  a0.x+=a1.x; a0.y+=a1.y; a0.z+=a1.z; a0.w+=a1.w;
  ushort4 ov;
  ov.x=f2bf(a0.x); ov.y=f2bf(a0.y); ov.z=f2bf(a0.z); ov.w=f2bf(a0.w);
  *(ushort4*)(h + (size_t)node*128 + fq*4) = ov;
  // fused BN stats from fp32 registers
  __shared__ float sP[8][132], sQ[8][132];
  int f0 = fq*4;
  sP[nl][f0+0]=a0.x; sP[nl][f0+1]=a0.y; sP[nl][f0+2]=a0.z; sP[nl][f0+3]=a0.w;
  sQ[nl][f0+0]=a0.x*a0.x; sQ[nl][f0+1]=a0.y*a0.y; sQ[nl][f0+2]=a0.z*a0.z; sQ[nl][f0+3]=a0.w*a0.w;
  __syncthreads();
  if (threadIdx.x < 128){
    int f = threadIdx.x;
    float s=0.f, sq=0.f;
    #pragma unroll
    for (int n=0;n<8;n++){ s += sP[n][f]; sq += sQ[n][f]; }
    float* base = stL + (blockIdx.x & (NREP-1))*256;
    atomicAdd(&base[f], s); atomicAdd(&base[128+f], sq);
  }
}

__global__ __launch_bounds__(256) void k_spmm_out(const float* __restrict__ sup,
    const unsigned int* __restrict__ sedge, const int* __restrict__ offs,
    float* __restrict__ h, int lbase){
  int node = blockIdx.x*8 + (threadIdx.x>>5);
  int c = threadIdx.x & 31;
  int p = offs[lbase+node], end = offs[lbase+node+1];
  float acc=0.f;
  for (; p<end; p++){
    unsigned int e = __builtin_nontemporal_load(sedge+p);
    float w = __half2float(__ushort_as_half((unsigned short)(e>>16)));
    if (c<OUTC) acc += w*sup[(size_t)(e&0xFFFFu)*OUTC+c];
  }
  if (c<OUTC) h[(size_t)node*OUTC+c]=acc;
}

// ---------------- output-layer BN stats (8-way replicated) ----------------
__global__ __launch_bounds__(256) void k_bn_stats_out(const float* __restrict__ h,
    float* __restrict__ st8, int rpb){
  int f = threadIdx.x % 32;
  int g = threadIdx.x / 32;
  float s=0.f, ss=0.f;
  int r0 = blockIdx.x*rpb;
  int r1 = min(NN, r0+rpb);
  if (f < OUTC){
    for (int r=r0+g; r<r1; r+=8){ float v = h[(size_t)r*OUTC+f]; s+=v; ss+=v*v; }
  }
  __shared__ float sh[256], sh2[256];
  sh[threadIdx.x]=s; sh2[threadIdx.x]=ss; __syncthreads();
  if (threadIdx.x < 32){
    #pragma unroll
    for (int i=1;i<8;i++){ s+=sh[threadIdx.x+i*32]; ss+=sh2[threadIdx.x+i*32]; }
    if (f<OUTC){
      float* base = st8 + (blockIdx.x&7)*64;
      atomicAdd(&base[f], s); atomicAdd(&base[32+f], ss);
    }
  }
}

__global__ void k_bn_reduce8(const float* __restrict__ st8, float* __restrict__ st){
  int f = threadIdx.x;          // 64
  float s=0.f;
  #pragma unroll
  for (int g=0; g<8; g++) s += st8[g*64+f];
  st[f]=s;
}

__global__ void k_bn_out(float* __restrict__ h, const float* __restrict__ st,
    const float* __restrict__ gamma, const float* __restrict__ beta){
  int gid = blockIdx.x*256+threadIdx.x;
  if (gid>=NN*OUTC) return;
  int f = gid % OUTC;
  const float invN = 1.0f/NN;
  float m = st[f]*invN;
  float var = st[32+f]*invN - m*m;
  float sc = rsqrtf(var+BN_EPS)*gamma[f];
  h[gid] = fmaxf((h[gid]-m)*sc + beta[f], 0.f);
}

// ---------------- final masked reduce (8-way replicated) ----------------
__global__ __launch_bounds__(256) void k_reduce(const float* __restrict__ xf,
    const int* __restrict__ verts, const float* __restrict__ mw,
    float* __restrict__ acc8, int rpb){
  int c = threadIdx.x & 31, g = threadIdx.x >> 5;
  int r0 = blockIdx.x*rpb;
  int r1 = min(NN, r0+rpb);
  float s=0.f;
  for (int r=r0+g; r<r1; r+=8){
    float m = mw[verts[r]];
    if (c<OUTC) s += m * xf[(size_t)r*OUTC+c];
  }
  __shared__ float sh[256];
  sh[threadIdx.x]=s; __syncthreads();
  if (threadIdx.x<32){
    #pragma unroll
    for (int i=1;i<8;i++) s += sh[threadIdx.x + i*32];
    if (c<OUTC) atomicAdd(&acc8[(blockIdx.x&7)*32 + c], s);
  }
}

__global__ void k_final(const float* __restrict__ acc8, const float* __restrict__ mb,
                        float* __restrict__ out){
  int c=threadIdx.x;
  if (c<OUTC){
    float s=0.f;
    #pragma unroll
    for (int g=0; g<8; g++) s += acc8[g*32+c];
    out[c] = sigm(s+mb[c]);
  }
}

// ---------------- host ----------------
extern "C" void kernel_launch(void* const* d_in, const int* in_sizes, int n_in,
                              void* d_out, int out_size, void* d_ws, size_t ws_size,
                              hipStream_t stream){
  const int*   verts = (const int*)d_in[0];
  const int*   ei    = (const int*)d_in[1];
  const float* ew    = (const float*)d_in[2];
  const float* emb   = (const float*)d_in[3];
  const float* wh    = (const float*)d_in[4];
  const float* w_out = (const float*)d_in[6];
  const float* bng_h = (const float*)d_in[8];
  const float* bnb_h = (const float*)d_in[9];
  const float* bng_o = (const float*)d_in[10];
  const float* bnb_o = (const float*)d_in[11];
  const float* tewl  = (const float*)d_in[12];
  const float* tewc  = (const float*)d_in[13];
  const float* teb   = (const float*)d_in[14];
  const float* maskw = (const float*)d_in[15];
  const float* maskb = (const float*)d_in[16];
  float* out = (float*)d_out;

  char* ws = (char*)d_ws;
  size_t off=0;
  auto alloc=[&](size_t bytes)->char*{ char* p = ws+off; off += (bytes+255)&~(size_t)255; return p; };
  unsigned int* sedge = (unsigned int*)alloc(sizeof(int)*LE);   // 22.4 MB
  int*   offs   = (int*)  alloc(sizeof(int)*(LN+1));            // 1.4 MB
  int*   Gm     = (int*)  alloc(sizeof(int)*LL*NBLK*392);       // 1.4 MB
  int*   S      = (int*)  alloc(sizeof(int)*(SCN+1));           // 1.4 MB
  int*   bsums  = (int*)  alloc(sizeof(int)*1024);
  float* x      = (float*)alloc(sizeof(float)*NN*DIM);          // 25.6 MB
  unsigned short* supbf = (unsigned short*)alloc(sizeof(short)*NN*DIM); // 12.8 MB
  unsigned short* hbf   = (unsigned short*)alloc(sizeof(short)*NN*DIM); // 12.8 MB
  float* buf20  = (float*)alloc(sizeof(float)*NN*OUTC);         // 4 MB
  unsigned short* Wt = (unsigned short*)alloc(sizeof(short)*18*DIM*DIM);
  const int STATSZ = 6*NREP*256 + 8*64 + 64 + 8*32;
  float* stats  = (float*)alloc(sizeof(float)*STATSZ);
  float* ostat8 = stats + 6*NREP*256;  // [8][64]
  float* ostat  = ostat8 + 8*64;       // [64]
  float* racc8  = ostat + 64;          // [8][32]
  // btmpP (22.4 MB) aliases x; btmpD (5.6 MB) aliases supbf (dead during preproc)
  unsigned int*  btmpP = (unsigned int*)x;
  unsigned char* btmpD = (unsigned char*)supbf;

  // --- preprocessing: 4-pass LDS-atomic counting sort ---
  hipMemsetAsync(stats, 0, sizeof(float)*STATSZ, stream);
  k_prep_w<<<1152,256,0,stream>>>(wh, tewl, tewc, Wt);
  k_bh<<<LL*NBLK,256,0,stream>>>(ei, Gm);
  int nsb = (SCN+4095)/4096;  // 86
  k_scan1p<<<nsb,256,0,stream>>>(Gm, S, bsums);
  k_scan2<<<1,1024,0,stream>>>(bsums, nsb);
  k_scan3<<<(SCN+256)/256,256,0,stream>>>(S, bsums);
  k_bscatter<<<LL*NBLK,256,0,stream>>>(ei, ew, S, btmpP, btmpD);
  k_fsort<<<LL*NBUK,256,0,stream>>>(btmpP, btmpD, S, sedge, offs);
  k_gather_emb<<<NN*32/256,256,0,stream>>>(verts, emb, x);

  // --- 6 hidden layers; sup for layer i+1 computed inside gate2 of layer i ---
  k_gemm_sup<<<(NN+63)/64,256,0,stream>>>(x, Wt, supbf, NN);
  for (int i=0;i<6;i++){
    int j = (i==0)?5:(i-1);
    float* stL = stats + i*NREP*256;
    k_spmm128<<<NN/8,256,0,stream>>>(supbf, sedge, offs, hbf, i*NN, stL);
    if (i<5)
      k_gemm_gate2<1><<<(NN+63)/64,256,0,stream>>>(hbf, stL,
          bng_h+(size_t)i*DIM, bnb_h+(size_t)i*DIM,
          Wt + (size_t)(6+j)*DIM*DIM, Wt + (size_t)(12+j)*DIM*DIM,
          Wt + (size_t)(i+1)*DIM*DIM, teb + (size_t)j*DIM, x, supbf, NN);
    else
      k_gemm_gate2<0><<<(NN+63)/64,256,0,stream>>>(hbf, stL,
          bng_h+(size_t)i*DIM, bnb_h+(size_t)i*DIM,
          Wt + (size_t)(6+j)*DIM*DIM, Wt + (size_t)(12+j)*DIM*DIM,
          Wt, teb + (size_t)j*DIM, x, supbf, NN);
  }

  // --- output layer (fp32 throughout) ---
  k_gemm_out<<<(NN+7)/8,256,0,stream>>>(x, w_out, buf20, NN);
  k_spmm_out<<<NN/8,256,0,stream>>>(buf20, sedge, offs, (float*)hbf, 6*NN);
  float* bufO = (float*)hbf;   // NN*OUTC fp32 = 4 MB <= 12.8 MB
  k_bn_stats_out<<<512,256,0,stream>>>(bufO, ostat8, 98);
  k_bn_reduce8<<<1,64,0,stream>>>(ostat8, ostat);
  k_bn_out<<<(NN*OUTC+255)/256,256,0,stream>>>(bufO, ostat, bng_o, bnb_o);
  k_reduce<<<512,256,0,stream>>>(bufO, verts, maskw, racc8, 98);
  k_final<<<1,64,0,stream>>>(racc8, maskb, out);
}

// Round 11
// 1020.333 us; speedup vs baseline: 2.9730x; 1.0103x over previous
//
#include <hip/hip_runtime.h>
#include <hip/hip_fp16.h>

#define NN 50000
#define EE 800000
#define DIM 128
#define OUTC 20
#define LL 7
#define LE (LL*EE)
#define LN (LL*NN)
#define BN_EPS 1e-5f
#define LSTRIDE 136     // bf16 elems per LDS row
#define NREP 64         // BN stat replicas
#define NBUK 391        // coarse buckets of 128 dsts per layer
#define NBLK 256        // edge-blocks per layer (EE/NBLK = 3125)
#define CH   3125
#define SCN  (LL*NBUK*NBLK)   // 700672 scan entries

typedef __attribute__((ext_vector_type(8))) short short8;
typedef __attribute__((ext_vector_type(4))) float f32x4;

static __device__ __forceinline__ float sigm(float z){ return 1.0f/(1.0f+expf(-z)); }
static __device__ __forceinline__ unsigned short f2bf(float f){
  unsigned int u = __float_as_uint(f);
  u += 0x7FFF + ((u>>16)&1);            // RNE
  return (unsigned short)(u>>16);
}
static __device__ __forceinline__ float bf2f(unsigned short s){
  return __uint_as_float(((unsigned int)s)<<16);
}

// ======== preprocessing: counting sort, all atomics in LDS, streaming writes ========

// P1: per-(layer,block) LDS histogram over 391 coarse buckets
__global__ __launch_bounds__(256) void k_bh(const int* __restrict__ ei,
    int* __restrict__ Gm){
  int l = blockIdx.x >> 8, b = blockIdx.x & 255;
  int t = threadIdx.x;
  __shared__ int h[392];
  for (int i=t;i<392;i+=256) h[i]=0;
  __syncthreads();
  const int* dsts = ei + (size_t)(2*l+1)*EE + b*CH;
  for (int k=t; k<CH; k+=256) atomicAdd(&h[__builtin_nontemporal_load(dsts+k)>>7], 1);
  __syncthreads();
  int* g = Gm + (size_t)(l*NBLK+b)*392;
  for (int i=t;i<NBUK;i+=256) g[i]=h[i];
}

// P2: exclusive scan over (l,buk,b) enumeration of Gm[(l,b),buk]
__global__ __launch_bounds__(256) void k_scan1p(const int* __restrict__ Gm,
    int* __restrict__ part, int* __restrict__ bsums){
  __shared__ int s[256];
  int t = threadIdx.x;
  int base = blockIdx.x*4096 + t*16;
  int v[16]; int sum = 0;
  #pragma unroll
  for (int i=0;i<16;i++){
    int idx = base+i; int val = 0;
    if (idx < SCN){
      int l = idx/(NBUK*NBLK);
      int r = idx - l*(NBUK*NBLK);
      int buk = r>>8, b = r&255;
      val = Gm[(size_t)(l*NBLK+b)*392 + buk];
    }
    v[i]=val; sum+=val;
  }
  s[t]=sum; __syncthreads();
  for (int off=1; off<256; off<<=1){
    int x = (t>=off)? s[t-off] : 0;
    __syncthreads(); s[t]+=x; __syncthreads();
  }
  if (t==255) bsums[blockIdx.x] = s[255];
  int run = s[t]-sum;
  #pragma unroll
  for (int i=0;i<16;i++){ if (base+i<SCN) part[base+i]=run; run += v[i]; }
}

__global__ __launch_bounds__(1024) void k_scan2(int* bsums, int nb){
  __shared__ int s[1024];
  int t=threadIdx.x;
  int v = (t<nb)? bsums[t]:0;
  s[t]=v; __syncthreads();
  for (int off=1; off<1024; off<<=1){
    int x=(t>=off)? s[t-off]:0; __syncthreads(); s[t]+=x; __syncthreads();
  }
  if (t<nb) bsums[t] = s[t]-v;
}

__global__ void k_scan3(int* __restrict__ S, const int* __restrict__ bsums){
  int gid = blockIdx.x*256+threadIdx.x;
  if (gid < SCN) S[gid] += bsums[gid>>12];
  if (gid==0) S[SCN]=LE;
}

// P3: LDS counting-sort by bucket (record = origk|dst7|buk), contiguous run writes
// of FINAL packed edges (src16|halfw16) + 1B dst array. LDS ~20 KB -> 8 blocks/CU.
__global__ __launch_bounds__(256) void k_bscatter(const int* __restrict__ ei,
    const float* __restrict__ ew, const int* __restrict__ S,
    unsigned int* __restrict__ btmpP, unsigned char* __restrict__ btmpD){
  int l = blockIdx.x >> 8, b = blockIdx.x & 255;
  int t = threadIdx.x;
  __shared__ int cnt[392], bstart[392], cur[392], runb[392];
  __shared__ int ps[256];
  __shared__ unsigned int eb[CH];       // 12.5 KB
  for (int i=t;i<392;i+=256) cnt[i]=0;
  __syncthreads();
  const int* srcs = ei + (size_t)(2*l)*EE + b*CH;
  const int* dsts = ei + (size_t)(2*l+1)*EE + b*CH;
  const float* wsrc = ew + (size_t)l*EE + b*CH;
  for (int k=t;k<CH;k+=256) atomicAdd(&cnt[dsts[k]>>7],1);
  __syncthreads();
  // exclusive scan over 392 counts (2 per thread)
  int v0 = (2*t<392)? cnt[2*t]:0;
  int v1 = (2*t+1<392)? cnt[2*t+1]:0;
  int sum = v0+v1;
  ps[t]=sum; __syncthreads();
  for (int o=1;o<256;o<<=1){ int x=(t>=o)?ps[t-o]:0; __syncthreads(); ps[t]+=x; __syncthreads(); }
  int run = ps[t]-sum;
  if (2*t<392){ bstart[2*t]=run; cur[2*t]=run; }
  if (2*t+1<392){ bstart[2*t+1]=run+v0; cur[2*t+1]=run+v0; }
  for (int i=t;i<NBUK;i+=256) runb[i] = S[(size_t)(l*NBUK+i)*NBLK + b];
  __syncthreads();
  // place records into LDS in bucket order (L1 re-read of dsts)
  for (int k=t;k<CH;k+=256){
    int dst = dsts[k];
    int buk = dst>>7;
    int pos = atomicAdd(&cur[buk],1);
    eb[pos] = (unsigned)k | ((unsigned)(dst&127)<<16) | ((unsigned)buk<<23);
  }
  __syncthreads();
  // streaming write; src/w fetched from the block's L1-hot input slice
  for (int k=t;k<CH;k+=256){
    unsigned e = eb[k];
    int buk = e>>23;
    int origk = e & 0x1FFF;
    int src = srcs[origk];
    float w = wsrc[origk];
    int gp = runb[buk] + (k - bstart[buk]);
    unsigned short hw = __half_as_ushort(__float2half(w));
    btmpP[gp] = (unsigned)src | ((unsigned)hw<<16);
    btmpD[gp] = (unsigned char)((e>>16)&127);
  }
}

// P4: per-bucket count+scan from 1B dst array, then direct scatter of packed edges
__global__ __launch_bounds__(256) void k_fsort(const unsigned int* __restrict__ btmpP,
    const unsigned char* __restrict__ btmpD, const int* __restrict__ S,
    unsigned int* __restrict__ sedge, int* __restrict__ offs){
  int lbuk = blockIdx.x;                 // 0..2736
  int l = lbuk/NBUK, bl = lbuk - l*NBUK;
  int t = threadIdx.x;
  int base = S[(size_t)lbuk*NBLK];
  int end  = S[(size_t)(lbuk+1)*NBLK];
  int nE = end - base;
  __shared__ int cnt[132], sc[132];
  if (t<132) cnt[t]=0;
  __syncthreads();
  for (int k=t; k<nE; k+=256) atomicAdd(&cnt[btmpD[base+k]], 1);
  __syncthreads();
  int c = (t<128)? cnt[t] : 0;
  if (t<128) sc[t]=c;
  __syncthreads();
  for (int o=1;o<128;o<<=1){
    int v = (t<128 && t>=o)? sc[t-o]:0;
    __syncthreads();
    if (t<128) sc[t]+=v;
    __syncthreads();
  }
  if (t<128){
    int excl = sc[t]-c;
    int node = bl*128+t;
    if (node<NN) offs[(size_t)l*NN+node] = base + excl;
    cnt[t] = base + excl;                // becomes cursor
  }
  if (lbuk==0 && t==255) offs[LN]=LE;
  __syncthreads();
  for (int k=t; k<nE; k+=256){
    int d = btmpD[base+k];
    int r = atomicAdd(&cnt[d],1);
    sedge[r] = btmpP[base+k];
  }
}

// gather embedding -> bf16 x
__global__ void k_gather_emb(const int* __restrict__ verts, const float* __restrict__ emb,
                             unsigned short* __restrict__ x){
  int gid = blockIdx.x*256+threadIdx.x;   // NN*16 groups of 8
  int n = gid>>4, q = gid&15;
  if (n>=NN) return;
  int v = verts[n];
  const float4* p = (const float4*)emb + (size_t)v*32 + q*2;
  float4 v0 = p[0], v1 = p[1];
  short8 w;
  w[0]=(short)f2bf(v0.x); w[1]=(short)f2bf(v0.y); w[2]=(short)f2bf(v0.z); w[3]=(short)f2bf(v0.w);
  w[4]=(short)f2bf(v1.x); w[5]=(short)f2bf(v1.y); w[6]=(short)f2bf(v1.z); w[7]=(short)f2bf(v1.w);
  *(short8*)(x + (size_t)n*128 + q*8) = w;
}

// ---- transpose + bf16-convert all 18 hidden weight matrices: Wt[m][n][k] ----
__global__ __launch_bounds__(256) void k_prep_w(const float* __restrict__ wh,
    const float* __restrict__ tewl, const float* __restrict__ tewc,
    unsigned short* __restrict__ Wt){
  int gid = blockIdx.x*256+threadIdx.x;          // 18*16384
  int m = gid>>14; int idx = gid&16383;
  int n = idx>>7, k = idx&127;
  const float* src = (m<6)? wh + (size_t)m*16384
                   : (m<12)? tewl + (size_t)(m-6)*16384
                   : tewc + (size_t)(m-12)*16384;
  Wt[gid] = f2bf(src[k*128+n]);
}

// stage 64 bf16 rows -> LDS tile [64][LSTRIDE]
static __device__ __forceinline__ void stage64bf(const unsigned short* __restrict__ src,
    int row0, int M, unsigned short* Xs, int tid){
  #pragma unroll
  for (int it=0; it<4; it++){
    int idx = tid + it*256;
    int r = idx>>4, k8 = idx&15;
    short8 v = short8(0);
    if (row0+r < M) v = *(const short8*)(src + (size_t)(row0+r)*128 + k8*8);
    *(short8*)&Xs[r*LSTRIDE + k8*8] = v;
  }
}

// ---------------- MFMA GEMM: Ybf16 = xbf @ Wt (layer 0 only) ----------------
__global__ __launch_bounds__(256) void k_gemm_sup(const unsigned short* __restrict__ X,
    const unsigned short* __restrict__ Wt, unsigned short* __restrict__ Y, int M){
  __shared__ unsigned short Xs[64*LSTRIDE];
  int tid = threadIdx.x;
  int row0 = blockIdx.x*64;
  stage64bf(X, row0, M, Xs, tid);
  __syncthreads();
  int w = tid>>6, lane = tid&63, m = lane&15, q = lane>>4;
  f32x4 acc[8];
  #pragma unroll
  for (int nt=0;nt<8;nt++){ acc[nt][0]=0.f; acc[nt][1]=0.f; acc[nt][2]=0.f; acc[nt][3]=0.f; }
  #pragma unroll
  for (int kc=0; kc<4; kc++){
    short8 a = *(const short8*)&Xs[(16*w+m)*LSTRIDE + kc*32 + 8*q];
    #pragma unroll
    for (int nt=0; nt<8; nt++){
      short8 b = *(const short8*)&Wt[(size_t)(nt*16+m)*128 + kc*32 + 8*q];
      acc[nt] = __builtin_amdgcn_mfma_f32_16x16x32_bf16(a, b, acc[nt], 0,0,0);
    }
  }
  #pragma unroll
  for (int nt=0; nt<8; nt++){
    #pragma unroll
    for (int i=0;i<4;i++){
      int rr = row0 + 16*w + 4*q + i;
      if (rr<M) Y[(size_t)rr*128 + nt*16 + m] = f2bf(acc[nt][i]);
    }
  }
}

// ------- fused: BN(bf16 h)+ReLU -> LDS; dual MFMA; gate; short8 writeback; [+ next sup] -------
template<int FUSE>
__global__ __launch_bounds__(256) void k_gemm_gate2(const unsigned short* __restrict__ H,
    const float* __restrict__ stL,            // NREP replicas [rep][sum128|sq128]
    const float* __restrict__ gamma, const float* __restrict__ beta,
    const unsigned short* __restrict__ Wl, const unsigned short* __restrict__ Wc,
    const unsigned short* __restrict__ Wn, const float* __restrict__ teb,
    unsigned short* __restrict__ x, unsigned short* __restrict__ supY, int M){
  __shared__ unsigned short XsX[64*LSTRIDE];
  __shared__ unsigned short XsH[64*LSTRIDE];
  __shared__ float sSc[128], sOff[128];
  int tid = threadIdx.x;
  int row0 = blockIdx.x*64;
  if (tid<128){
    float s=0.f, sq=0.f;
    #pragma unroll 8
    for (int g=0; g<NREP; g++){ s += stL[g*256+tid]; sq += stL[g*256+128+tid]; }
    float mean = s*(1.0f/NN);
    float var = sq*(1.0f/NN) - mean*mean;
    float sc = rsqrtf(var+BN_EPS)*gamma[tid];
    sSc[tid]=sc; sOff[tid]=beta[tid]-mean*sc;
  }
  stage64bf(x, row0, M, XsX, tid);
  __syncthreads();
  #pragma unroll
  for (int it=0; it<4; it++){
    int idx = tid + it*256;
    int r = idx>>4, k8 = idx&15;
    short8 hv8 = short8(0);
    if (row0+r < M) hv8 = *(const short8*)(H + (size_t)(row0+r)*128 + k8*8);
    int k = k8*8;
    short8 w;
    #pragma unroll
    for (int j=0;j<8;j++){
      float o = bf2f((unsigned short)hv8[j]);
      float hn = fmaxf(fmaf(o, sSc[k+j], sOff[k+j]), 0.f);
      w[j] = (short)f2bf(hn);
    }
    *(short8*)&XsH[r*LSTRIDE + k8*8] = w;
  }
  __syncthreads();
  int w = tid>>6, lane = tid&63, m = lane&15, q = lane>>4;
  f32x4 acc[8];
  #pragma unroll
  for (int nt=0;nt<8;nt++){ acc[nt][0]=0.f; acc[nt][1]=0.f; acc[nt][2]=0.f; acc[nt][3]=0.f; }
  #pragma unroll
  for (int kc=0; kc<4; kc++){
    short8 a = *(const short8*)&XsX[(16*w+m)*LSTRIDE + kc*32 + 8*q];
    #pragma unroll
    for (int nt=0; nt<8; nt++){
      short8 b = *(const short8*)&Wl[(size_t)(nt*16+m)*128 + kc*32 + 8*q];
      acc[nt] = __builtin_amdgcn_mfma_f32_16x16x32_bf16(a, b, acc[nt], 0,0,0);
    }
  }
  #pragma unroll
  for (int kc=0; kc<4; kc++){
    short8 a = *(const short8*)&XsH[(16*w+m)*LSTRIDE + kc*32 + 8*q];
    #pragma unroll
    for (int nt=0; nt<8; nt++){
      short8 b = *(const short8*)&Wc[(size_t)(nt*16+m)*128 + kc*32 + 8*q];
      acc[nt] = __builtin_amdgcn_mfma_f32_16x16x32_bf16(a, b, acc[nt], 0,0,0);
    }
  }
  // gate epilogue: write xn into XsH (each cell owned by one thread), XsX too if FUSE
  #pragma unroll
  for (int nt=0; nt<8; nt++){
    int col = nt*16 + m;
    float bias = teb[col];
    #pragma unroll
    for (int i=0;i<4;i++){
      int lr = 16*w + 4*q + i;
      float hv = bf2f(XsH[lr*LSTRIDE + col]);
      float xo = bf2f(XsX[lr*LSTRIDE + col]);
      float g = sigm(acc[nt][i] + bias);
      unsigned short xnb = f2bf(g*hv + (1.f-g)*xo);
      XsH[lr*LSTRIDE + col] = xnb;
      if (FUSE) XsX[lr*LSTRIDE + col] = xnb;
    }
  }
  __syncthreads();
  // coalesced short8 writeback of x_new
  #pragma unroll
  for (int it=0; it<4; it++){
    int idx = tid + it*256;
    int r = idx>>4, k8 = idx&15;
    if (row0+r < M)
      *(short8*)(x + (size_t)(row0+r)*128 + k8*8) = *(short8*)&XsH[r*LSTRIDE + k8*8];
  }
  if (FUSE){
    #pragma unroll
    for (int nt=0;nt<8;nt++){ acc[nt][0]=0.f; acc[nt][1]=0.f; acc[nt][2]=0.f; acc[nt][3]=0.f; }
    #pragma unroll
    for (int kc=0; kc<4; kc++){
      short8 a = *(const short8*)&XsX[(16*w+m)*LSTRIDE + kc*32 + 8*q];
      #pragma unroll
      for (int nt=0; nt<8; nt++){
        short8 b = *(const short8*)&Wn[(size_t)(nt*16+m)*128 + kc*32 + 8*q];
        acc[nt] = __builtin_amdgcn_mfma_f32_16x16x32_bf16(a, b, acc[nt], 0,0,0);
      }
    }
    #pragma unroll
    for (int nt=0; nt<8; nt++){
      #pragma unroll
      for (int i=0;i<4;i++){
        int rr = row0 + 16*w + 4*q + i;
        if (rr<M) supY[(size_t)rr*128 + nt*16 + m] = f2bf(acc[nt][i]);
      }
    }
  }
}

// ---------------- Y[M,20] = bf16 X[M,128] @ W[128,20] (fp32 acc) ----------------
__global__ __launch_bounds__(256) void k_gemm_out(const unsigned short* __restrict__ X,
    const float* __restrict__ W, float* __restrict__ Y, int M){
  __shared__ float Ws[DIM*OUTC];
  __shared__ float Xs2[8*DIM];
  int tid=threadIdx.x;
  for (int i=tid;i<DIM*OUTC;i+=256) Ws[i]=W[i];
  int row0=blockIdx.x*8;
  if (tid<128){
    int r = tid>>4, k8 = tid&15;
    short8 v = short8(0);
    if (row0+r<M) v = *(const short8*)(X + (size_t)(row0+r)*128 + k8*8);
    #pragma unroll
    for (int j=0;j<8;j++) Xs2[r*DIM+k8*8+j] = bf2f((unsigned short)v[j]);
  }
  __syncthreads();
  int c = tid&31, rl=tid>>5;
  if (c<OUTC && row0+rl<M){
    float acc=0.f;
    #pragma unroll 8
    for (int k=0;k<DIM;k++) acc += Xs2[rl*DIM+k]*Ws[k*OUTC+c];
    Y[(size_t)(row0+rl)*OUTC+c]=acc;
  }
}

// -------- SpMM gather (contiguous per-node edges, 4-deep unroll) + fused BN stats --------
__global__ __launch_bounds__(256) void k_spmm128(const unsigned short* __restrict__ sup,
    const unsigned int* __restrict__ sedge, const int* __restrict__ offs,
    unsigned short* __restrict__ h, int lbase, float* __restrict__ stL){
  int nl = threadIdx.x>>5;
  int node = blockIdx.x*8 + nl;
  int fq = threadIdx.x & 31;
  int p = offs[lbase+node], end = offs[lbase+node+1];
  float4 a0 = make_float4(0.f,0.f,0.f,0.f), a1 = a0, a2 = a0, a3 = a0;
  for (; p+3<end; p+=4){
    unsigned int e0 = __builtin_nontemporal_load(sedge+p);
    unsigned int e1 = __builtin_nontemporal_load(sedge+p+1);
    unsigned int e2 = __builtin_nontemporal_load(sedge+p+2);
    unsigned int e3 = __builtin_nontemporal_load(sedge+p+3);
    ushort4 s0 = *(const ushort4*)(sup + (size_t)(e0&0xFFFFu)*128 + fq*4);
    ushort4 s1 = *(const ushort4*)(sup + (size_t)(e1&0xFFFFu)*128 + fq*4);
    ushort4 s2 = *(const ushort4*)(sup + (size_t)(e2&0xFFFFu)*128 + fq*4);
    ushort4 s3 = *(const ushort4*)(sup + (size_t)(e3&0xFFFFu)*128 + fq*4);
    float w0 = __half2float(__ushort_as_half((unsigned short)(e0>>16)));
    float w1 = __half2float(__ushort_as_half((unsigned short)(e1>>16)));
    float w2 = __half2float(__ushort_as_half((unsigned short)(e2>>16)));
    float w3 = __half2float(__ushort_as_half((unsigned short)(e3>>16)));
    a0.x += w0*bf2f(s0.x); a0.y += w0*bf2f(s0.y); a0.z += w0*bf2f(s0.z); a0.w += w0*bf2f(s0.w);
    a1.x += w1*bf2f(s1.x); a1.y += w1*bf2f(s1.y); a1.z += w1*bf2f(s1.z); a1.w += w1*bf2f(s1.w);
    a2.x += w2*bf2f(s2.x); a2.y += w2*bf2f(s2.y); a2.z += w2*bf2f(s2.z); a2.w += w2*bf2f(s2.w);
    a3.x += w3*bf2f(s3.x); a3.y += w3*bf2f(s3.y); a3.z += w3*bf2f(s3.z); a3.w += w3*bf2f(s3.w);
  }
  for (; p<end; p++){
    unsigned int e0 = __builtin_nontemporal_load(sedge+p);
    float w0 = __half2float(__ushort_as_half((unsigned short)(e0>>16)));
    ushort4 s0 = *(const ushort4*)(sup + (size_t)(e0&0xFFFFu)*128 + fq*4);
    a0.x += w0*bf2f(s0.x); a0.y += w0*bf2f(s0.y); a0.z += w0*bf2f(s0.z); a0.w += w0*bf2f(s0.w);
  }
  a0.x+=a1.x+a2.x+a3.x; a0.y+=a1.y+a2.y+a3.y;
  a0.z+=a1.z+a2.z+a3.z; a0.w+=a1.w+a2.w+a3.w;
  ushort4 ov;
  ov.x=f2bf(a0.x); ov.y=f2bf(a0.y); ov.z=f2bf(a0.z); ov.w=f2bf(a0.w);
  *(ushort4*)(h + (size_t)node*128 + fq*4) = ov;
  // fused BN stats from fp32 registers
  __shared__ float sP[8][132], sQ[8][132];
  int f0 = fq*4;
  sP[nl][f0+0]=a0.x; sP[nl][f0+1]=a0.y; sP[nl][f0+2]=a0.z; sP[nl][f0+3]=a0.w;
  sQ[nl][f0+0]=a0.x*a0.x; sQ[nl][f0+1]=a0.y*a0.y; sQ[nl][f0+2]=a0.z*a0.z; sQ[nl][f0+3]=a0.w*a0.w;
  __syncthreads();
  if (threadIdx.x < 128){
    int f = threadIdx.x;
    float s=0.f, sq=0.f;
    #pragma unroll
    for (int n=0;n<8;n++){ s += sP[n][f]; sq += sQ[n][f]; }
    float* base = stL + (blockIdx.x & (NREP-1))*256;
    atomicAdd(&base[f], s); atomicAdd(&base[128+f], sq);
  }
}

__global__ __launch_bounds__(256) void k_spmm_out(const float* __restrict__ sup,
    const unsigned int* __restrict__ sedge, const int* __restrict__ offs,
    float* __restrict__ h, int lbase){
  int node = blockIdx.x*8 + (threadIdx.x>>5);
  int c = threadIdx.x & 31;
  int p = offs[lbase+node], end = offs[lbase+node+1];
  float acc=0.f;
  for (; p<end; p++){
    unsigned int e = __builtin_nontemporal_load(sedge+p);
    float w = __half2float(__ushort_as_half((unsigned short)(e>>16)));
    if (c<OUTC) acc += w*sup[(size_t)(e&0xFFFFu)*OUTC+c];
  }
  if (c<OUTC) h[(size_t)node*OUTC+c]=acc;
}

// ---------------- output-layer BN stats (8-way replicated) ----------------
__global__ __launch_bounds__(256) void k_bn_stats_out(const float* __restrict__ h,
    float* __restrict__ st8, int rpb){
  int f = threadIdx.x % 32;
  int g = threadIdx.x / 32;
  float s=0.f, ss=0.f;
  int r0 = blockIdx.x*rpb;
  int r1 = min(NN, r0+rpb);
  if (f < OUTC){
    for (int r=r0+g; r<r1; r+=8){ float v = h[(size_t)r*OUTC+f]; s+=v; ss+=v*v; }
  }
  __shared__ float sh[256], sh2[256];
  sh[threadIdx.x]=s; sh2[threadIdx.x]=ss; __syncthreads();
  if (threadIdx.x < 32){
    #pragma unroll
    for (int i=1;i<8;i++){ s+=sh[threadIdx.x+i*32]; ss+=sh2[threadIdx.x+i*32]; }
    if (f<OUTC){
      float* base = st8 + (blockIdx.x&7)*64;
      atomicAdd(&base[f], s); atomicAdd(&base[32+f], ss);
    }
  }
}

__global__ void k_bn_reduce8(const float* __restrict__ st8, float* __restrict__ st){
  int f = threadIdx.x;          // 64
  float s=0.f;
  #pragma unroll
  for (int g=0; g<8; g++) s += st8[g*64+f];
  st[f]=s;
}

__global__ void k_bn_out(float* __restrict__ h, const float* __restrict__ st,
    const float* __restrict__ gamma, const float* __restrict__ beta){
  int gid = blockIdx.x*256+threadIdx.x;
  if (gid>=NN*OUTC) return;
  int f = gid % OUTC;
  const float invN = 1.0f/NN;
  float m = st[f]*invN;
  float var = st[32+f]*invN - m*m;
  float sc = rsqrtf(var+BN_EPS)*gamma[f];
  h[gid] = fmaxf((h[gid]-m)*sc + beta[f], 0.f);
}

// ---------------- final masked reduce (8-way replicated) ----------------
__global__ __launch_bounds__(256) void k_reduce(const float* __restrict__ xf,
    const int* __restrict__ verts, const float* __restrict__ mw,
    float* __restrict__ acc8, int rpb){
  int c = threadIdx.x & 31, g = threadIdx.x >> 5;
  int r0 = blockIdx.x*rpb;
  int r1 = min(NN, r0+rpb);
  float s=0.f;
  for (int r=r0+g; r<r1; r+=8){
    float m = mw[verts[r]];
    if (c<OUTC) s += m * xf[(size_t)r*OUTC+c];
  }
  __shared__ float sh[256];
  sh[threadIdx.x]=s; __syncthreads();
  if (threadIdx.x<32){
    #pragma unroll
    for (int i=1;i<8;i++) s += sh[threadIdx.x + i*32];
    if (c<OUTC) atomicAdd(&acc8[(blockIdx.x&7)*32 + c], s);
  }
}

__global__ void k_final(const float* __restrict__ acc8, const float* __restrict__ mb,
                        float* __restrict__ out){
  int c=threadIdx.x;
  if (c<OUTC){
    float s=0.f;
    #pragma unroll
    for (int g=0; g<8; g++) s += acc8[g*32+c];
    out[c] = sigm(s+mb[c]);
  }
}

// ---------------- host ----------------
extern "C" void kernel_launch(void* const* d_in, const int* in_sizes, int n_in,
                              void* d_out, int out_size, void* d_ws, size_t ws_size,
                              hipStream_t stream){
  const int*   verts = (const int*)d_in[0];
  const int*   ei    = (const int*)d_in[1];
  const float* ew    = (const float*)d_in[2];
  const float* emb   = (const float*)d_in[3];
  const float* wh    = (const float*)d_in[4];
  const float* w_out = (const float*)d_in[6];
  const float* bng_h = (const float*)d_in[8];
  const float* bnb_h = (const float*)d_in[9];
  const float* bng_o = (const float*)d_in[10];
  const float* bnb_o = (const float*)d_in[11];
  const float* tewl  = (const float*)d_in[12];
  const float* tewc  = (const float*)d_in[13];
  const float* teb   = (const float*)d_in[14];
  const float* maskw = (const float*)d_in[15];
  const float* maskb = (const float*)d_in[16];
  float* out = (float*)d_out;

  char* ws = (char*)d_ws;
  size_t off=0;
  auto alloc=[&](size_t bytes)->char*{ char* p = ws+off; off += (bytes+255)&~(size_t)255; return p; };
  unsigned int* sedge = (unsigned int*)alloc(sizeof(int)*LE);   // 22.4 MB
  int*   offs   = (int*)  alloc(sizeof(int)*(LN+1));            // 1.4 MB
  int*   Gm     = (int*)  alloc(sizeof(int)*LL*NBLK*392);       // 2.8 MB
  int*   S      = (int*)  alloc(sizeof(int)*(SCN+1));           // 2.8 MB
  int*   bsums  = (int*)  alloc(sizeof(int)*1024);
  unsigned short* xbf   = (unsigned short*)alloc(sizeof(short)*NN*DIM); // 12.8 MB
  unsigned short* supbf = (unsigned short*)alloc(sizeof(short)*NN*DIM); // 12.8 MB
  unsigned short* hbf   = (unsigned short*)alloc(sizeof(short)*NN*DIM); // 12.8 MB
  float* buf20  = (float*)alloc(sizeof(float)*NN*OUTC);         // 4 MB
  unsigned short* Wt = (unsigned short*)alloc(sizeof(short)*18*DIM*DIM);
  const int STATSZ = 6*NREP*256 + 8*64 + 64 + 8*32;
  float* stats  = (float*)alloc(sizeof(float)*STATSZ);
  float* ostat8 = stats + 6*NREP*256;  // [8][64]
  float* ostat  = ostat8 + 8*64;       // [64]
  float* racc8  = ostat + 64;          // [8][32]
  // btmpP (22.4 MB) aliases xbf+supbf (25.6 MB contiguous); btmpD (5.6 MB) aliases hbf
  unsigned int*  btmpP = (unsigned int*)xbf;
  unsigned char* btmpD = (unsigned char*)hbf;

  // --- preprocessing: 4-pass LDS-atomic counting sort ---
  hipMemsetAsync(stats, 0, sizeof(float)*STATSZ, stream);
  k_prep_w<<<1152,256,0,stream>>>(wh, tewl, tewc, Wt);
  k_bh<<<LL*NBLK,256,0,stream>>>(ei, Gm);
  int nsb = (SCN+4095)/4096;  // 172
  k_scan1p<<<nsb,256,0,stream>>>(Gm, S, bsums);
  k_scan2<<<1,1024,0,stream>>>(bsums, nsb);
  k_scan3<<<(SCN+255)/256,256,0,stream>>>(S, bsums);
  k_bscatter<<<LL*NBLK,256,0,stream>>>(ei, ew, S, btmpP, btmpD);
  k_fsort<<<LL*NBUK,256,0,stream>>>(btmpP, btmpD, S, sedge, offs);
  k_gather_emb<<<NN*16/256,256,0,stream>>>(verts, emb, xbf);

  // --- 6 hidden layers; sup for layer i+1 computed inside gate2 of layer i ---
  k_gemm_sup<<<(NN+63)/64,256,0,stream>>>(xbf, Wt, supbf, NN);
  for (int i=0;i<6;i++){
    int j = (i==0)?5:(i-1);
    float* stL = stats + i*NREP*256;
    k_spmm128<<<NN/8,256,0,stream>>>(supbf, sedge, offs, hbf, i*NN, stL);
    if (i<5)
      k_gemm_gate2<1><<<(NN+63)/64,256,0,stream>>>(hbf, stL,
          bng_h+(size_t)i*DIM, bnb_h+(size_t)i*DIM,
          Wt + (size_t)(6+j)*DIM*DIM, Wt + (size_t)(12+j)*DIM*DIM,
          Wt + (size_t)(i+1)*DIM*DIM, teb + (size_t)j*DIM, xbf, supbf, NN);
    else
      k_gemm_gate2<0><<<(NN+63)/64,256,0,stream>>>(hbf, stL,
          bng_h+(size_t)i*DIM, bnb_h+(size_t)i*DIM,
          Wt + (size_t)(6+j)*DIM*DIM, Wt + (size_t)(12+j)*DIM*DIM,
          Wt, teb + (size_t)j*DIM, xbf, supbf, NN);
  }

  // --- output layer (fp32 accumulate) ---
  k_gemm_out<<<(NN+7)/8,256,0,stream>>>(xbf, w_out, buf20, NN);
  k_spmm_out<<<NN/8,256,0,stream>>>(buf20, sedge, offs, (float*)hbf, 6*NN);
  float* bufO = (float*)hbf;   // NN*OUTC fp32 = 4 MB <= 12.8 MB
  k_bn_stats_out<<<512,256,0,stream>>>(bufO, ostat8, 98);
  k_bn_reduce8<<<1,64,0,stream>>>(ostat8, ostat);
  k_bn_out<<<(NN*OUTC+255)/256,256,0,stream>>>(bufO, ostat, bng_o, bnb_o);
  k_reduce<<<512,256,0,stream>>>(bufO, verts, maskw, racc8, 98);
  k_final<<<1,64,0,stream>>>(racc8, maskb, out);
}